// Round 3
// baseline (845.966 us; speedup 1.0000x reference)
//
#include <hip/hip_runtime.h>

#define N_NODES 50000
#define N_EDGES 800000
#define F_IN    128
#define H_DIM   256
#define C_OUT   40

// ---- in-degree count over dst ----
__global__ __launch_bounds__(256) void count_k(const int* __restrict__ dst, int* __restrict__ cnt, int E) {
    int i = blockIdx.x * 256 + threadIdx.x;
    if (i < E) atomicAdd(&cnt[dst[i]], 1);
}

// ---- dinv[i] = rsqrt(cnt[i] + 1) ----
__global__ __launch_bounds__(256) void dinv_k(const int* __restrict__ cnt, float* __restrict__ dinv, int n) {
    int i = blockIdx.x * 256 + threadIdx.x;
    if (i < n) dinv[i] = rsqrtf((float)cnt[i] + 1.0f);
}

// ---- single-block exclusive scan: rowptr[0..N], cursor[i]=rowptr[i] ----
#define SCAN_T 1024
#define SCAN_CHUNK ((N_NODES + SCAN_T - 1) / SCAN_T)   // 49
__global__ __launch_bounds__(SCAN_T) void scan_k(const int* __restrict__ cnt,
                                                 int* __restrict__ rowptr,
                                                 int* __restrict__ cursor) {
    __shared__ int part[SCAN_T];
    const int t = threadIdx.x;
    const int lo = t * SCAN_CHUNK;
    const int hi = min(lo + SCAN_CHUNK, N_NODES);
    int s = 0;
    for (int i = lo; i < hi; i++) s += cnt[i];
    part[t] = s;
    __syncthreads();
    for (int off = 1; off < SCAN_T; off <<= 1) {
        int v = (t >= off) ? part[t - off] : 0;
        __syncthreads();
        part[t] += v;
        __syncthreads();
    }
    int run = part[t] - s;  // exclusive prefix at chunk start
    if (t == 0) rowptr[0] = 0;
    for (int i = lo; i < hi; i++) {
        cursor[i] = run;
        run += cnt[i];
        rowptr[i + 1] = run;
    }
}

// ---- bucket edges by dst ----
__global__ __launch_bounds__(256) void bucket_k(const int* __restrict__ src, const int* __restrict__ dst,
                                                int* __restrict__ cursor, int* __restrict__ srcs, int E) {
    int i = blockIdx.x * 256 + threadIdx.x;
    if (i < E) {
        int pos = atomicAdd(&cursor[dst[i]], 1);
        srcs[pos] = src[i];
    }
}

// ---- gather width-128 fp32 (x -> aggx), one wave per node, float2/lane ----
__global__ __launch_bounds__(256) void gather1(const float2* __restrict__ x2,     // [N][64]
                                               const int* __restrict__ rowptr,
                                               const int* __restrict__ srcs,
                                               const float* __restrict__ dinv,
                                               float2* __restrict__ agg2) {      // [N][64]
    const int node = blockIdx.x * 4 + (threadIdx.x >> 6);
    const int lane = threadIdx.x & 63;
    if (node >= N_NODES) return;
    const int beg = rowptr[node], end = rowptr[node + 1];
    const float dd = dinv[node];
    float a0 = 0.f, a1 = 0.f;
    for (int e = beg; e < end; e++) {
        const int s = srcs[e];
        const float nm = dd * dinv[s];
        const float2 v = x2[(size_t)s * 64 + lane];
        a0 += nm * v.x;
        a1 += nm * v.y;
    }
    const float2 v = x2[(size_t)node * 64 + lane];
    a0 += dd * dd * v.x;
    a1 += dd * dd * v.y;
    float2 o; o.x = a0; o.y = a1;
    agg2[(size_t)node * 64 + lane] = o;
}

// ---- gather width-256 fp32 (h1 -> aggh), one wave per node, float4/lane ----
__global__ __launch_bounds__(256) void gather2(const float4* __restrict__ h4,     // [N][64]
                                               const int* __restrict__ rowptr,
                                               const int* __restrict__ srcs,
                                               const float* __restrict__ dinv,
                                               float4* __restrict__ agg4) {      // [N][64]
    const int node = blockIdx.x * 4 + (threadIdx.x >> 6);
    const int lane = threadIdx.x & 63;
    if (node >= N_NODES) return;
    const int beg = rowptr[node], end = rowptr[node + 1];
    const float dd = dinv[node];
    float a0 = 0.f, a1 = 0.f, a2 = 0.f, a3 = 0.f;
    for (int e = beg; e < end; e++) {
        const int s = srcs[e];
        const float nm = dd * dinv[s];
        const float4 v = h4[(size_t)s * 64 + lane];
        a0 += nm * v.x; a1 += nm * v.y; a2 += nm * v.z; a3 += nm * v.w;
    }
    const float4 v = h4[(size_t)node * 64 + lane];
    const float ss = dd * dd;
    a0 += ss * v.x; a1 += ss * v.y; a2 += ss * v.z; a3 += ss * v.w;
    float4 o; o.x = a0; o.y = a1; o.z = a2; o.w = a3;
    agg4[(size_t)node * 64 + lane] = o;
}

// ---- gemm1: h1 = relu(aggx @ W1^T + b1), K=128, 8 rows/block ----
#define RR 8
__global__ __launch_bounds__(256) void gemm1_k(const float* __restrict__ X,
                                               const float* __restrict__ W,
                                               const float* __restrict__ b,
                                               float* __restrict__ h1) {
    __shared__ float xs[RR * F_IN];
    const int row0 = blockIdx.x * RR;
    const int t = threadIdx.x;
    for (int j = t; j < RR * F_IN; j += 256) xs[j] = X[(size_t)row0 * F_IN + j];
    __syncthreads();
    const float4* w4 = reinterpret_cast<const float4*>(W + (size_t)t * F_IN);
    float acc[RR];
#pragma unroll
    for (int r = 0; r < RR; r++) acc[r] = 0.f;
    for (int k4 = 0; k4 < F_IN / 4; k4++) {
        const float4 w = w4[k4];
        const int k = k4 * 4;
#pragma unroll
        for (int r = 0; r < RR; r++) {
            const float* xr = &xs[r * F_IN + k];
            acc[r] += xr[0] * w.x + xr[1] * w.y + xr[2] * w.z + xr[3] * w.w;
        }
    }
    const float bb = b[t];
#pragma unroll
    for (int r = 0; r < RR; r++)
        h1[(size_t)(row0 + r) * H_DIM + t] = fmaxf(acc[r] + bb, 0.f);
}

// ---- gemm2: h2 = aggh @ W2^T + b2, K=256, 8 rows/block ----
__global__ __launch_bounds__(256) void gemm2_k(const float* __restrict__ X,
                                               const float* __restrict__ W,
                                               const float* __restrict__ b,
                                               float* __restrict__ h2) {
    __shared__ float xs[RR * H_DIM];
    const int row0 = blockIdx.x * RR;
    const int t = threadIdx.x;
    for (int j = t; j < RR * H_DIM; j += 256) xs[j] = X[(size_t)row0 * H_DIM + j];
    __syncthreads();
    const float4* w4 = reinterpret_cast<const float4*>(W + (size_t)t * H_DIM);
    float acc[RR];
#pragma unroll
    for (int r = 0; r < RR; r++) acc[r] = 0.f;
    for (int k4 = 0; k4 < H_DIM / 4; k4++) {
        const float4 w = w4[k4];
        const int k = k4 * 4;
#pragma unroll
        for (int r = 0; r < RR; r++) {
            const float* xr = &xs[r * H_DIM + k];
            acc[r] += xr[0] * w.x + xr[1] * w.y + xr[2] * w.z + xr[3] * w.w;
        }
    }
    const float bb = b[t];
#pragma unroll
    for (int r = 0; r < RR; r++)
        h2[(size_t)(row0 + r) * H_DIM + t] = acc[r] + bb;
}

// ---- head: out = h2 @ Wout^T + bout, K=256, C=40, 8 rows/block, 64 threads ----
__global__ __launch_bounds__(64) void head_k(const float* __restrict__ X,
                                             const float* __restrict__ W,
                                             const float* __restrict__ b,
                                             float* __restrict__ out) {
    __shared__ float xs[RR * H_DIM];
    const int row0 = blockIdx.x * RR;
    const int t = threadIdx.x;
    for (int j = t; j < RR * H_DIM; j += 64) xs[j] = X[(size_t)row0 * H_DIM + j];
    __syncthreads();
    if (t >= C_OUT) return;
    const float4* w4 = reinterpret_cast<const float4*>(W + (size_t)t * H_DIM);
    float acc[RR];
#pragma unroll
    for (int r = 0; r < RR; r++) acc[r] = 0.f;
    for (int k4 = 0; k4 < H_DIM / 4; k4++) {
        const float4 w = w4[k4];
        const int k = k4 * 4;
#pragma unroll
        for (int r = 0; r < RR; r++) {
            const float* xr = &xs[r * H_DIM + k];
            acc[r] += xr[0] * w.x + xr[1] * w.y + xr[2] * w.z + xr[3] * w.w;
        }
    }
    const float bb = b[t];
#pragma unroll
    for (int r = 0; r < RR; r++)
        out[(size_t)(row0 + r) * C_OUT + t] = acc[r] + bb;
}

extern "C" void kernel_launch(void* const* d_in, const int* in_sizes, int n_in,
                              void* d_out, int out_size, void* d_ws, size_t ws_size,
                              hipStream_t stream) {
    const float* x    = (const float*)d_in[0];
    const int*   ei   = (const int*)d_in[1];
    const float* W1   = (const float*)d_in[2];
    const float* b1   = (const float*)d_in[3];
    const float* W2   = (const float*)d_in[4];
    const float* b2   = (const float*)d_in[5];
    const float* Wout = (const float*)d_in[6];
    const float* bout = (const float*)d_in[7];
    float* out = (float*)d_out;

    const int* src = ei;            // edge_index[0]
    const int* dst = ei + N_EDGES;  // edge_index[1]

    // workspace layout (~106.5 MB)
    char* ws = (char*)d_ws;
    size_t o = 0;
    auto alloc = [&](size_t bytes) { size_t p = o; o = (o + bytes + 255) & ~(size_t)255; return p; };
    int*   cnt    = (int*)(ws + alloc((size_t)N_NODES * 4));
    float* dinv   = (float*)(ws + alloc((size_t)N_NODES * 4));
    int*   rowptr = (int*)(ws + alloc((size_t)(N_NODES + 1) * 4));
    int*   cursor = (int*)(ws + alloc((size_t)N_NODES * 4));
    int*   srcs   = (int*)(ws + alloc((size_t)N_EDGES * 4));
    float* bufA   = (float*)(ws + alloc((size_t)N_NODES * H_DIM * 4));  // h1, then h2
    float* bufB   = (float*)(ws + alloc((size_t)N_NODES * H_DIM * 4));  // aggx, then aggh

    // CSR build
    hipMemsetAsync(cnt, 0, (size_t)N_NODES * 4, stream);
    count_k<<<(N_EDGES + 255) / 256, 256, 0, stream>>>(dst, cnt, N_EDGES);
    dinv_k<<<(N_NODES + 255) / 256, 256, 0, stream>>>(cnt, dinv, N_NODES);
    scan_k<<<1, SCAN_T, 0, stream>>>(cnt, rowptr, cursor);
    bucket_k<<<(N_EDGES + 255) / 256, 256, 0, stream>>>(src, dst, cursor, srcs, N_EDGES);

    // layer 1 (aggregate-first by linearity): aggx = A*x ; h1 = relu(aggx@W1^T + b1)
    gather1<<<(N_NODES + 3) / 4, 256, 0, stream>>>((const float2*)x, rowptr, srcs, dinv, (float2*)bufB);
    gemm1_k<<<N_NODES / RR, 256, 0, stream>>>(bufB, W1, b1, bufA);

    // layer 2: aggh = A*h1 ; h2 = aggh@W2^T + b2
    gather2<<<(N_NODES + 3) / 4, 256, 0, stream>>>((const float4*)bufA, rowptr, srcs, dinv, (float4*)bufB);
    gemm2_k<<<N_NODES / RR, 256, 0, stream>>>(bufB, W2, b2, bufA);

    // head
    head_k<<<N_NODES / RR, 64, 0, stream>>>(bufA, Wout, bout, out);
}

// Round 4
// 636.599 us; speedup vs baseline: 1.3289x; 1.3289x over previous
//
#include <hip/hip_runtime.h>

#define N_NODES 50000
#define N_EDGES 800000
#define F_IN    128
#define H_DIM   256
#define C_OUT   40

typedef unsigned short u16;
typedef unsigned int   u32;
typedef short bf16x8 __attribute__((ext_vector_type(8)));
typedef float f32x4  __attribute__((ext_vector_type(4)));

__device__ inline float bfbits2f(u16 u) { return __uint_as_float(((u32)u) << 16); }
__device__ inline u16 f2bf(float f) {
    u32 u = __float_as_uint(f);
    u += 0x7fffu + ((u >> 16) & 1u);   // RNE
    return (u16)(u >> 16);
}
__device__ inline u32 pack2(float a, float b) {
    return (u32)f2bf(a) | ((u32)f2bf(b) << 16);
}

// ---- fp32 -> bf16 convert (4 elems/thread) ----
__global__ __launch_bounds__(256) void cvt_k(const float4* __restrict__ src,
                                             uint2* __restrict__ dst, int n4) {
    int i = blockIdx.x * 256 + threadIdx.x;
    if (i < n4) {
        float4 v = src[i];
        uint2 o; o.x = pack2(v.x, v.y); o.y = pack2(v.z, v.w);
        dst[i] = o;
    }
}

// ---- in-degree count over dst ----
__global__ __launch_bounds__(256) void count_k(const int* __restrict__ dst, int* __restrict__ cnt, int E) {
    int i = blockIdx.x * 256 + threadIdx.x;
    if (i < E) atomicAdd(&cnt[dst[i]], 1);
}

// ---- dinv[i] = rsqrt(cnt[i] + 1) ----
__global__ __launch_bounds__(256) void dinv_k(const int* __restrict__ cnt, float* __restrict__ dinv, int n) {
    int i = blockIdx.x * 256 + threadIdx.x;
    if (i < n) dinv[i] = rsqrtf((float)cnt[i] + 1.0f);
}

// ---- single-block exclusive scan: rowptr[0..N], cursor[i]=rowptr[i] ----
#define SCAN_T 1024
#define SCAN_CHUNK ((N_NODES + SCAN_T - 1) / SCAN_T)   // 49
__global__ __launch_bounds__(SCAN_T) void scan_k(const int* __restrict__ cnt,
                                                 int* __restrict__ rowptr,
                                                 int* __restrict__ cursor) {
    __shared__ int part[SCAN_T];
    const int t = threadIdx.x;
    const int lo = t * SCAN_CHUNK;
    const int hi = min(lo + SCAN_CHUNK, N_NODES);
    int s = 0;
    for (int i = lo; i < hi; i++) s += cnt[i];
    part[t] = s;
    __syncthreads();
    for (int off = 1; off < SCAN_T; off <<= 1) {
        int v = (t >= off) ? part[t - off] : 0;
        __syncthreads();
        part[t] += v;
        __syncthreads();
    }
    int run = part[t] - s;
    if (t == 0) rowptr[0] = 0;
    for (int i = lo; i < hi; i++) {
        cursor[i] = run;
        run += cnt[i];
        rowptr[i + 1] = run;
    }
}

// ---- bucket edges by dst ----
__global__ __launch_bounds__(256) void bucket_k(const int* __restrict__ src, const int* __restrict__ dst,
                                                int* __restrict__ cursor, int* __restrict__ srcs, int E) {
    int i = blockIdx.x * 256 + threadIdx.x;
    if (i < E) {
        int pos = atomicAdd(&cursor[dst[i]], 1);
        srcs[pos] = src[i];
    }
}

// ---- gather width-128 bf16 (xb -> aggx), one wave per node, u32(2 bf16)/lane ----
__global__ __launch_bounds__(256) void gather1_k(const u32* __restrict__ xb,     // [N][64] u32
                                                 const int* __restrict__ rowptr,
                                                 const int* __restrict__ srcs,
                                                 const float* __restrict__ dinv,
                                                 u32* __restrict__ aggx) {      // [N][64] u32
    const int node = blockIdx.x * 4 + (threadIdx.x >> 6);
    const int lane = threadIdx.x & 63;
    if (node >= N_NODES) return;
    const int beg = rowptr[node], end = rowptr[node + 1];
    const float dd = dinv[node];
    float a0 = 0.f, a1 = 0.f;
    for (int e = beg; e < end; e++) {
        const int s = srcs[e];
        const float nm = dd * dinv[s];
        const u32 v = xb[(size_t)s * 64 + lane];
        a0 += nm * bfbits2f((u16)v);
        a1 += nm * bfbits2f((u16)(v >> 16));
    }
    const u32 v = xb[(size_t)node * 64 + lane];
    a0 += dd * dd * bfbits2f((u16)v);
    a1 += dd * dd * bfbits2f((u16)(v >> 16));
    aggx[(size_t)node * 64 + lane] = pack2(a0, a1);
}

// ---- gather width-256 bf16 (h1b -> aggh), one wave per node, uint2(4 bf16)/lane ----
__global__ __launch_bounds__(256) void gather2_k(const uint2* __restrict__ hb,   // [N][64] uint2
                                                 const int* __restrict__ rowptr,
                                                 const int* __restrict__ srcs,
                                                 const float* __restrict__ dinv,
                                                 uint2* __restrict__ agg) {     // [N][64] uint2
    const int node = blockIdx.x * 4 + (threadIdx.x >> 6);
    const int lane = threadIdx.x & 63;
    if (node >= N_NODES) return;
    const int beg = rowptr[node], end = rowptr[node + 1];
    const float dd = dinv[node];
    float a0 = 0.f, a1 = 0.f, a2 = 0.f, a3 = 0.f;
    for (int e = beg; e < end; e++) {
        const int s = srcs[e];
        const float nm = dd * dinv[s];
        const uint2 v = hb[(size_t)s * 64 + lane];
        a0 += nm * bfbits2f((u16)v.x); a1 += nm * bfbits2f((u16)(v.x >> 16));
        a2 += nm * bfbits2f((u16)v.y); a3 += nm * bfbits2f((u16)(v.y >> 16));
    }
    const uint2 v = hb[(size_t)node * 64 + lane];
    const float ss = dd * dd;
    a0 += ss * bfbits2f((u16)v.x); a1 += ss * bfbits2f((u16)(v.x >> 16));
    a2 += ss * bfbits2f((u16)v.y); a3 += ss * bfbits2f((u16)(v.y >> 16));
    uint2 o; o.x = pack2(a0, a1); o.y = pack2(a2, a3);
    agg[(size_t)node * 64 + lane] = o;
}

// ---- MFMA GEMM: Y[m, n] = act( sum_k X[m,k]*W[n,k] + b[n] )
// X: [N_NODES][K] bf16, W: [*][K] bf16. Block = 64 rows (4 waves x 16), NT n-tiles of 16.
// A-frag: lane holds X[m0+(lane&15)][kk + quad*8 + j]; B-frag: W[nt*16+(lane&15)][same k]
// D: col = lane&15 (n), row = quad*4 + reg.  [layouts per m89/m120 verified mappings]
template<int K, int NT, bool RELU, bool OUT_F32>
__global__ __launch_bounds__(256) void mfma_gemm_k(const u16* __restrict__ X,
                                                   const u16* __restrict__ W,
                                                   const float* __restrict__ bias,
                                                   void* __restrict__ Y,
                                                   int wrow_max, int ocols) {
    const int wave = threadIdx.x >> 6;
    const int lane = threadIdx.x & 63;
    const int quad = lane >> 4;
    const int nn = lane & 15;
    const int m0 = blockIdx.x * 64 + wave * 16;

    int arow = m0 + nn;
    if (arow > N_NODES - 1) arow = N_NODES - 1;
    const u16* aptr = X + (size_t)arow * K + quad * 8;

    f32x4 acc[NT];
#pragma unroll
    for (int nt = 0; nt < NT; nt++) acc[nt] = (f32x4){0.f, 0.f, 0.f, 0.f};

#pragma unroll
    for (int kk = 0; kk < K; kk += 32) {
        bf16x8 af = *(const bf16x8*)(aptr + kk);
#pragma unroll
        for (int nt = 0; nt < NT; nt++) {
            int wr = nt * 16 + nn;
            if (wr > wrow_max) wr = wrow_max;
            bf16x8 bfr = *(const bf16x8*)(W + (size_t)wr * K + kk + quad * 8);
            acc[nt] = __builtin_amdgcn_mfma_f32_16x16x32_bf16(af, bfr, acc[nt], 0, 0, 0);
        }
    }

#pragma unroll
    for (int nt = 0; nt < NT; nt++) {
        const int col = nt * 16 + nn;
        if (col >= ocols) continue;
        const float bb = bias[col];
#pragma unroll
        for (int r = 0; r < 4; r++) {
            const int row = m0 + quad * 4 + r;
            if (row >= N_NODES) continue;
            float v = acc[nt][r] + bb;
            if (RELU) v = fmaxf(v, 0.f);
            if (OUT_F32) ((float*)Y)[(size_t)row * ocols + col] = v;
            else         ((u16*)Y)[(size_t)row * ocols + col] = f2bf(v);
        }
    }
}

extern "C" void kernel_launch(void* const* d_in, const int* in_sizes, int n_in,
                              void* d_out, int out_size, void* d_ws, size_t ws_size,
                              hipStream_t stream) {
    const float* x    = (const float*)d_in[0];
    const int*   ei   = (const int*)d_in[1];
    const float* W1   = (const float*)d_in[2];
    const float* b1   = (const float*)d_in[3];
    const float* W2   = (const float*)d_in[4];
    const float* b2   = (const float*)d_in[5];
    const float* Wout = (const float*)d_in[6];
    const float* bout = (const float*)d_in[7];
    float* out = (float*)d_out;

    const int* src = ei;            // edge_index[0]
    const int* dst = ei + N_EDGES;  // edge_index[1]

    // workspace (~106.6 MB)
    char* ws = (char*)d_ws;
    size_t o = 0;
    auto alloc = [&](size_t bytes) { size_t p = o; o = (o + bytes + 255) & ~(size_t)255; return p; };
    int*   cnt    = (int*)(ws + alloc((size_t)N_NODES * 4));
    float* dinv   = (float*)(ws + alloc((size_t)N_NODES * 4));
    int*   rowptr = (int*)(ws + alloc((size_t)(N_NODES + 1) * 4));
    int*   cursor = (int*)(ws + alloc((size_t)N_NODES * 4));
    int*   srcs   = (int*)(ws + alloc((size_t)N_EDGES * 4));
    u16*   xb     = (u16*)(ws + alloc((size_t)N_NODES * F_IN * 2));   // 12.8 MB
    u16*   aggxb  = (u16*)(ws + alloc((size_t)N_NODES * F_IN * 2));   // 12.8 MB
    u16*   h1b    = (u16*)(ws + alloc((size_t)N_NODES * H_DIM * 2));  // 25.6 MB
    u16*   agghb  = (u16*)(ws + alloc((size_t)N_NODES * H_DIM * 2));  // 25.6 MB
    u16*   h2b    = (u16*)(ws + alloc((size_t)N_NODES * H_DIM * 2));  // 25.6 MB
    u16*   W1b    = (u16*)(ws + alloc((size_t)H_DIM * F_IN * 2));
    u16*   W2b    = (u16*)(ws + alloc((size_t)H_DIM * H_DIM * 2));
    u16*   Woutb  = (u16*)(ws + alloc((size_t)C_OUT * H_DIM * 2));

    // CSR build
    hipMemsetAsync(cnt, 0, (size_t)N_NODES * 4, stream);
    count_k<<<(N_EDGES + 255) / 256, 256, 0, stream>>>(dst, cnt, N_EDGES);
    dinv_k<<<(N_NODES + 255) / 256, 256, 0, stream>>>(cnt, dinv, N_NODES);
    scan_k<<<1, SCAN_T, 0, stream>>>(cnt, rowptr, cursor);
    bucket_k<<<(N_EDGES + 255) / 256, 256, 0, stream>>>(src, dst, cursor, srcs, N_EDGES);

    // fp32 -> bf16 conversions
    cvt_k<<<(N_NODES * F_IN / 4 + 255) / 256, 256, 0, stream>>>((const float4*)x, (uint2*)xb, N_NODES * F_IN / 4);
    cvt_k<<<(H_DIM * F_IN / 4 + 255) / 256, 256, 0, stream>>>((const float4*)W1, (uint2*)W1b, H_DIM * F_IN / 4);
    cvt_k<<<(H_DIM * H_DIM / 4 + 255) / 256, 256, 0, stream>>>((const float4*)W2, (uint2*)W2b, H_DIM * H_DIM / 4);
    cvt_k<<<(C_OUT * H_DIM / 4 + 255) / 256, 256, 0, stream>>>((const float4*)Wout, (uint2*)Woutb, C_OUT * H_DIM / 4);

    const int gemm_grid = (N_NODES + 63) / 64;   // 782

    // layer 1 (aggregate-first): aggx = A*xb ; h1 = relu(aggx@W1^T + b1)
    gather1_k<<<(N_NODES + 3) / 4, 256, 0, stream>>>((const u32*)xb, rowptr, srcs, dinv, (u32*)aggxb);
    mfma_gemm_k<F_IN, 16, true, false><<<gemm_grid, 256, 0, stream>>>(aggxb, W1b, b1, h1b, H_DIM - 1, H_DIM);

    // layer 2: aggh = A*h1 ; h2 = aggh@W2^T + b2
    gather2_k<<<(N_NODES + 3) / 4, 256, 0, stream>>>((const uint2*)h1b, rowptr, srcs, dinv, (uint2*)agghb);
    mfma_gemm_k<H_DIM, 16, false, false><<<gemm_grid, 256, 0, stream>>>(agghb, W2b, b2, h2b, H_DIM - 1, H_DIM);

    // head: out = h2@Wout^T + bout (fp32 out), 3 n-tiles (48 cols, stores guarded to 40)
    mfma_gemm_k<H_DIM, 3, false, true><<<gemm_grid, 256, 0, stream>>>(h2b, Woutb, bout, out, C_OUT - 1, C_OUT);
}

// Round 5
// 585.534 us; speedup vs baseline: 1.4448x; 1.0872x over previous
//
#include <hip/hip_runtime.h>

#define N_NODES 50000
#define N_EDGES 800000
#define F_IN    128
#define H_DIM   256
#define C_OUT   40

typedef unsigned short u16;
typedef unsigned int   u32;
typedef short bf16x8 __attribute__((ext_vector_type(8)));
typedef float f32x4  __attribute__((ext_vector_type(4)));

__device__ inline float bfbits2f(u16 u) { return __uint_as_float(((u32)u) << 16); }
__device__ inline u16 f2bf(float f) {
    u32 u = __float_as_uint(f);
    u += 0x7fffu + ((u >> 16) & 1u);   // RNE
    return (u16)(u >> 16);
}
__device__ inline u32 pack2(float a, float b) {
    return (u32)f2bf(a) | ((u32)f2bf(b) << 16);
}

// ---- in-degree count over dst ----
__global__ __launch_bounds__(256) void count_k(const int* __restrict__ dst, int* __restrict__ cnt, int E) {
    int i = blockIdx.x * 256 + threadIdx.x;
    if (i < E) atomicAdd(&cnt[dst[i]], 1);
}

// ---- single-block: dinv + exclusive scan (rowptr, cursor) ----
#define SCAN_T 1024
#define SCAN_CHUNK ((N_NODES + SCAN_T - 1) / SCAN_T)   // 49
__global__ __launch_bounds__(SCAN_T) void scan_k(const int* __restrict__ cnt,
                                                 float* __restrict__ dinv,
                                                 int* __restrict__ rowptr,
                                                 int* __restrict__ cursor) {
    __shared__ int part[SCAN_T];
    const int t = threadIdx.x;
    const int lo = t * SCAN_CHUNK;
    const int hi = min(lo + SCAN_CHUNK, N_NODES);
    int s = 0;
    for (int i = lo; i < hi; i++) {
        int c = cnt[i];
        dinv[i] = rsqrtf((float)c + 1.0f);
        s += c;
    }
    part[t] = s;
    __syncthreads();
    for (int off = 1; off < SCAN_T; off <<= 1) {
        int v = (t >= off) ? part[t - off] : 0;
        __syncthreads();
        part[t] += v;
        __syncthreads();
    }
    int run = part[t] - s;
    if (t == 0) rowptr[0] = 0;
    for (int i = lo; i < hi; i++) {
        cursor[i] = run;
        run += cnt[i];
        rowptr[i + 1] = run;
    }
}

// ---- bucket edges by dst; store {src, norm} packed per edge ----
__global__ __launch_bounds__(256) void bucket_k(const int* __restrict__ src, const int* __restrict__ dst,
                                                const float* __restrict__ dinv,
                                                int* __restrict__ cursor, uint2* __restrict__ edata, int E) {
    int i = blockIdx.x * 256 + threadIdx.x;
    if (i < E) {
        const int s = src[i], d = dst[i];
        int pos = atomicAdd(&cursor[d], 1);
        uint2 ed;
        ed.x = (u32)s;
        ed.y = __float_as_uint(dinv[s] * dinv[d]);
        edata[pos] = ed;
    }
}

// ---- fused fp32 -> bf16 convert for x, W1, W2, Wout ----
#define CVT_X  (N_NODES * F_IN / 4)          // 1,600,000 float4 groups
#define CVT_W1 (H_DIM * F_IN / 4)            // 8192
#define CVT_W2 (H_DIM * H_DIM / 4)           // 16384
#define CVT_WO (C_OUT * H_DIM / 4)           // 2560
#define CVT_TOT (CVT_X + CVT_W1 + CVT_W2 + CVT_WO)
__global__ __launch_bounds__(256) void cvt_all_k(const float4* __restrict__ x, uint2* __restrict__ xb,
                                                 const float4* __restrict__ W1, uint2* __restrict__ W1b,
                                                 const float4* __restrict__ W2, uint2* __restrict__ W2b,
                                                 const float4* __restrict__ Wo, uint2* __restrict__ Wob) {
    int i = blockIdx.x * 256 + threadIdx.x;
    const float4* s; uint2* d; int j;
    if (i < CVT_X) { s = x; d = xb; j = i; }
    else if (i < CVT_X + CVT_W1) { s = W1; d = W1b; j = i - CVT_X; }
    else if (i < CVT_X + CVT_W1 + CVT_W2) { s = W2; d = W2b; j = i - CVT_X - CVT_W1; }
    else if (i < CVT_TOT) { s = Wo; d = Wob; j = i - CVT_X - CVT_W1 - CVT_W2; }
    else return;
    float4 v = s[j];
    uint2 o; o.x = pack2(v.x, v.y); o.y = pack2(v.z, v.w);
    d[j] = o;
}

// ---- gather width-128 bf16 (xb -> aggx), one wave per node, u32(2 bf16)/lane ----
__global__ __launch_bounds__(256) void gather1_k(const u32* __restrict__ xb,     // [N][64] u32
                                                 const int* __restrict__ rowptr,
                                                 const uint2* __restrict__ edata,
                                                 const float* __restrict__ dinv,
                                                 u32* __restrict__ aggx) {
    const int node = blockIdx.x * 4 + (threadIdx.x >> 6);
    const int lane = threadIdx.x & 63;
    if (node >= N_NODES) return;
    const int beg = rowptr[node], end = rowptr[node + 1];
    const float dd = dinv[node];
    const u32 vs = xb[(size_t)node * 64 + lane];
    float a0 = dd * dd * bfbits2f((u16)vs);
    float a1 = dd * dd * bfbits2f((u16)(vs >> 16));
    int e = beg;
    for (; e + 1 < end; e += 2) {
        const uint2 e0 = edata[e];
        const uint2 e1 = edata[e + 1];
        const u32 v0 = xb[(size_t)e0.x * 64 + lane];
        const u32 v1 = xb[(size_t)e1.x * 64 + lane];
        const float n0 = __uint_as_float(e0.y);
        const float n1 = __uint_as_float(e1.y);
        a0 += n0 * bfbits2f((u16)v0);
        a1 += n0 * bfbits2f((u16)(v0 >> 16));
        a0 += n1 * bfbits2f((u16)v1);
        a1 += n1 * bfbits2f((u16)(v1 >> 16));
    }
    if (e < end) {
        const uint2 e0 = edata[e];
        const u32 v0 = xb[(size_t)e0.x * 64 + lane];
        const float n0 = __uint_as_float(e0.y);
        a0 += n0 * bfbits2f((u16)v0);
        a1 += n0 * bfbits2f((u16)(v0 >> 16));
    }
    aggx[(size_t)node * 64 + lane] = pack2(a0, a1);
}

// ---- gather width-256 bf16 (h1b -> aggh), one wave per node, uint2(4 bf16)/lane ----
__global__ __launch_bounds__(256) void gather2_k(const uint2* __restrict__ hb,   // [N][64] uint2
                                                 const int* __restrict__ rowptr,
                                                 const uint2* __restrict__ edata,
                                                 const float* __restrict__ dinv,
                                                 uint2* __restrict__ agg) {
    const int node = blockIdx.x * 4 + (threadIdx.x >> 6);
    const int lane = threadIdx.x & 63;
    if (node >= N_NODES) return;
    const int beg = rowptr[node], end = rowptr[node + 1];
    const float dd = dinv[node];
    const uint2 vs = hb[(size_t)node * 64 + lane];
    const float ss = dd * dd;
    float a0 = ss * bfbits2f((u16)vs.x);
    float a1 = ss * bfbits2f((u16)(vs.x >> 16));
    float a2 = ss * bfbits2f((u16)vs.y);
    float a3 = ss * bfbits2f((u16)(vs.y >> 16));
    int e = beg;
    for (; e + 1 < end; e += 2) {
        const uint2 e0 = edata[e];
        const uint2 e1 = edata[e + 1];
        const uint2 v0 = hb[(size_t)e0.x * 64 + lane];
        const uint2 v1 = hb[(size_t)e1.x * 64 + lane];
        const float n0 = __uint_as_float(e0.y);
        const float n1 = __uint_as_float(e1.y);
        a0 += n0 * bfbits2f((u16)v0.x); a1 += n0 * bfbits2f((u16)(v0.x >> 16));
        a2 += n0 * bfbits2f((u16)v0.y); a3 += n0 * bfbits2f((u16)(v0.y >> 16));
        a0 += n1 * bfbits2f((u16)v1.x); a1 += n1 * bfbits2f((u16)(v1.x >> 16));
        a2 += n1 * bfbits2f((u16)v1.y); a3 += n1 * bfbits2f((u16)(v1.y >> 16));
    }
    if (e < end) {
        const uint2 e0 = edata[e];
        const uint2 v0 = hb[(size_t)e0.x * 64 + lane];
        const float n0 = __uint_as_float(e0.y);
        a0 += n0 * bfbits2f((u16)v0.x); a1 += n0 * bfbits2f((u16)(v0.x >> 16));
        a2 += n0 * bfbits2f((u16)v0.y); a3 += n0 * bfbits2f((u16)(v0.y >> 16));
    }
    uint2 o; o.x = pack2(a0, a1); o.y = pack2(a2, a3);
    agg[(size_t)node * 64 + lane] = o;
}

// ---- MFMA GEMM: Y[m, n] = act( sum_k X[m,k]*W[n,k] + b[n] ) ----
template<int K, int NT, bool RELU, bool OUT_F32>
__global__ __launch_bounds__(256) void mfma_gemm_k(const u16* __restrict__ X,
                                                   const u16* __restrict__ W,
                                                   const float* __restrict__ bias,
                                                   void* __restrict__ Y,
                                                   int wrow_max, int ocols) {
    const int wave = threadIdx.x >> 6;
    const int lane = threadIdx.x & 63;
    const int quad = lane >> 4;
    const int nn = lane & 15;
    const int m0 = blockIdx.x * 64 + wave * 16;

    int arow = m0 + nn;
    if (arow > N_NODES - 1) arow = N_NODES - 1;
    const u16* aptr = X + (size_t)arow * K + quad * 8;

    f32x4 acc[NT];
#pragma unroll
    for (int nt = 0; nt < NT; nt++) acc[nt] = (f32x4){0.f, 0.f, 0.f, 0.f};

#pragma unroll
    for (int kk = 0; kk < K; kk += 32) {
        bf16x8 af = *(const bf16x8*)(aptr + kk);
#pragma unroll
        for (int nt = 0; nt < NT; nt++) {
            int wr = nt * 16 + nn;
            if (wr > wrow_max) wr = wrow_max;
            bf16x8 bfr = *(const bf16x8*)(W + (size_t)wr * K + kk + quad * 8);
            acc[nt] = __builtin_amdgcn_mfma_f32_16x16x32_bf16(af, bfr, acc[nt], 0, 0, 0);
        }
    }

#pragma unroll
    for (int nt = 0; nt < NT; nt++) {
        const int col = nt * 16 + nn;
        if (col >= ocols) continue;
        const float bb = bias[col];
#pragma unroll
        for (int r = 0; r < 4; r++) {
            const int row = m0 + quad * 4 + r;
            if (row >= N_NODES) continue;
            float v = acc[nt][r] + bb;
            if (RELU) v = fmaxf(v, 0.f);
            if (OUT_F32) ((float*)Y)[(size_t)row * ocols + col] = v;
            else         ((u16*)Y)[(size_t)row * ocols + col] = f2bf(v);
        }
    }
}

extern "C" void kernel_launch(void* const* d_in, const int* in_sizes, int n_in,
                              void* d_out, int out_size, void* d_ws, size_t ws_size,
                              hipStream_t stream) {
    const float* x    = (const float*)d_in[0];
    const int*   ei   = (const int*)d_in[1];
    const float* W1   = (const float*)d_in[2];
    const float* b1   = (const float*)d_in[3];
    const float* W2   = (const float*)d_in[4];
    const float* b2   = (const float*)d_in[5];
    const float* Wout = (const float*)d_in[6];
    const float* bout = (const float*)d_in[7];
    float* out = (float*)d_out;

    const int* src = ei;            // edge_index[0]
    const int* dst = ei + N_EDGES;  // edge_index[1]

    // workspace (~110 MB)
    char* ws = (char*)d_ws;
    size_t o = 0;
    auto alloc = [&](size_t bytes) { size_t p = o; o = (o + bytes + 255) & ~(size_t)255; return p; };
    int*   cnt    = (int*)(ws + alloc((size_t)N_NODES * 4));
    float* dinv   = (float*)(ws + alloc((size_t)N_NODES * 4));
    int*   rowptr = (int*)(ws + alloc((size_t)(N_NODES + 1) * 4));
    int*   cursor = (int*)(ws + alloc((size_t)N_NODES * 4));
    uint2* edata  = (uint2*)(ws + alloc((size_t)N_EDGES * 8));         // 6.4 MB
    u16*   xb     = (u16*)(ws + alloc((size_t)N_NODES * F_IN * 2));    // 12.8 MB
    u16*   aggxb  = (u16*)(ws + alloc((size_t)N_NODES * F_IN * 2));    // 12.8 MB
    u16*   h1b    = (u16*)(ws + alloc((size_t)N_NODES * H_DIM * 2));   // 25.6 MB
    u16*   agghb  = (u16*)(ws + alloc((size_t)N_NODES * H_DIM * 2));   // 25.6 MB
    u16*   h2b    = (u16*)(ws + alloc((size_t)N_NODES * H_DIM * 2));   // 25.6 MB
    u16*   W1b    = (u16*)(ws + alloc((size_t)H_DIM * F_IN * 2));
    u16*   W2b    = (u16*)(ws + alloc((size_t)H_DIM * H_DIM * 2));
    u16*   Woutb  = (u16*)(ws + alloc((size_t)C_OUT * H_DIM * 2));

    // CSR build
    hipMemsetAsync(cnt, 0, (size_t)N_NODES * 4, stream);
    count_k<<<(N_EDGES + 255) / 256, 256, 0, stream>>>(dst, cnt, N_EDGES);
    scan_k<<<1, SCAN_T, 0, stream>>>(cnt, dinv, rowptr, cursor);
    bucket_k<<<(N_EDGES + 255) / 256, 256, 0, stream>>>(src, dst, dinv, cursor, edata, N_EDGES);

    // fp32 -> bf16 conversions (single fused kernel)
    cvt_all_k<<<(CVT_TOT + 255) / 256, 256, 0, stream>>>(
        (const float4*)x, (uint2*)xb, (const float4*)W1, (uint2*)W1b,
        (const float4*)W2, (uint2*)W2b, (const float4*)Wout, (uint2*)Woutb);

    const int gemm_grid = (N_NODES + 63) / 64;   // 782

    // layer 1 (aggregate-first): aggx = A*xb ; h1 = relu(aggx@W1^T + b1)
    gather1_k<<<(N_NODES + 3) / 4, 256, 0, stream>>>((const u32*)xb, rowptr, edata, dinv, (u32*)aggxb);
    mfma_gemm_k<F_IN, 16, true, false><<<gemm_grid, 256, 0, stream>>>(aggxb, W1b, b1, h1b, H_DIM - 1, H_DIM);

    // layer 2: aggh = A*h1 ; h2 = aggh@W2^T + b2
    gather2_k<<<(N_NODES + 3) / 4, 256, 0, stream>>>((const uint2*)h1b, rowptr, edata, dinv, (uint2*)agghb);
    mfma_gemm_k<H_DIM, 16, false, false><<<gemm_grid, 256, 0, stream>>>(agghb, W2b, b2, h2b, H_DIM - 1, H_DIM);

    // head: out = h2@Wout^T + bout (fp32 out), 3 n-tiles (48 cols, stores guarded to 40)
    mfma_gemm_k<H_DIM, 3, false, true><<<gemm_grid, 256, 0, stream>>>(h2b, Woutb, bout, out, C_OUT - 1, C_OUT);
}

// Round 6
// 437.152 us; speedup vs baseline: 1.9352x; 1.3394x over previous
//
#include <hip/hip_runtime.h>

#define N_NODES 50000
#define N_EDGES 800000
#define F_IN    128
#define H_DIM   256
#define C_OUT   40
#define NB_SCAN ((N_NODES + 255) / 256)   // 196

typedef unsigned short u16;
typedef unsigned int   u32;
typedef short bf16x8 __attribute__((ext_vector_type(8)));
typedef float f32x4  __attribute__((ext_vector_type(4)));

__device__ inline float bfbits2f(u16 u) { return __uint_as_float(((u32)u) << 16); }
__device__ inline u16 f2bf(float f) {
    u32 u = __float_as_uint(f);
    u += 0x7fffu + ((u >> 16) & 1u);   // RNE
    return (u16)(u >> 16);
}
__device__ inline u32 pack2(float a, float b) {
    return (u32)f2bf(a) | ((u32)f2bf(b) << 16);
}

// ---- in-degree count over dst ----
__global__ __launch_bounds__(256) void count_k(const int* __restrict__ dst, int* __restrict__ cnt, int E) {
    int i = blockIdx.x * 256 + threadIdx.x;
    if (i < E) atomicAdd(&cnt[dst[i]], 1);
}

// ---- scan phase 1: coalesced dinv + per-block exclusive scan + block sums ----
__global__ __launch_bounds__(256) void scan1_k(const int* __restrict__ cnt,
                                               float* __restrict__ dinv,
                                               int* __restrict__ rowptr,   // excl prefix (block-local)
                                               int* __restrict__ bsum) {
    __shared__ int sh[256];
    const int t = threadIdx.x;
    const int i = blockIdx.x * 256 + t;
    int c = (i < N_NODES) ? cnt[i] : 0;
    if (i < N_NODES) dinv[i] = rsqrtf((float)c + 1.0f);
    sh[t] = c;
    __syncthreads();
    for (int off = 1; off < 256; off <<= 1) {
        int v = (t >= off) ? sh[t - off] : 0;
        __syncthreads();
        sh[t] += v;
        __syncthreads();
    }
    if (i < N_NODES) rowptr[i] = sh[t] - c;            // exclusive, block-local
    if (t == 255) bsum[blockIdx.x] = sh[255];
}

// ---- scan phase 2: scan block sums (single small block) ----
__global__ __launch_bounds__(256) void scan2_k(const int* __restrict__ bsum,
                                               int* __restrict__ boff,
                                               int* __restrict__ rowptr) {
    __shared__ int sh[256];
    const int t = threadIdx.x;
    int c = (t < NB_SCAN) ? bsum[t] : 0;
    sh[t] = c;
    __syncthreads();
    for (int off = 1; off < 256; off <<= 1) {
        int v = (t >= off) ? sh[t - off] : 0;
        __syncthreads();
        sh[t] += v;
        __syncthreads();
    }
    if (t < NB_SCAN) boff[t] = sh[t] - c;
    if (t == 0) rowptr[N_NODES] = N_EDGES;
}

// ---- scan phase 3: add block offsets, init cursor ----
__global__ __launch_bounds__(256) void scan3_k(int* __restrict__ rowptr,
                                               int* __restrict__ cursor,
                                               const int* __restrict__ boff) {
    const int i = blockIdx.x * 256 + threadIdx.x;
    if (i < N_NODES) {
        int r = rowptr[i] + boff[blockIdx.x];
        rowptr[i] = r;
        cursor[i] = r;
    }
}

// ---- bucket edges by dst; store {src, norm} packed per edge ----
__global__ __launch_bounds__(256) void bucket_k(const int* __restrict__ src, const int* __restrict__ dst,
                                                const float* __restrict__ dinv,
                                                int* __restrict__ cursor, uint2* __restrict__ edata, int E) {
    int i = blockIdx.x * 256 + threadIdx.x;
    if (i < E) {
        const int s = src[i], d = dst[i];
        int pos = atomicAdd(&cursor[d], 1);
        uint2 ed;
        ed.x = (u32)s;
        ed.y = __float_as_uint(dinv[s] * dinv[d]);
        edata[pos] = ed;
    }
}

// ---- fused fp32 -> bf16 convert for x, W1, W2, Wout ----
#define CVT_X  (N_NODES * F_IN / 4)
#define CVT_W1 (H_DIM * F_IN / 4)
#define CVT_W2 (H_DIM * H_DIM / 4)
#define CVT_WO (C_OUT * H_DIM / 4)
#define CVT_TOT (CVT_X + CVT_W1 + CVT_W2 + CVT_WO)
__global__ __launch_bounds__(256) void cvt_all_k(const float4* __restrict__ x, uint2* __restrict__ xb,
                                                 const float4* __restrict__ W1, uint2* __restrict__ W1b,
                                                 const float4* __restrict__ W2, uint2* __restrict__ W2b,
                                                 const float4* __restrict__ Wo, uint2* __restrict__ Wob) {
    int i = blockIdx.x * 256 + threadIdx.x;
    const float4* s; uint2* d; int j;
    if (i < CVT_X) { s = x; d = xb; j = i; }
    else if (i < CVT_X + CVT_W1) { s = W1; d = W1b; j = i - CVT_X; }
    else if (i < CVT_X + CVT_W1 + CVT_W2) { s = W2; d = W2b; j = i - CVT_X - CVT_W1; }
    else if (i < CVT_TOT) { s = Wo; d = Wob; j = i - CVT_X - CVT_W1 - CVT_W2; }
    else return;
    float4 v = s[j];
    uint2 o; o.x = pack2(v.x, v.y); o.y = pack2(v.z, v.w);
    d[j] = o;
}

// ---- gather width-128 bf16 (xb -> aggx), one wave per node ----
__global__ __launch_bounds__(256) void gather1_k(const u32* __restrict__ xb,
                                                 const int* __restrict__ rowptr,
                                                 const uint2* __restrict__ edata,
                                                 const float* __restrict__ dinv,
                                                 u32* __restrict__ aggx) {
    const int node = blockIdx.x * 4 + (threadIdx.x >> 6);
    const int lane = threadIdx.x & 63;
    if (node >= N_NODES) return;
    const int beg = rowptr[node], end = rowptr[node + 1];
    const float dd = dinv[node];
    const u32 vs = xb[(size_t)node * 64 + lane];
    float a0 = dd * dd * bfbits2f((u16)vs);
    float a1 = dd * dd * bfbits2f((u16)(vs >> 16));
    int e = beg;
    for (; e + 1 < end; e += 2) {
        const uint2 e0 = edata[e];
        const uint2 e1 = edata[e + 1];
        const u32 v0 = xb[(size_t)e0.x * 64 + lane];
        const u32 v1 = xb[(size_t)e1.x * 64 + lane];
        const float n0 = __uint_as_float(e0.y);
        const float n1 = __uint_as_float(e1.y);
        a0 += n0 * bfbits2f((u16)v0);
        a1 += n0 * bfbits2f((u16)(v0 >> 16));
        a0 += n1 * bfbits2f((u16)v1);
        a1 += n1 * bfbits2f((u16)(v1 >> 16));
    }
    if (e < end) {
        const uint2 e0 = edata[e];
        const u32 v0 = xb[(size_t)e0.x * 64 + lane];
        const float n0 = __uint_as_float(e0.y);
        a0 += n0 * bfbits2f((u16)v0);
        a1 += n0 * bfbits2f((u16)(v0 >> 16));
    }
    aggx[(size_t)node * 64 + lane] = pack2(a0, a1);
}

// ---- gather width-256 bf16 (h1b -> aggh), one wave per node ----
__global__ __launch_bounds__(256) void gather2_k(const uint2* __restrict__ hb,
                                                 const int* __restrict__ rowptr,
                                                 const uint2* __restrict__ edata,
                                                 const float* __restrict__ dinv,
                                                 uint2* __restrict__ agg) {
    const int node = blockIdx.x * 4 + (threadIdx.x >> 6);
    const int lane = threadIdx.x & 63;
    if (node >= N_NODES) return;
    const int beg = rowptr[node], end = rowptr[node + 1];
    const float dd = dinv[node];
    const uint2 vs = hb[(size_t)node * 64 + lane];
    const float ss = dd * dd;
    float a0 = ss * bfbits2f((u16)vs.x);
    float a1 = ss * bfbits2f((u16)(vs.x >> 16));
    float a2 = ss * bfbits2f((u16)vs.y);
    float a3 = ss * bfbits2f((u16)(vs.y >> 16));
    int e = beg;
    for (; e + 1 < end; e += 2) {
        const uint2 e0 = edata[e];
        const uint2 e1 = edata[e + 1];
        const uint2 v0 = hb[(size_t)e0.x * 64 + lane];
        const uint2 v1 = hb[(size_t)e1.x * 64 + lane];
        const float n0 = __uint_as_float(e0.y);
        const float n1 = __uint_as_float(e1.y);
        a0 += n0 * bfbits2f((u16)v0.x); a1 += n0 * bfbits2f((u16)(v0.x >> 16));
        a2 += n0 * bfbits2f((u16)v0.y); a3 += n0 * bfbits2f((u16)(v0.y >> 16));
        a0 += n1 * bfbits2f((u16)v1.x); a1 += n1 * bfbits2f((u16)(v1.x >> 16));
        a2 += n1 * bfbits2f((u16)v1.y); a3 += n1 * bfbits2f((u16)(v1.y >> 16));
    }
    if (e < end) {
        const uint2 e0 = edata[e];
        const uint2 v0 = hb[(size_t)e0.x * 64 + lane];
        const float n0 = __uint_as_float(e0.y);
        a0 += n0 * bfbits2f((u16)v0.x); a1 += n0 * bfbits2f((u16)(v0.x >> 16));
        a2 += n0 * bfbits2f((u16)v0.y); a3 += n0 * bfbits2f((u16)(v0.y >> 16));
    }
    uint2 o; o.x = pack2(a0, a1); o.y = pack2(a2, a3);
    agg[(size_t)node * 64 + lane] = o;
}

// ---- MFMA GEMM: Y[m, n] = act( sum_k X[m,k]*W[n,k] + b[n] ) ----
template<int K, int NT, bool RELU, bool OUT_F32>
__global__ __launch_bounds__(256) void mfma_gemm_k(const u16* __restrict__ X,
                                                   const u16* __restrict__ W,
                                                   const float* __restrict__ bias,
                                                   void* __restrict__ Y,
                                                   int wrow_max, int ocols) {
    const int wave = threadIdx.x >> 6;
    const int lane = threadIdx.x & 63;
    const int quad = lane >> 4;
    const int nn = lane & 15;
    const int m0 = blockIdx.x * 64 + wave * 16;

    int arow = m0 + nn;
    if (arow > N_NODES - 1) arow = N_NODES - 1;
    const u16* aptr = X + (size_t)arow * K + quad * 8;

    f32x4 acc[NT];
#pragma unroll
    for (int nt = 0; nt < NT; nt++) acc[nt] = (f32x4){0.f, 0.f, 0.f, 0.f};

#pragma unroll
    for (int kk = 0; kk < K; kk += 32) {
        bf16x8 af = *(const bf16x8*)(aptr + kk);
#pragma unroll
        for (int nt = 0; nt < NT; nt++) {
            int wr = nt * 16 + nn;
            if (wr > wrow_max) wr = wrow_max;
            bf16x8 bfr = *(const bf16x8*)(W + (size_t)wr * K + kk + quad * 8);
            acc[nt] = __builtin_amdgcn_mfma_f32_16x16x32_bf16(af, bfr, acc[nt], 0, 0, 0);
        }
    }

#pragma unroll
    for (int nt = 0; nt < NT; nt++) {
        const int col = nt * 16 + nn;
        if (col >= ocols) continue;
        const float bb = bias[col];
#pragma unroll
        for (int r = 0; r < 4; r++) {
            const int row = m0 + quad * 4 + r;
            if (row >= N_NODES) continue;
            float v = acc[nt][r] + bb;
            if (RELU) v = fmaxf(v, 0.f);
            if (OUT_F32) ((float*)Y)[(size_t)row * ocols + col] = v;
            else         ((u16*)Y)[(size_t)row * ocols + col] = f2bf(v);
        }
    }
}

extern "C" void kernel_launch(void* const* d_in, const int* in_sizes, int n_in,
                              void* d_out, int out_size, void* d_ws, size_t ws_size,
                              hipStream_t stream) {
    const float* x    = (const float*)d_in[0];
    const int*   ei   = (const int*)d_in[1];
    const float* W1   = (const float*)d_in[2];
    const float* b1   = (const float*)d_in[3];
    const float* W2   = (const float*)d_in[4];
    const float* b2   = (const float*)d_in[5];
    const float* Wout = (const float*)d_in[6];
    const float* bout = (const float*)d_in[7];
    float* out = (float*)d_out;

    const int* src = ei;            // edge_index[0]
    const int* dst = ei + N_EDGES;  // edge_index[1]

    // workspace (~110 MB)
    char* ws = (char*)d_ws;
    size_t o = 0;
    auto alloc = [&](size_t bytes) { size_t p = o; o = (o + bytes + 255) & ~(size_t)255; return p; };
    int*   cnt    = (int*)(ws + alloc((size_t)N_NODES * 4));
    float* dinv   = (float*)(ws + alloc((size_t)N_NODES * 4));
    int*   rowptr = (int*)(ws + alloc((size_t)(N_NODES + 1) * 4));
    int*   cursor = (int*)(ws + alloc((size_t)N_NODES * 4));
    int*   bsum   = (int*)(ws + alloc((size_t)NB_SCAN * 4));
    int*   boff   = (int*)(ws + alloc((size_t)NB_SCAN * 4));
    uint2* edata  = (uint2*)(ws + alloc((size_t)N_EDGES * 8));
    u16*   xb     = (u16*)(ws + alloc((size_t)N_NODES * F_IN * 2));
    u16*   aggxb  = (u16*)(ws + alloc((size_t)N_NODES * F_IN * 2));
    u16*   h1b    = (u16*)(ws + alloc((size_t)N_NODES * H_DIM * 2));
    u16*   agghb  = (u16*)(ws + alloc((size_t)N_NODES * H_DIM * 2));
    u16*   h2b    = (u16*)(ws + alloc((size_t)N_NODES * H_DIM * 2));
    u16*   W1b    = (u16*)(ws + alloc((size_t)H_DIM * F_IN * 2));
    u16*   W2b    = (u16*)(ws + alloc((size_t)H_DIM * H_DIM * 2));
    u16*   Woutb  = (u16*)(ws + alloc((size_t)C_OUT * H_DIM * 2));

    // CSR build (multi-block scan)
    hipMemsetAsync(cnt, 0, (size_t)N_NODES * 4, stream);
    count_k<<<(N_EDGES + 255) / 256, 256, 0, stream>>>(dst, cnt, N_EDGES);
    scan1_k<<<NB_SCAN, 256, 0, stream>>>(cnt, dinv, rowptr, bsum);
    scan2_k<<<1, 256, 0, stream>>>(bsum, boff, rowptr);
    scan3_k<<<NB_SCAN, 256, 0, stream>>>(rowptr, cursor, boff);
    bucket_k<<<(N_EDGES + 255) / 256, 256, 0, stream>>>(src, dst, dinv, cursor, edata, N_EDGES);

    // fp32 -> bf16 conversions (single fused kernel)
    cvt_all_k<<<(CVT_TOT + 255) / 256, 256, 0, stream>>>(
        (const float4*)x, (uint2*)xb, (const float4*)W1, (uint2*)W1b,
        (const float4*)W2, (uint2*)W2b, (const float4*)Wout, (uint2*)Woutb);

    const int gemm_grid = (N_NODES + 63) / 64;   // 782

    // layer 1 (aggregate-first): aggx = A*xb ; h1 = relu(aggx@W1^T + b1)
    gather1_k<<<(N_NODES + 3) / 4, 256, 0, stream>>>((const u32*)xb, rowptr, edata, dinv, (u32*)aggxb);
    mfma_gemm_k<F_IN, 16, true, false><<<gemm_grid, 256, 0, stream>>>(aggxb, W1b, b1, h1b, H_DIM - 1, H_DIM);

    // layer 2: aggh = A*h1 ; h2 = aggh@W2^T + b2
    gather2_k<<<(N_NODES + 3) / 4, 256, 0, stream>>>((const uint2*)h1b, rowptr, edata, dinv, (uint2*)agghb);
    mfma_gemm_k<H_DIM, 16, false, false><<<gemm_grid, 256, 0, stream>>>(agghb, W2b, b2, h2b, H_DIM - 1, H_DIM);

    // head: out = h2@Wout^T + bout (fp32 out)
    mfma_gemm_k<H_DIM, 3, false, true><<<gemm_grid, 256, 0, stream>>>(h2b, Woutb, bout, out, C_OUT - 1, C_OUT);
}

// Round 7
// 359.573 us; speedup vs baseline: 2.3527x; 1.2158x over previous
//
#include <hip/hip_runtime.h>

#define N_NODES 50000
#define N_EDGES 800000
#define F_IN    128
#define H_DIM   256
#define C_OUT   40
#define NB_SCAN ((N_NODES + 255) / 256)   // 196
#define MT_TOT  (N_NODES / 16)            // 3125 m-tiles (50000 = 16*3125)

typedef unsigned short u16;
typedef unsigned int   u32;
typedef short bf16x8 __attribute__((ext_vector_type(8)));
typedef float f32x4  __attribute__((ext_vector_type(4)));

__device__ inline float bfbits2f(u16 u) { return __uint_as_float(((u32)u) << 16); }
__device__ inline u16 f2bf(float f) {
    u32 u = __float_as_uint(f);
    u += 0x7fffu + ((u >> 16) & 1u);   // RNE
    return (u16)(u >> 16);
}
__device__ inline u32 pack2(float a, float b) {
    return (u32)f2bf(a) | ((u32)f2bf(b) << 16);
}

// ---- in-degree count over dst ----
__global__ __launch_bounds__(256) void count_k(const int* __restrict__ dst, int* __restrict__ cnt, int E) {
    int i = blockIdx.x * 256 + threadIdx.x;
    if (i < E) atomicAdd(&cnt[dst[i]], 1);
}

// ---- scan phase 1 ----
__global__ __launch_bounds__(256) void scan1_k(const int* __restrict__ cnt,
                                               float* __restrict__ dinv,
                                               int* __restrict__ rowptr,
                                               int* __restrict__ bsum) {
    __shared__ int sh[256];
    const int t = threadIdx.x;
    const int i = blockIdx.x * 256 + t;
    int c = (i < N_NODES) ? cnt[i] : 0;
    if (i < N_NODES) dinv[i] = rsqrtf((float)c + 1.0f);
    sh[t] = c;
    __syncthreads();
    for (int off = 1; off < 256; off <<= 1) {
        int v = (t >= off) ? sh[t - off] : 0;
        __syncthreads();
        sh[t] += v;
        __syncthreads();
    }
    if (i < N_NODES) rowptr[i] = sh[t] - c;
    if (t == 255) bsum[blockIdx.x] = sh[255];
}

// ---- scan phase 2 ----
__global__ __launch_bounds__(256) void scan2_k(const int* __restrict__ bsum,
                                               int* __restrict__ boff,
                                               int* __restrict__ rowptr) {
    __shared__ int sh[256];
    const int t = threadIdx.x;
    int c = (t < NB_SCAN) ? bsum[t] : 0;
    sh[t] = c;
    __syncthreads();
    for (int off = 1; off < 256; off <<= 1) {
        int v = (t >= off) ? sh[t - off] : 0;
        __syncthreads();
        sh[t] += v;
        __syncthreads();
    }
    if (t < NB_SCAN) boff[t] = sh[t] - c;
    if (t == 0) rowptr[N_NODES] = N_EDGES;
}

// ---- scan phase 3 ----
__global__ __launch_bounds__(256) void scan3_k(int* __restrict__ rowptr,
                                               int* __restrict__ cursor,
                                               const int* __restrict__ boff) {
    const int i = blockIdx.x * 256 + threadIdx.x;
    if (i < N_NODES) {
        int r = rowptr[i] + boff[blockIdx.x];
        rowptr[i] = r;
        cursor[i] = r;
    }
}

// ---- bucket edges by dst; store {src, norm} packed per edge ----
__global__ __launch_bounds__(256) void bucket_k(const int* __restrict__ src, const int* __restrict__ dst,
                                                const float* __restrict__ dinv,
                                                int* __restrict__ cursor, uint2* __restrict__ edata, int E) {
    int i = blockIdx.x * 256 + threadIdx.x;
    if (i < E) {
        const int s = src[i], d = dst[i];
        int pos = atomicAdd(&cursor[d], 1);
        uint2 ed;
        ed.x = (u32)s;
        ed.y = __float_as_uint(dinv[s] * dinv[d]);
        edata[pos] = ed;
    }
}

// ---- fused fp32 -> bf16 convert ----
#define CVT_X  (N_NODES * F_IN / 4)
#define CVT_W1 (H_DIM * F_IN / 4)
#define CVT_W2 (H_DIM * H_DIM / 4)
#define CVT_WO (C_OUT * H_DIM / 4)
#define CVT_TOT (CVT_X + CVT_W1 + CVT_W2 + CVT_WO)
__global__ __launch_bounds__(256) void cvt_all_k(const float4* __restrict__ x, uint2* __restrict__ xb,
                                                 const float4* __restrict__ W1, uint2* __restrict__ W1b,
                                                 const float4* __restrict__ W2, uint2* __restrict__ W2b,
                                                 const float4* __restrict__ Wo, uint2* __restrict__ Wob) {
    int i = blockIdx.x * 256 + threadIdx.x;
    const float4* s; uint2* d; int j;
    if (i < CVT_X) { s = x; d = xb; j = i; }
    else if (i < CVT_X + CVT_W1) { s = W1; d = W1b; j = i - CVT_X; }
    else if (i < CVT_X + CVT_W1 + CVT_W2) { s = W2; d = W2b; j = i - CVT_X - CVT_W1; }
    else if (i < CVT_TOT) { s = Wo; d = Wob; j = i - CVT_X - CVT_W1 - CVT_W2; }
    else return;
    float4 v = s[j];
    uint2 o; o.x = pack2(v.x, v.y); o.y = pack2(v.z, v.w);
    d[j] = o;
}

// ---- gather width-128 bf16 ----
__global__ __launch_bounds__(256) void gather1_k(const u32* __restrict__ xb,
                                                 const int* __restrict__ rowptr,
                                                 const uint2* __restrict__ edata,
                                                 const float* __restrict__ dinv,
                                                 u32* __restrict__ aggx) {
    const int node = blockIdx.x * 4 + (threadIdx.x >> 6);
    const int lane = threadIdx.x & 63;
    if (node >= N_NODES) return;
    const int beg = rowptr[node], end = rowptr[node + 1];
    const float dd = dinv[node];
    const u32 vs = xb[(size_t)node * 64 + lane];
    float a0 = dd * dd * bfbits2f((u16)vs);
    float a1 = dd * dd * bfbits2f((u16)(vs >> 16));
    int e = beg;
    for (; e + 1 < end; e += 2) {
        const uint2 e0 = edata[e];
        const uint2 e1 = edata[e + 1];
        const u32 v0 = xb[(size_t)e0.x * 64 + lane];
        const u32 v1 = xb[(size_t)e1.x * 64 + lane];
        const float n0 = __uint_as_float(e0.y);
        const float n1 = __uint_as_float(e1.y);
        a0 += n0 * bfbits2f((u16)v0);
        a1 += n0 * bfbits2f((u16)(v0 >> 16));
        a0 += n1 * bfbits2f((u16)v1);
        a1 += n1 * bfbits2f((u16)(v1 >> 16));
    }
    if (e < end) {
        const uint2 e0 = edata[e];
        const u32 v0 = xb[(size_t)e0.x * 64 + lane];
        const float n0 = __uint_as_float(e0.y);
        a0 += n0 * bfbits2f((u16)v0);
        a1 += n0 * bfbits2f((u16)(v0 >> 16));
    }
    aggx[(size_t)node * 64 + lane] = pack2(a0, a1);
}

// ---- gather width-256 bf16 ----
__global__ __launch_bounds__(256) void gather2_k(const uint2* __restrict__ hb,
                                                 const int* __restrict__ rowptr,
                                                 const uint2* __restrict__ edata,
                                                 const float* __restrict__ dinv,
                                                 uint2* __restrict__ agg) {
    const int node = blockIdx.x * 4 + (threadIdx.x >> 6);
    const int lane = threadIdx.x & 63;
    if (node >= N_NODES) return;
    const int beg = rowptr[node], end = rowptr[node + 1];
    const float dd = dinv[node];
    const uint2 vs = hb[(size_t)node * 64 + lane];
    const float ss = dd * dd;
    float a0 = ss * bfbits2f((u16)vs.x);
    float a1 = ss * bfbits2f((u16)(vs.x >> 16));
    float a2 = ss * bfbits2f((u16)vs.y);
    float a3 = ss * bfbits2f((u16)(vs.y >> 16));
    int e = beg;
    for (; e + 1 < end; e += 2) {
        const uint2 e0 = edata[e];
        const uint2 e1 = edata[e + 1];
        const uint2 v0 = hb[(size_t)e0.x * 64 + lane];
        const uint2 v1 = hb[(size_t)e1.x * 64 + lane];
        const float n0 = __uint_as_float(e0.y);
        const float n1 = __uint_as_float(e1.y);
        a0 += n0 * bfbits2f((u16)v0.x); a1 += n0 * bfbits2f((u16)(v0.x >> 16));
        a2 += n0 * bfbits2f((u16)v0.y); a3 += n0 * bfbits2f((u16)(v0.y >> 16));
        a0 += n1 * bfbits2f((u16)v1.x); a1 += n1 * bfbits2f((u16)(v1.x >> 16));
        a2 += n1 * bfbits2f((u16)v1.y); a3 += n1 * bfbits2f((u16)(v1.y >> 16));
    }
    if (e < end) {
        const uint2 e0 = edata[e];
        const uint2 v0 = hb[(size_t)e0.x * 64 + lane];
        const float n0 = __uint_as_float(e0.y);
        a0 += n0 * bfbits2f((u16)v0.x); a1 += n0 * bfbits2f((u16)(v0.x >> 16));
        a2 += n0 * bfbits2f((u16)v0.y); a3 += n0 * bfbits2f((u16)(v0.y >> 16));
    }
    uint2 o; o.x = pack2(a0, a1); o.y = pack2(a2, a3);
    agg[(size_t)node * 64 + lane] = o;
}

// ---- B-stationary MFMA GEMM ----
// Wave owns NTW n-tiles; all B-fragments held in VGPRs for the whole kernel.
// Block = 4 waves -> covers blockIdx.y * (4*NTW*16) .. + 4*NTW*16 output cols.
// Grid-strides over m-tiles with double-buffered A-loads.
template<int K, int NTW, bool RELU, bool OUT_F32>
__global__ __launch_bounds__(256) void bgemm_k(const u16* __restrict__ X,
                                               const u16* __restrict__ W,
                                               const float* __restrict__ bias,
                                               void* __restrict__ Y,
                                               int wrow_max, int ocols) {
    constexpr int KF = K / 32;
    const int wave = threadIdx.x >> 6;
    const int lane = threadIdx.x & 63;
    const int quad = lane >> 4;
    const int nn = lane & 15;
    const int ngbase = (blockIdx.y * 4 + wave) * (NTW * 16);

    // load all B fragments once (held in registers for kernel lifetime)
    bf16x8 Bf[NTW][KF];
    float bb[NTW];
#pragma unroll
    for (int j = 0; j < NTW; j++) {
        int wr = ngbase + j * 16 + nn;
        if (wr > wrow_max) wr = wrow_max;
#pragma unroll
        for (int kf = 0; kf < KF; kf++)
            Bf[j][kf] = *(const bf16x8*)(W + (size_t)wr * K + kf * 32 + quad * 8);
        const int col = ngbase + j * 16 + nn;
        bb[j] = (col < ocols) ? bias[col] : 0.f;
    }

    int mt = blockIdx.x;
    if (mt >= MT_TOT) return;
    const int stride = gridDim.x;

    bf16x8 Acur[KF], Anext[KF];
    {
        const u16* ap = X + (size_t)(mt * 16 + nn) * K + quad * 8;
#pragma unroll
        for (int kf = 0; kf < KF; kf++) Acur[kf] = *(const bf16x8*)(ap + kf * 32);
    }

    while (true) {
        const int mtn = mt + stride;
        if (mtn < MT_TOT) {
            const u16* ap = X + (size_t)(mtn * 16 + nn) * K + quad * 8;
#pragma unroll
            for (int kf = 0; kf < KF; kf++) Anext[kf] = *(const bf16x8*)(ap + kf * 32);
        }

        f32x4 acc[NTW];
#pragma unroll
        for (int j = 0; j < NTW; j++) acc[j] = (f32x4){0.f, 0.f, 0.f, 0.f};
#pragma unroll
        for (int kf = 0; kf < KF; kf++)
#pragma unroll
            for (int j = 0; j < NTW; j++)
                acc[j] = __builtin_amdgcn_mfma_f32_16x16x32_bf16(Acur[kf], Bf[j][kf], acc[j], 0, 0, 0);

#pragma unroll
        for (int j = 0; j < NTW; j++) {
            const int col = ngbase + j * 16 + nn;
            if (col >= ocols) continue;
#pragma unroll
            for (int r = 0; r < 4; r++) {
                const int row = mt * 16 + quad * 4 + r;
                float v = acc[j][r] + bb[j];
                if (RELU) v = fmaxf(v, 0.f);
                if (OUT_F32) ((float*)Y)[(size_t)row * ocols + col] = v;
                else         ((u16*)Y)[(size_t)row * ocols + col] = f2bf(v);
            }
        }

        if (mtn >= MT_TOT) break;
#pragma unroll
        for (int kf = 0; kf < KF; kf++) Acur[kf] = Anext[kf];
        mt = mtn;
    }
}

extern "C" void kernel_launch(void* const* d_in, const int* in_sizes, int n_in,
                              void* d_out, int out_size, void* d_ws, size_t ws_size,
                              hipStream_t stream) {
    const float* x    = (const float*)d_in[0];
    const int*   ei   = (const int*)d_in[1];
    const float* W1   = (const float*)d_in[2];
    const float* b1   = (const float*)d_in[3];
    const float* W2   = (const float*)d_in[4];
    const float* b2   = (const float*)d_in[5];
    const float* Wout = (const float*)d_in[6];
    const float* bout = (const float*)d_in[7];
    float* out = (float*)d_out;

    const int* src = ei;            // edge_index[0]
    const int* dst = ei + N_EDGES;  // edge_index[1]

    // workspace (~110 MB)
    char* ws = (char*)d_ws;
    size_t o = 0;
    auto alloc = [&](size_t bytes) { size_t p = o; o = (o + bytes + 255) & ~(size_t)255; return p; };
    int*   cnt    = (int*)(ws + alloc((size_t)N_NODES * 4));
    float* dinv   = (float*)(ws + alloc((size_t)N_NODES * 4));
    int*   rowptr = (int*)(ws + alloc((size_t)(N_NODES + 1) * 4));
    int*   cursor = (int*)(ws + alloc((size_t)N_NODES * 4));
    int*   bsum   = (int*)(ws + alloc((size_t)NB_SCAN * 4));
    int*   boff   = (int*)(ws + alloc((size_t)NB_SCAN * 4));
    uint2* edata  = (uint2*)(ws + alloc((size_t)N_EDGES * 8));
    u16*   xb     = (u16*)(ws + alloc((size_t)N_NODES * F_IN * 2));
    u16*   aggxb  = (u16*)(ws + alloc((size_t)N_NODES * F_IN * 2));
    u16*   h1b    = (u16*)(ws + alloc((size_t)N_NODES * H_DIM * 2));
    u16*   agghb  = (u16*)(ws + alloc((size_t)N_NODES * H_DIM * 2));
    u16*   h2b    = (u16*)(ws + alloc((size_t)N_NODES * H_DIM * 2));
    u16*   W1b    = (u16*)(ws + alloc((size_t)H_DIM * F_IN * 2));
    u16*   W2b    = (u16*)(ws + alloc((size_t)H_DIM * H_DIM * 2));
    u16*   Woutb  = (u16*)(ws + alloc((size_t)C_OUT * H_DIM * 2));

    // CSR build (multi-block scan)
    hipMemsetAsync(cnt, 0, (size_t)N_NODES * 4, stream);
    count_k<<<(N_EDGES + 255) / 256, 256, 0, stream>>>(dst, cnt, N_EDGES);
    scan1_k<<<NB_SCAN, 256, 0, stream>>>(cnt, dinv, rowptr, bsum);
    scan2_k<<<1, 256, 0, stream>>>(bsum, boff, rowptr);
    scan3_k<<<NB_SCAN, 256, 0, stream>>>(rowptr, cursor, boff);
    bucket_k<<<(N_EDGES + 255) / 256, 256, 0, stream>>>(src, dst, dinv, cursor, edata, N_EDGES);

    // fp32 -> bf16 conversions
    cvt_all_k<<<(CVT_TOT + 255) / 256, 256, 0, stream>>>(
        (const float4*)x, (uint2*)xb, (const float4*)W1, (uint2*)W1b,
        (const float4*)W2, (uint2*)W2b, (const float4*)Wout, (uint2*)Woutb);

    // layer 1 (aggregate-first): aggx = A*xb ; h1 = relu(aggx@W1^T + b1)
    gather1_k<<<(N_NODES + 3) / 4, 256, 0, stream>>>((const u32*)xb, rowptr, edata, dinv, (u32*)aggxb);
    bgemm_k<F_IN, 4, true, false><<<dim3(768, 1), 256, 0, stream>>>(aggxb, W1b, b1, h1b, H_DIM - 1, H_DIM);

    // layer 2: aggh = A*h1 ; h2 = aggh@W2^T + b2
    gather2_k<<<(N_NODES + 3) / 4, 256, 0, stream>>>((const uint2*)h1b, rowptr, edata, dinv, (uint2*)agghb);
    bgemm_k<H_DIM, 2, false, false><<<dim3(768, 2), 256, 0, stream>>>(agghb, W2b, b2, h2b, H_DIM - 1, H_DIM);

    // head: out = h2@Wout^T + bout (fp32 out), 4 waves x 1 n-tile = 64 cols (40 used)
    bgemm_k<H_DIM, 1, false, true><<<dim3(512, 1), 256, 0, stream>>>(h2b, Woutb, bout, out, C_OUT - 1, C_OUT);
}

// Round 8
// 355.166 us; speedup vs baseline: 2.3819x; 1.0124x over previous
//
#include <hip/hip_runtime.h>

#define N_NODES 50000
#define N_EDGES 800000
#define F_IN    128
#define H_DIM   256
#define C_OUT   40
#define NB_SCAN ((N_NODES + 255) / 256)   // 196
#define MT_TOT  (N_NODES / 16)            // 3125 m-tiles

typedef unsigned short u16;
typedef unsigned int   u32;
typedef short bf16x8 __attribute__((ext_vector_type(8)));
typedef float f32x4  __attribute__((ext_vector_type(4)));

__device__ inline float bfbits2f(u16 u) { return __uint_as_float(((u32)u) << 16); }
__device__ inline u16 f2bf(float f) {
    u32 u = __float_as_uint(f);
    u += 0x7fffu + ((u >> 16) & 1u);   // RNE
    return (u16)(u >> 16);
}
__device__ inline u32 pack2(float a, float b) {
    return (u32)f2bf(a) | ((u32)f2bf(b) << 16);
}

// ---- in-degree count over dst ----
__global__ __launch_bounds__(256) void count_k(const int* __restrict__ dst, int* __restrict__ cnt, int E) {
    int i = blockIdx.x * 256 + threadIdx.x;
    if (i < E) atomicAdd(&cnt[dst[i]], 1);
}

// ---- scan phase 1 ----
__global__ __launch_bounds__(256) void scan1_k(const int* __restrict__ cnt,
                                               float* __restrict__ dinv,
                                               int* __restrict__ rowptr,
                                               int* __restrict__ bsum) {
    __shared__ int sh[256];
    const int t = threadIdx.x;
    const int i = blockIdx.x * 256 + t;
    int c = (i < N_NODES) ? cnt[i] : 0;
    if (i < N_NODES) dinv[i] = rsqrtf((float)c + 1.0f);
    sh[t] = c;
    __syncthreads();
    for (int off = 1; off < 256; off <<= 1) {
        int v = (t >= off) ? sh[t - off] : 0;
        __syncthreads();
        sh[t] += v;
        __syncthreads();
    }
    if (i < N_NODES) rowptr[i] = sh[t] - c;
    if (t == 255) bsum[blockIdx.x] = sh[255];
}

// ---- scan phase 2 ----
__global__ __launch_bounds__(256) void scan2_k(const int* __restrict__ bsum,
                                               int* __restrict__ boff,
                                               int* __restrict__ rowptr) {
    __shared__ int sh[256];
    const int t = threadIdx.x;
    int c = (t < NB_SCAN) ? bsum[t] : 0;
    sh[t] = c;
    __syncthreads();
    for (int off = 1; off < 256; off <<= 1) {
        int v = (t >= off) ? sh[t - off] : 0;
        __syncthreads();
        sh[t] += v;
        __syncthreads();
    }
    if (t < NB_SCAN) boff[t] = sh[t] - c;
    if (t == 0) rowptr[N_NODES] = N_EDGES;
}

// ---- scan phase 3 ----
__global__ __launch_bounds__(256) void scan3_k(int* __restrict__ rowptr,
                                               int* __restrict__ cursor,
                                               const int* __restrict__ boff) {
    const int i = blockIdx.x * 256 + threadIdx.x;
    if (i < N_NODES) {
        int r = rowptr[i] + boff[blockIdx.x];
        rowptr[i] = r;
        cursor[i] = r;
    }
}

// ---- bucket edges by dst; store {src, norm} packed per edge ----
__global__ __launch_bounds__(256) void bucket_k(const int* __restrict__ src, const int* __restrict__ dst,
                                                const float* __restrict__ dinv,
                                                int* __restrict__ cursor, uint2* __restrict__ edata, int E) {
    int i = blockIdx.x * 256 + threadIdx.x;
    if (i < E) {
        const int s = src[i], d = dst[i];
        int pos = atomicAdd(&cursor[d], 1);
        uint2 ed;
        ed.x = (u32)s;
        ed.y = __float_as_uint(dinv[s] * dinv[d]);
        edata[pos] = ed;
    }
}

// ---- fused fp32 -> bf16 convert ----
#define CVT_X  (N_NODES * F_IN / 4)
#define CVT_W1 (H_DIM * F_IN / 4)
#define CVT_W2 (H_DIM * H_DIM / 4)
#define CVT_WO (C_OUT * H_DIM / 4)
#define CVT_TOT (CVT_X + CVT_W1 + CVT_W2 + CVT_WO)
__global__ __launch_bounds__(256) void cvt_all_k(const float4* __restrict__ x, uint2* __restrict__ xb,
                                                 const float4* __restrict__ W1, uint2* __restrict__ W1b,
                                                 const float4* __restrict__ W2, uint2* __restrict__ W2b,
                                                 const float4* __restrict__ Wo, uint2* __restrict__ Wob) {
    int i = blockIdx.x * 256 + threadIdx.x;
    const float4* s; uint2* d; int j;
    if (i < CVT_X) { s = x; d = xb; j = i; }
    else if (i < CVT_X + CVT_W1) { s = W1; d = W1b; j = i - CVT_X; }
    else if (i < CVT_X + CVT_W1 + CVT_W2) { s = W2; d = W2b; j = i - CVT_X - CVT_W1; }
    else if (i < CVT_TOT) { s = Wo; d = Wob; j = i - CVT_X - CVT_W1 - CVT_W2; }
    else return;
    float4 v = s[j];
    uint2 o; o.x = pack2(v.x, v.y); o.y = pack2(v.z, v.w);
    d[j] = o;
}

// ---- gather width-128 bf16, one wave per node, unroll x4 ----
__global__ __launch_bounds__(256) void gather1_k(const u32* __restrict__ xb,
                                                 const int* __restrict__ rowptr,
                                                 const uint2* __restrict__ edata,
                                                 const float* __restrict__ dinv,
                                                 u32* __restrict__ aggx) {
    const int node = blockIdx.x * 4 + (threadIdx.x >> 6);
    const int lane = threadIdx.x & 63;
    if (node >= N_NODES) return;
    const int beg = rowptr[node], end = rowptr[node + 1];
    const float dd = dinv[node];
    const u32 vs = xb[(size_t)node * 64 + lane];
    float a0 = dd * dd * bfbits2f((u16)vs);
    float a1 = dd * dd * bfbits2f((u16)(vs >> 16));
    int e = beg;
    for (; e + 3 < end; e += 4) {
        const uint2 e0 = edata[e], e1 = edata[e + 1], e2 = edata[e + 2], e3 = edata[e + 3];
        const u32 v0 = xb[(size_t)e0.x * 64 + lane];
        const u32 v1 = xb[(size_t)e1.x * 64 + lane];
        const u32 v2 = xb[(size_t)e2.x * 64 + lane];
        const u32 v3 = xb[(size_t)e3.x * 64 + lane];
        const float n0 = __uint_as_float(e0.y), n1 = __uint_as_float(e1.y);
        const float n2 = __uint_as_float(e2.y), n3 = __uint_as_float(e3.y);
        a0 += n0 * bfbits2f((u16)v0); a1 += n0 * bfbits2f((u16)(v0 >> 16));
        a0 += n1 * bfbits2f((u16)v1); a1 += n1 * bfbits2f((u16)(v1 >> 16));
        a0 += n2 * bfbits2f((u16)v2); a1 += n2 * bfbits2f((u16)(v2 >> 16));
        a0 += n3 * bfbits2f((u16)v3); a1 += n3 * bfbits2f((u16)(v3 >> 16));
    }
    for (; e < end; e++) {
        const uint2 e0 = edata[e];
        const u32 v0 = xb[(size_t)e0.x * 64 + lane];
        const float n0 = __uint_as_float(e0.y);
        a0 += n0 * bfbits2f((u16)v0);
        a1 += n0 * bfbits2f((u16)(v0 >> 16));
    }
    aggx[(size_t)node * 64 + lane] = pack2(a0, a1);
}

// ---- gather width-256 bf16, TWO waves per node (128 feat each), unroll x4 ----
__global__ __launch_bounds__(256) void gather2_k(const u32* __restrict__ hb,     // [N][128] u32 view
                                                 const int* __restrict__ rowptr,
                                                 const uint2* __restrict__ edata,
                                                 const float* __restrict__ dinv,
                                                 u32* __restrict__ agg) {
    const int wv   = threadIdx.x >> 6;             // 0..3
    const int node = blockIdx.x * 2 + (wv >> 1);
    const int lane = threadIdx.x & 63;
    if (node >= N_NODES) return;
    const int col = (wv & 1) * 64 + lane;          // 0..127 (u32 granularity)
    const int beg = rowptr[node], end = rowptr[node + 1];
    const float dd = dinv[node];
    const u32 vs = hb[(size_t)node * 128 + col];
    float a0 = dd * dd * bfbits2f((u16)vs);
    float a1 = dd * dd * bfbits2f((u16)(vs >> 16));
    int e = beg;
    for (; e + 3 < end; e += 4) {
        const uint2 e0 = edata[e], e1 = edata[e + 1], e2 = edata[e + 2], e3 = edata[e + 3];
        const u32 v0 = hb[(size_t)e0.x * 128 + col];
        const u32 v1 = hb[(size_t)e1.x * 128 + col];
        const u32 v2 = hb[(size_t)e2.x * 128 + col];
        const u32 v3 = hb[(size_t)e3.x * 128 + col];
        const float n0 = __uint_as_float(e0.y), n1 = __uint_as_float(e1.y);
        const float n2 = __uint_as_float(e2.y), n3 = __uint_as_float(e3.y);
        a0 += n0 * bfbits2f((u16)v0); a1 += n0 * bfbits2f((u16)(v0 >> 16));
        a0 += n1 * bfbits2f((u16)v1); a1 += n1 * bfbits2f((u16)(v1 >> 16));
        a0 += n2 * bfbits2f((u16)v2); a1 += n2 * bfbits2f((u16)(v2 >> 16));
        a0 += n3 * bfbits2f((u16)v3); a1 += n3 * bfbits2f((u16)(v3 >> 16));
    }
    for (; e < end; e++) {
        const uint2 e0 = edata[e];
        const u32 v0 = hb[(size_t)e0.x * 128 + col];
        const float n0 = __uint_as_float(e0.y);
        a0 += n0 * bfbits2f((u16)v0);
        a1 += n0 * bfbits2f((u16)(v0 >> 16));
    }
    agg[(size_t)node * 128 + col] = pack2(a0, a1);
}

// ---- B-stationary MFMA GEMM (validated round 7) ----
template<int K, int NTW, bool RELU, bool OUT_F32>
__global__ __launch_bounds__(256) void bgemm_k(const u16* __restrict__ X,
                                               const u16* __restrict__ W,
                                               const float* __restrict__ bias,
                                               void* __restrict__ Y,
                                               int wrow_max, int ocols) {
    constexpr int KF = K / 32;
    const int wave = threadIdx.x >> 6;
    const int lane = threadIdx.x & 63;
    const int quad = lane >> 4;
    const int nn = lane & 15;
    const int ngbase = (blockIdx.y * 4 + wave) * (NTW * 16);

    bf16x8 Bf[NTW][KF];
    float bb[NTW];
#pragma unroll
    for (int j = 0; j < NTW; j++) {
        int wr = ngbase + j * 16 + nn;
        if (wr > wrow_max) wr = wrow_max;
#pragma unroll
        for (int kf = 0; kf < KF; kf++)
            Bf[j][kf] = *(const bf16x8*)(W + (size_t)wr * K + kf * 32 + quad * 8);
        const int col = ngbase + j * 16 + nn;
        bb[j] = (col < ocols) ? bias[col] : 0.f;
    }

    int mt = blockIdx.x;
    if (mt >= MT_TOT) return;
    const int stride = gridDim.x;

    bf16x8 Acur[KF], Anext[KF];
    {
        const u16* ap = X + (size_t)(mt * 16 + nn) * K + quad * 8;
#pragma unroll
        for (int kf = 0; kf < KF; kf++) Acur[kf] = *(const bf16x8*)(ap + kf * 32);
    }

    while (true) {
        const int mtn = mt + stride;
        if (mtn < MT_TOT) {
            const u16* ap = X + (size_t)(mtn * 16 + nn) * K + quad * 8;
#pragma unroll
            for (int kf = 0; kf < KF; kf++) Anext[kf] = *(const bf16x8*)(ap + kf * 32);
        }

        f32x4 acc[NTW];
#pragma unroll
        for (int j = 0; j < NTW; j++) acc[j] = (f32x4){0.f, 0.f, 0.f, 0.f};
#pragma unroll
        for (int kf = 0; kf < KF; kf++)
#pragma unroll
            for (int j = 0; j < NTW; j++)
                acc[j] = __builtin_amdgcn_mfma_f32_16x16x32_bf16(Acur[kf], Bf[j][kf], acc[j], 0, 0, 0);

#pragma unroll
        for (int j = 0; j < NTW; j++) {
            const int col = ngbase + j * 16 + nn;
            if (col >= ocols) continue;
#pragma unroll
            for (int r = 0; r < 4; r++) {
                const int row = mt * 16 + quad * 4 + r;
                float v = acc[j][r] + bb[j];
                if (RELU) v = fmaxf(v, 0.f);
                if (OUT_F32) ((float*)Y)[(size_t)row * ocols + col] = v;
                else         ((u16*)Y)[(size_t)row * ocols + col] = f2bf(v);
            }
        }

        if (mtn >= MT_TOT) break;
#pragma unroll
        for (int kf = 0; kf < KF; kf++) Acur[kf] = Anext[kf];
        mt = mtn;
    }
}

extern "C" void kernel_launch(void* const* d_in, const int* in_sizes, int n_in,
                              void* d_out, int out_size, void* d_ws, size_t ws_size,
                              hipStream_t stream) {
    const float* x    = (const float*)d_in[0];
    const int*   ei   = (const int*)d_in[1];
    const float* W1   = (const float*)d_in[2];
    const float* b1   = (const float*)d_in[3];
    const float* W2   = (const float*)d_in[4];
    const float* b2   = (const float*)d_in[5];
    const float* Wout = (const float*)d_in[6];
    const float* bout = (const float*)d_in[7];
    float* out = (float*)d_out;

    const int* src = ei;            // edge_index[0]
    const int* dst = ei + N_EDGES;  // edge_index[1]

    // workspace (~110 MB)
    char* ws = (char*)d_ws;
    size_t o = 0;
    auto alloc = [&](size_t bytes) { size_t p = o; o = (o + bytes + 255) & ~(size_t)255; return p; };
    int*   cnt    = (int*)(ws + alloc((size_t)N_NODES * 4));
    float* dinv   = (float*)(ws + alloc((size_t)N_NODES * 4));
    int*   rowptr = (int*)(ws + alloc((size_t)(N_NODES + 1) * 4));
    int*   cursor = (int*)(ws + alloc((size_t)N_NODES * 4));
    int*   bsum   = (int*)(ws + alloc((size_t)NB_SCAN * 4));
    int*   boff   = (int*)(ws + alloc((size_t)NB_SCAN * 4));
    uint2* edata  = (uint2*)(ws + alloc((size_t)N_EDGES * 8));
    u16*   xb     = (u16*)(ws + alloc((size_t)N_NODES * F_IN * 2));
    u16*   aggxb  = (u16*)(ws + alloc((size_t)N_NODES * F_IN * 2));
    u16*   h1b    = (u16*)(ws + alloc((size_t)N_NODES * H_DIM * 2));
    u16*   agghb  = (u16*)(ws + alloc((size_t)N_NODES * H_DIM * 2));
    u16*   h2b    = (u16*)(ws + alloc((size_t)N_NODES * H_DIM * 2));
    u16*   W1b    = (u16*)(ws + alloc((size_t)H_DIM * F_IN * 2));
    u16*   W2b    = (u16*)(ws + alloc((size_t)H_DIM * H_DIM * 2));
    u16*   Woutb  = (u16*)(ws + alloc((size_t)C_OUT * H_DIM * 2));

    // CSR build (multi-block scan)
    hipMemsetAsync(cnt, 0, (size_t)N_NODES * 4, stream);
    count_k<<<(N_EDGES + 255) / 256, 256, 0, stream>>>(dst, cnt, N_EDGES);
    scan1_k<<<NB_SCAN, 256, 0, stream>>>(cnt, dinv, rowptr, bsum);
    scan2_k<<<1, 256, 0, stream>>>(bsum, boff, rowptr);
    scan3_k<<<NB_SCAN, 256, 0, stream>>>(rowptr, cursor, boff);
    bucket_k<<<(N_EDGES + 255) / 256, 256, 0, stream>>>(src, dst, dinv, cursor, edata, N_EDGES);

    // fp32 -> bf16 conversions
    cvt_all_k<<<(CVT_TOT + 255) / 256, 256, 0, stream>>>(
        (const float4*)x, (uint2*)xb, (const float4*)W1, (uint2*)W1b,
        (const float4*)W2, (uint2*)W2b, (const float4*)Wout, (uint2*)Woutb);

    // layer 1 (aggregate-first): aggx = A*xb ; h1 = relu(aggx@W1^T + b1)
    gather1_k<<<(N_NODES + 3) / 4, 256, 0, stream>>>((const u32*)xb, rowptr, edata, dinv, (u32*)aggxb);
    bgemm_k<F_IN, 4, true, false><<<dim3(768, 1), 256, 0, stream>>>(aggxb, W1b, b1, h1b, H_DIM - 1, H_DIM);

    // layer 2: aggh = A*h1 ; h2 = aggh@W2^T + b2
    gather2_k<<<(N_NODES + 1) / 2, 256, 0, stream>>>((const u32*)h1b, rowptr, edata, dinv, (u32*)agghb);
    bgemm_k<H_DIM, 2, false, false><<<dim3(768, 2), 256, 0, stream>>>(agghb, W2b, b2, h2b, H_DIM - 1, H_DIM);

    // head: out = h2@Wout^T + bout (fp32 out)
    bgemm_k<H_DIM, 1, false, true><<<dim3(512, 1), 256, 0, stream>>>(h2b, Woutb, bout, out, C_OUT - 1, C_OUT);
}

// Round 9
// 344.851 us; speedup vs baseline: 2.4531x; 1.0299x over previous
//
#include <hip/hip_runtime.h>

#define N_NODES 50000
#define N_EDGES 800000
#define F_IN    128
#define H_DIM   256
#define C_OUT   40
#define NB_SCAN ((N_NODES + 255) / 256)   // 196
#define MT_TOT  (N_NODES / 16)            // 3125 m-tiles

typedef unsigned short u16;
typedef unsigned int   u32;
typedef short bf16x8 __attribute__((ext_vector_type(8)));
typedef float f32x4  __attribute__((ext_vector_type(4)));

__device__ inline float bfbits2f(u16 u) { return __uint_as_float(((u32)u) << 16); }
__device__ inline u16 f2bf(float f) {
    u32 u = __float_as_uint(f);
    u += 0x7fffu + ((u >> 16) & 1u);   // RNE
    return (u16)(u >> 16);
}
__device__ inline u32 pack2(float a, float b) {
    return (u32)f2bf(a) | ((u32)f2bf(b) << 16);
}

// ---- in-degree count over dst ----
__global__ __launch_bounds__(256) void count_k(const int* __restrict__ dst, int* __restrict__ cnt, int E) {
    int i = blockIdx.x * 256 + threadIdx.x;
    if (i < E) atomicAdd(&cnt[dst[i]], 1);
}

// ---- scan phase 1 ----
__global__ __launch_bounds__(256) void scan1_k(const int* __restrict__ cnt,
                                               float* __restrict__ dinv,
                                               int* __restrict__ rowptr,
                                               int* __restrict__ bsum) {
    __shared__ int sh[256];
    const int t = threadIdx.x;
    const int i = blockIdx.x * 256 + t;
    int c = (i < N_NODES) ? cnt[i] : 0;
    if (i < N_NODES) dinv[i] = rsqrtf((float)c + 1.0f);
    sh[t] = c;
    __syncthreads();
    for (int off = 1; off < 256; off <<= 1) {
        int v = (t >= off) ? sh[t - off] : 0;
        __syncthreads();
        sh[t] += v;
        __syncthreads();
    }
    if (i < N_NODES) rowptr[i] = sh[t] - c;
    if (t == 255) bsum[blockIdx.x] = sh[255];
}

// ---- scan phase 2 ----
__global__ __launch_bounds__(256) void scan2_k(const int* __restrict__ bsum,
                                               int* __restrict__ boff,
                                               int* __restrict__ rowptr) {
    __shared__ int sh[256];
    const int t = threadIdx.x;
    int c = (t < NB_SCAN) ? bsum[t] : 0;
    sh[t] = c;
    __syncthreads();
    for (int off = 1; off < 256; off <<= 1) {
        int v = (t >= off) ? sh[t - off] : 0;
        __syncthreads();
        sh[t] += v;
        __syncthreads();
    }
    if (t < NB_SCAN) boff[t] = sh[t] - c;
    if (t == 0) rowptr[N_NODES] = N_EDGES;
}

// ---- scan phase 3 ----
__global__ __launch_bounds__(256) void scan3_k(int* __restrict__ rowptr,
                                               int* __restrict__ cursor,
                                               const int* __restrict__ boff) {
    const int i = blockIdx.x * 256 + threadIdx.x;
    if (i < N_NODES) {
        int r = rowptr[i] + boff[blockIdx.x];
        rowptr[i] = r;
        cursor[i] = r;
    }
}

// ---- bucket edges by dst; store {src, norm} packed per edge ----
__global__ __launch_bounds__(256) void bucket_k(const int* __restrict__ src, const int* __restrict__ dst,
                                                const float* __restrict__ dinv,
                                                int* __restrict__ cursor, uint2* __restrict__ edata, int E) {
    int i = blockIdx.x * 256 + threadIdx.x;
    if (i < E) {
        const int s = src[i], d = dst[i];
        int pos = atomicAdd(&cursor[d], 1);
        uint2 ed;
        ed.x = (u32)s;
        ed.y = __float_as_uint(dinv[s] * dinv[d]);
        edata[pos] = ed;
    }
}

// ---- fused fp32 -> bf16 convert ----
#define CVT_X  (N_NODES * F_IN / 4)
#define CVT_W1 (H_DIM * F_IN / 4)
#define CVT_W2 (H_DIM * H_DIM / 4)
#define CVT_WO (C_OUT * H_DIM / 4)
#define CVT_TOT (CVT_X + CVT_W1 + CVT_W2 + CVT_WO)
__global__ __launch_bounds__(256) void cvt_all_k(const float4* __restrict__ x, uint2* __restrict__ xb,
                                                 const float4* __restrict__ W1, uint2* __restrict__ W1b,
                                                 const float4* __restrict__ W2, uint2* __restrict__ W2b,
                                                 const float4* __restrict__ Wo, uint2* __restrict__ Wob) {
    int i = blockIdx.x * 256 + threadIdx.x;
    const float4* s; uint2* d; int j;
    if (i < CVT_X) { s = x; d = xb; j = i; }
    else if (i < CVT_X + CVT_W1) { s = W1; d = W1b; j = i - CVT_X; }
    else if (i < CVT_X + CVT_W1 + CVT_W2) { s = W2; d = W2b; j = i - CVT_X - CVT_W1; }
    else if (i < CVT_TOT) { s = Wo; d = Wob; j = i - CVT_X - CVT_W1 - CVT_W2; }
    else return;
    float4 v = s[j];
    uint2 o; o.x = pack2(v.x, v.y); o.y = pack2(v.z, v.w);
    d[j] = o;
}

// ---- gather width-128 bf16, one wave per node, unroll x4 ----
__global__ __launch_bounds__(256) void gather1_k(const u32* __restrict__ xb,
                                                 const int* __restrict__ rowptr,
                                                 const uint2* __restrict__ edata,
                                                 const float* __restrict__ dinv,
                                                 u32* __restrict__ aggx) {
    const int node = blockIdx.x * 4 + (threadIdx.x >> 6);
    const int lane = threadIdx.x & 63;
    if (node >= N_NODES) return;
    const int beg = rowptr[node], end = rowptr[node + 1];
    const float dd = dinv[node];
    const u32 vs = xb[(size_t)node * 64 + lane];
    float a0 = dd * dd * bfbits2f((u16)vs);
    float a1 = dd * dd * bfbits2f((u16)(vs >> 16));
    int e = beg;
    for (; e + 3 < end; e += 4) {
        const uint2 e0 = edata[e], e1 = edata[e + 1], e2 = edata[e + 2], e3 = edata[e + 3];
        const u32 v0 = xb[(size_t)e0.x * 64 + lane];
        const u32 v1 = xb[(size_t)e1.x * 64 + lane];
        const u32 v2 = xb[(size_t)e2.x * 64 + lane];
        const u32 v3 = xb[(size_t)e3.x * 64 + lane];
        const float n0 = __uint_as_float(e0.y), n1 = __uint_as_float(e1.y);
        const float n2 = __uint_as_float(e2.y), n3 = __uint_as_float(e3.y);
        a0 += n0 * bfbits2f((u16)v0); a1 += n0 * bfbits2f((u16)(v0 >> 16));
        a0 += n1 * bfbits2f((u16)v1); a1 += n1 * bfbits2f((u16)(v1 >> 16));
        a0 += n2 * bfbits2f((u16)v2); a1 += n2 * bfbits2f((u16)(v2 >> 16));
        a0 += n3 * bfbits2f((u16)v3); a1 += n3 * bfbits2f((u16)(v3 >> 16));
    }
    for (; e < end; e++) {
        const uint2 e0 = edata[e];
        const u32 v0 = xb[(size_t)e0.x * 64 + lane];
        const float n0 = __uint_as_float(e0.y);
        a0 += n0 * bfbits2f((u16)v0);
        a1 += n0 * bfbits2f((u16)(v0 >> 16));
    }
    aggx[(size_t)node * 64 + lane] = pack2(a0, a1);
}

// ---- gather width-256 bf16, ONE wave per node, uint2 (512 B) loads, unroll x4 ----
__global__ __launch_bounds__(256) void gather2_k(const uint2* __restrict__ hb,   // [N][64] uint2
                                                 const int* __restrict__ rowptr,
                                                 const uint2* __restrict__ edata,
                                                 const float* __restrict__ dinv,
                                                 uint2* __restrict__ agg) {
    const int node = blockIdx.x * 4 + (threadIdx.x >> 6);
    const int lane = threadIdx.x & 63;
    if (node >= N_NODES) return;
    const int beg = rowptr[node], end = rowptr[node + 1];
    const float dd = dinv[node];
    const uint2 vs = hb[(size_t)node * 64 + lane];
    const float ss = dd * dd;
    float a0 = ss * bfbits2f((u16)vs.x);
    float a1 = ss * bfbits2f((u16)(vs.x >> 16));
    float a2 = ss * bfbits2f((u16)vs.y);
    float a3 = ss * bfbits2f((u16)(vs.y >> 16));
    int e = beg;
    for (; e + 3 < end; e += 4) {
        const uint2 e0 = edata[e], e1 = edata[e + 1], e2 = edata[e + 2], e3 = edata[e + 3];
        const uint2 v0 = hb[(size_t)e0.x * 64 + lane];
        const uint2 v1 = hb[(size_t)e1.x * 64 + lane];
        const uint2 v2 = hb[(size_t)e2.x * 64 + lane];
        const uint2 v3 = hb[(size_t)e3.x * 64 + lane];
        const float n0 = __uint_as_float(e0.y), n1 = __uint_as_float(e1.y);
        const float n2 = __uint_as_float(e2.y), n3 = __uint_as_float(e3.y);
        a0 += n0 * bfbits2f((u16)v0.x); a1 += n0 * bfbits2f((u16)(v0.x >> 16));
        a2 += n0 * bfbits2f((u16)v0.y); a3 += n0 * bfbits2f((u16)(v0.y >> 16));
        a0 += n1 * bfbits2f((u16)v1.x); a1 += n1 * bfbits2f((u16)(v1.x >> 16));
        a2 += n1 * bfbits2f((u16)v1.y); a3 += n1 * bfbits2f((u16)(v1.y >> 16));
        a0 += n2 * bfbits2f((u16)v2.x); a1 += n2 * bfbits2f((u16)(v2.x >> 16));
        a2 += n2 * bfbits2f((u16)v2.y); a3 += n2 * bfbits2f((u16)(v2.y >> 16));
        a0 += n3 * bfbits2f((u16)v3.x); a1 += n3 * bfbits2f((u16)(v3.x >> 16));
        a2 += n3 * bfbits2f((u16)v3.y); a3 += n3 * bfbits2f((u16)(v3.y >> 16));
    }
    for (; e < end; e++) {
        const uint2 e0 = edata[e];
        const uint2 v0 = hb[(size_t)e0.x * 64 + lane];
        const float n0 = __uint_as_float(e0.y);
        a0 += n0 * bfbits2f((u16)v0.x); a1 += n0 * bfbits2f((u16)(v0.x >> 16));
        a2 += n0 * bfbits2f((u16)v0.y); a3 += n0 * bfbits2f((u16)(v0.y >> 16));
    }
    uint2 o; o.x = pack2(a0, a1); o.y = pack2(a2, a3);
    agg[(size_t)node * 64 + lane] = o;
}

// ---- B-stationary MFMA GEMM (validated round 7) ----
template<int K, int NTW, bool RELU, bool OUT_F32>
__global__ __launch_bounds__(256) void bgemm_k(const u16* __restrict__ X,
                                               const u16* __restrict__ W,
                                               const float* __restrict__ bias,
                                               void* __restrict__ Y,
                                               int wrow_max, int ocols) {
    constexpr int KF = K / 32;
    const int wave = threadIdx.x >> 6;
    const int lane = threadIdx.x & 63;
    const int quad = lane >> 4;
    const int nn = lane & 15;
    const int ngbase = (blockIdx.y * 4 + wave) * (NTW * 16);

    bf16x8 Bf[NTW][KF];
    float bb[NTW];
#pragma unroll
    for (int j = 0; j < NTW; j++) {
        int wr = ngbase + j * 16 + nn;
        if (wr > wrow_max) wr = wrow_max;
#pragma unroll
        for (int kf = 0; kf < KF; kf++)
            Bf[j][kf] = *(const bf16x8*)(W + (size_t)wr * K + kf * 32 + quad * 8);
        const int col = ngbase + j * 16 + nn;
        bb[j] = (col < ocols) ? bias[col] : 0.f;
    }

    int mt = blockIdx.x;
    if (mt >= MT_TOT) return;
    const int stride = gridDim.x;

    bf16x8 Acur[KF], Anext[KF];
    {
        const u16* ap = X + (size_t)(mt * 16 + nn) * K + quad * 8;
#pragma unroll
        for (int kf = 0; kf < KF; kf++) Acur[kf] = *(const bf16x8*)(ap + kf * 32);
    }

    while (true) {
        const int mtn = mt + stride;
        if (mtn < MT_TOT) {
            const u16* ap = X + (size_t)(mtn * 16 + nn) * K + quad * 8;
#pragma unroll
            for (int kf = 0; kf < KF; kf++) Anext[kf] = *(const bf16x8*)(ap + kf * 32);
        }

        f32x4 acc[NTW];
#pragma unroll
        for (int j = 0; j < NTW; j++) acc[j] = (f32x4){0.f, 0.f, 0.f, 0.f};
#pragma unroll
        for (int kf = 0; kf < KF; kf++)
#pragma unroll
            for (int j = 0; j < NTW; j++)
                acc[j] = __builtin_amdgcn_mfma_f32_16x16x32_bf16(Acur[kf], Bf[j][kf], acc[j], 0, 0, 0);

#pragma unroll
        for (int j = 0; j < NTW; j++) {
            const int col = ngbase + j * 16 + nn;
            if (col >= ocols) continue;
#pragma unroll
            for (int r = 0; r < 4; r++) {
                const int row = mt * 16 + quad * 4 + r;
                float v = acc[j][r] + bb[j];
                if (RELU) v = fmaxf(v, 0.f);
                if (OUT_F32) ((float*)Y)[(size_t)row * ocols + col] = v;
                else         ((u16*)Y)[(size_t)row * ocols + col] = f2bf(v);
            }
        }

        if (mtn >= MT_TOT) break;
#pragma unroll
        for (int kf = 0; kf < KF; kf++) Acur[kf] = Anext[kf];
        mt = mtn;
    }
}

extern "C" void kernel_launch(void* const* d_in, const int* in_sizes, int n_in,
                              void* d_out, int out_size, void* d_ws, size_t ws_size,
                              hipStream_t stream) {
    const float* x    = (const float*)d_in[0];
    const int*   ei   = (const int*)d_in[1];
    const float* W1   = (const float*)d_in[2];
    const float* b1   = (const float*)d_in[3];
    const float* W2   = (const float*)d_in[4];
    const float* b2   = (const float*)d_in[5];
    const float* Wout = (const float*)d_in[6];
    const float* bout = (const float*)d_in[7];
    float* out = (float*)d_out;

    const int* src = ei;            // edge_index[0]
    const int* dst = ei + N_EDGES;  // edge_index[1]

    // workspace (~110 MB)
    char* ws = (char*)d_ws;
    size_t o = 0;
    auto alloc = [&](size_t bytes) { size_t p = o; o = (o + bytes + 255) & ~(size_t)255; return p; };
    int*   cnt    = (int*)(ws + alloc((size_t)N_NODES * 4));
    float* dinv   = (float*)(ws + alloc((size_t)N_NODES * 4));
    int*   rowptr = (int*)(ws + alloc((size_t)(N_NODES + 1) * 4));
    int*   cursor = (int*)(ws + alloc((size_t)N_NODES * 4));
    int*   bsum   = (int*)(ws + alloc((size_t)NB_SCAN * 4));
    int*   boff   = (int*)(ws + alloc((size_t)NB_SCAN * 4));
    uint2* edata  = (uint2*)(ws + alloc((size_t)N_EDGES * 8));
    u16*   xb     = (u16*)(ws + alloc((size_t)N_NODES * F_IN * 2));
    u16*   aggxb  = (u16*)(ws + alloc((size_t)N_NODES * F_IN * 2));
    u16*   h1b    = (u16*)(ws + alloc((size_t)N_NODES * H_DIM * 2));
    u16*   agghb  = (u16*)(ws + alloc((size_t)N_NODES * H_DIM * 2));
    u16*   h2b    = (u16*)(ws + alloc((size_t)N_NODES * H_DIM * 2));
    u16*   W1b    = (u16*)(ws + alloc((size_t)H_DIM * F_IN * 2));
    u16*   W2b    = (u16*)(ws + alloc((size_t)H_DIM * H_DIM * 2));
    u16*   Woutb  = (u16*)(ws + alloc((size_t)C_OUT * H_DIM * 2));

    // CSR build (multi-block scan)
    hipMemsetAsync(cnt, 0, (size_t)N_NODES * 4, stream);
    count_k<<<(N_EDGES + 255) / 256, 256, 0, stream>>>(dst, cnt, N_EDGES);
    scan1_k<<<NB_SCAN, 256, 0, stream>>>(cnt, dinv, rowptr, bsum);
    scan2_k<<<1, 256, 0, stream>>>(bsum, boff, rowptr);
    scan3_k<<<NB_SCAN, 256, 0, stream>>>(rowptr, cursor, boff);
    bucket_k<<<(N_EDGES + 255) / 256, 256, 0, stream>>>(src, dst, dinv, cursor, edata, N_EDGES);

    // fp32 -> bf16 conversions
    cvt_all_k<<<(CVT_TOT + 255) / 256, 256, 0, stream>>>(
        (const float4*)x, (uint2*)xb, (const float4*)W1, (uint2*)W1b,
        (const float4*)W2, (uint2*)W2b, (const float4*)Wout, (uint2*)Woutb);

    // layer 1 (aggregate-first): aggx = A*xb ; h1 = relu(aggx@W1^T + b1)
    gather1_k<<<(N_NODES + 3) / 4, 256, 0, stream>>>((const u32*)xb, rowptr, edata, dinv, (u32*)aggxb);
    bgemm_k<F_IN, 4, true, false><<<dim3(768, 1), 256, 0, stream>>>(aggxb, W1b, b1, h1b, H_DIM - 1, H_DIM);

    // layer 2: aggh = A*h1 ; h2 = aggh@W2^T + b2
    gather2_k<<<(N_NODES + 3) / 4, 256, 0, stream>>>((const uint2*)h1b, rowptr, edata, dinv, (uint2*)agghb);
    bgemm_k<H_DIM, 2, false, false><<<dim3(768, 2), 256, 0, stream>>>(agghb, W2b, b2, h2b, H_DIM - 1, H_DIM);

    // head: out = h2@Wout^T + bout (fp32 out)
    bgemm_k<H_DIM, 1, false, true><<<dim3(512, 1), 256, 0, stream>>>(h2b, Woutb, bout, out, C_OUT - 1, C_OUT);
}

// Round 10
// 331.077 us; speedup vs baseline: 2.5552x; 1.0416x over previous
//
#include <hip/hip_runtime.h>

#define N_NODES 50000
#define N_EDGES 800000
#define F_IN    128
#define H_DIM   256
#define C_OUT   40
#define NB_SCAN ((N_NODES + 255) / 256)   // 196
#define MT_TOT  (N_NODES / 16)            // 3125 m-tiles

typedef unsigned short u16;
typedef unsigned int   u32;
typedef short bf16x8 __attribute__((ext_vector_type(8)));
typedef float f32x4  __attribute__((ext_vector_type(4)));

__device__ inline float bfbits2f(u16 u) { return __uint_as_float(((u32)u) << 16); }
__device__ inline u16 f2bf(float f) {
    u32 u = __float_as_uint(f);
    u += 0x7fffu + ((u >> 16) & 1u);   // RNE
    return (u16)(u >> 16);
}
__device__ inline u32 pack2(float a, float b) {
    return (u32)f2bf(a) | ((u32)f2bf(b) << 16);
}

// ---- in-degree count over dst ----
__global__ __launch_bounds__(256) void count_k(const int* __restrict__ dst, int* __restrict__ cnt, int E) {
    int i = blockIdx.x * 256 + threadIdx.x;
    if (i < E) atomicAdd(&cnt[dst[i]], 1);
}

// ---- scan phase 1 ----
__global__ __launch_bounds__(256) void scan1_k(const int* __restrict__ cnt,
                                               float* __restrict__ dinv,
                                               int* __restrict__ rowptr,
                                               int* __restrict__ bsum) {
    __shared__ int sh[256];
    const int t = threadIdx.x;
    const int i = blockIdx.x * 256 + t;
    int c = (i < N_NODES) ? cnt[i] : 0;
    if (i < N_NODES) dinv[i] = rsqrtf((float)c + 1.0f);
    sh[t] = c;
    __syncthreads();
    for (int off = 1; off < 256; off <<= 1) {
        int v = (t >= off) ? sh[t - off] : 0;
        __syncthreads();
        sh[t] += v;
        __syncthreads();
    }
    if (i < N_NODES) rowptr[i] = sh[t] - c;
    if (t == 255) bsum[blockIdx.x] = sh[255];
}

// ---- scan phase 2 ----
__global__ __launch_bounds__(256) void scan2_k(const int* __restrict__ bsum,
                                               int* __restrict__ boff,
                                               int* __restrict__ rowptr) {
    __shared__ int sh[256];
    const int t = threadIdx.x;
    int c = (t < NB_SCAN) ? bsum[t] : 0;
    sh[t] = c;
    __syncthreads();
    for (int off = 1; off < 256; off <<= 1) {
        int v = (t >= off) ? sh[t - off] : 0;
        __syncthreads();
        sh[t] += v;
        __syncthreads();
    }
    if (t < NB_SCAN) boff[t] = sh[t] - c;
    if (t == 0) rowptr[N_NODES] = N_EDGES;
}

// ---- scan phase 3 ----
__global__ __launch_bounds__(256) void scan3_k(int* __restrict__ rowptr,
                                               int* __restrict__ cursor,
                                               const int* __restrict__ boff) {
    const int i = blockIdx.x * 256 + threadIdx.x;
    if (i < N_NODES) {
        int r = rowptr[i] + boff[blockIdx.x];
        rowptr[i] = r;
        cursor[i] = r;
    }
}

// ---- bucket edges by dst; store {src, norm} packed per edge ----
__global__ __launch_bounds__(256) void bucket_k(const int* __restrict__ src, const int* __restrict__ dst,
                                                const float* __restrict__ dinv,
                                                int* __restrict__ cursor, uint2* __restrict__ edata, int E) {
    int i = blockIdx.x * 256 + threadIdx.x;
    if (i < E) {
        const int s = src[i], d = dst[i];
        int pos = atomicAdd(&cursor[d], 1);
        uint2 ed;
        ed.x = (u32)s;
        ed.y = __float_as_uint(dinv[s] * dinv[d]);
        edata[pos] = ed;
    }
}

// ---- fused fp32 -> bf16 convert ----
#define CVT_X  (N_NODES * F_IN / 4)
#define CVT_W1 (H_DIM * F_IN / 4)
#define CVT_W2 (H_DIM * H_DIM / 4)
#define CVT_WO (C_OUT * H_DIM / 4)
#define CVT_TOT (CVT_X + CVT_W1 + CVT_W2 + CVT_WO)
__global__ __launch_bounds__(256) void cvt_all_k(const float4* __restrict__ x, uint2* __restrict__ xb,
                                                 const float4* __restrict__ W1, uint2* __restrict__ W1b,
                                                 const float4* __restrict__ W2, uint2* __restrict__ W2b,
                                                 const float4* __restrict__ Wo, uint2* __restrict__ Wob) {
    int i = blockIdx.x * 256 + threadIdx.x;
    const float4* s; uint2* d; int j;
    if (i < CVT_X) { s = x; d = xb; j = i; }
    else if (i < CVT_X + CVT_W1) { s = W1; d = W1b; j = i - CVT_X; }
    else if (i < CVT_X + CVT_W1 + CVT_W2) { s = W2; d = W2b; j = i - CVT_X - CVT_W1; }
    else if (i < CVT_TOT) { s = Wo; d = Wob; j = i - CVT_X - CVT_W1 - CVT_W2; }
    else return;
    float4 v = s[j];
    uint2 o; o.x = pack2(v.x, v.y); o.y = pack2(v.z, v.w);
    d[j] = o;
}

// ---- gather width-128 bf16, one wave per node, unroll x8, scalar edata path ----
__global__ __launch_bounds__(256) void gather1_k(const u32* __restrict__ xb,
                                                 const int* __restrict__ rowptr,
                                                 const uint2* __restrict__ edata,
                                                 const float* __restrict__ dinv,
                                                 u32* __restrict__ aggx) {
    const int node = __builtin_amdgcn_readfirstlane(blockIdx.x * 4 + (threadIdx.x >> 6));
    const int lane = threadIdx.x & 63;
    if (node >= N_NODES) return;
    const int beg = __builtin_amdgcn_readfirstlane(rowptr[node]);
    const int end = __builtin_amdgcn_readfirstlane(rowptr[node + 1]);
    const float dd = dinv[node];
    const u32 vs = xb[(size_t)node * 64 + lane];
    float a0 = dd * dd * bfbits2f((u16)vs);
    float a1 = dd * dd * bfbits2f((u16)(vs >> 16));
    int e = beg;
    for (; e + 7 < end; e += 8) {
        uint2 ed[8];
#pragma unroll
        for (int j = 0; j < 8; j++) ed[j] = edata[e + j];
        u32 v[8];
#pragma unroll
        for (int j = 0; j < 8; j++) v[j] = xb[(size_t)ed[j].x * 64 + lane];
#pragma unroll
        for (int j = 0; j < 8; j++) {
            const float n = __uint_as_float(ed[j].y);
            a0 += n * bfbits2f((u16)v[j]);
            a1 += n * bfbits2f((u16)(v[j] >> 16));
        }
    }
    for (; e < end; e++) {
        const uint2 e0 = edata[e];
        const u32 v0 = xb[(size_t)e0.x * 64 + lane];
        const float n0 = __uint_as_float(e0.y);
        a0 += n0 * bfbits2f((u16)v0);
        a1 += n0 * bfbits2f((u16)(v0 >> 16));
    }
    aggx[(size_t)node * 64 + lane] = pack2(a0, a1);
}

// ---- gather width-256 bf16, one wave per node, uint2 loads, unroll x8, scalar edata ----
__global__ __launch_bounds__(256) void gather2_k(const uint2* __restrict__ hb,   // [N][64] uint2
                                                 const int* __restrict__ rowptr,
                                                 const uint2* __restrict__ edata,
                                                 const float* __restrict__ dinv,
                                                 uint2* __restrict__ agg) {
    const int node = __builtin_amdgcn_readfirstlane(blockIdx.x * 4 + (threadIdx.x >> 6));
    const int lane = threadIdx.x & 63;
    if (node >= N_NODES) return;
    const int beg = __builtin_amdgcn_readfirstlane(rowptr[node]);
    const int end = __builtin_amdgcn_readfirstlane(rowptr[node + 1]);
    const float dd = dinv[node];
    const uint2 vs = hb[(size_t)node * 64 + lane];
    const float ss = dd * dd;
    float a0 = ss * bfbits2f((u16)vs.x);
    float a1 = ss * bfbits2f((u16)(vs.x >> 16));
    float a2 = ss * bfbits2f((u16)vs.y);
    float a3 = ss * bfbits2f((u16)(vs.y >> 16));
    int e = beg;
    for (; e + 7 < end; e += 8) {
        uint2 ed[8];
#pragma unroll
        for (int j = 0; j < 8; j++) ed[j] = edata[e + j];
        uint2 v[8];
#pragma unroll
        for (int j = 0; j < 8; j++) v[j] = hb[(size_t)ed[j].x * 64 + lane];
#pragma unroll
        for (int j = 0; j < 8; j++) {
            const float n = __uint_as_float(ed[j].y);
            a0 += n * bfbits2f((u16)v[j].x); a1 += n * bfbits2f((u16)(v[j].x >> 16));
            a2 += n * bfbits2f((u16)v[j].y); a3 += n * bfbits2f((u16)(v[j].y >> 16));
        }
    }
    for (; e < end; e++) {
        const uint2 e0 = edata[e];
        const uint2 v0 = hb[(size_t)e0.x * 64 + lane];
        const float n0 = __uint_as_float(e0.y);
        a0 += n0 * bfbits2f((u16)v0.x); a1 += n0 * bfbits2f((u16)(v0.x >> 16));
        a2 += n0 * bfbits2f((u16)v0.y); a3 += n0 * bfbits2f((u16)(v0.y >> 16));
    }
    uint2 o; o.x = pack2(a0, a1); o.y = pack2(a2, a3);
    agg[(size_t)node * 64 + lane] = o;
}

// ---- B-stationary MFMA GEMM (validated round 7) ----
template<int K, int NTW, bool RELU, bool OUT_F32>
__global__ __launch_bounds__(256) void bgemm_k(const u16* __restrict__ X,
                                               const u16* __restrict__ W,
                                               const float* __restrict__ bias,
                                               void* __restrict__ Y,
                                               int wrow_max, int ocols) {
    constexpr int KF = K / 32;
    const int wave = threadIdx.x >> 6;
    const int lane = threadIdx.x & 63;
    const int quad = lane >> 4;
    const int nn = lane & 15;
    const int ngbase = (blockIdx.y * 4 + wave) * (NTW * 16);

    bf16x8 Bf[NTW][KF];
    float bb[NTW];
#pragma unroll
    for (int j = 0; j < NTW; j++) {
        int wr = ngbase + j * 16 + nn;
        if (wr > wrow_max) wr = wrow_max;
#pragma unroll
        for (int kf = 0; kf < KF; kf++)
            Bf[j][kf] = *(const bf16x8*)(W + (size_t)wr * K + kf * 32 + quad * 8);
        const int col = ngbase + j * 16 + nn;
        bb[j] = (col < ocols) ? bias[col] : 0.f;
    }

    int mt = blockIdx.x;
    if (mt >= MT_TOT) return;
    const int stride = gridDim.x;

    bf16x8 Acur[KF], Anext[KF];
    {
        const u16* ap = X + (size_t)(mt * 16 + nn) * K + quad * 8;
#pragma unroll
        for (int kf = 0; kf < KF; kf++) Acur[kf] = *(const bf16x8*)(ap + kf * 32);
    }

    while (true) {
        const int mtn = mt + stride;
        if (mtn < MT_TOT) {
            const u16* ap = X + (size_t)(mtn * 16 + nn) * K + quad * 8;
#pragma unroll
            for (int kf = 0; kf < KF; kf++) Anext[kf] = *(const bf16x8*)(ap + kf * 32);
        }

        f32x4 acc[NTW];
#pragma unroll
        for (int j = 0; j < NTW; j++) acc[j] = (f32x4){0.f, 0.f, 0.f, 0.f};
#pragma unroll
        for (int kf = 0; kf < KF; kf++)
#pragma unroll
            for (int j = 0; j < NTW; j++)
                acc[j] = __builtin_amdgcn_mfma_f32_16x16x32_bf16(Acur[kf], Bf[j][kf], acc[j], 0, 0, 0);

#pragma unroll
        for (int j = 0; j < NTW; j++) {
            const int col = ngbase + j * 16 + nn;
            if (col >= ocols) continue;
#pragma unroll
            for (int r = 0; r < 4; r++) {
                const int row = mt * 16 + quad * 4 + r;
                float v = acc[j][r] + bb[j];
                if (RELU) v = fmaxf(v, 0.f);
                if (OUT_F32) ((float*)Y)[(size_t)row * ocols + col] = v;
                else         ((u16*)Y)[(size_t)row * ocols + col] = f2bf(v);
            }
        }

        if (mtn >= MT_TOT) break;
#pragma unroll
        for (int kf = 0; kf < KF; kf++) Acur[kf] = Anext[kf];
        mt = mtn;
    }
}

extern "C" void kernel_launch(void* const* d_in, const int* in_sizes, int n_in,
                              void* d_out, int out_size, void* d_ws, size_t ws_size,
                              hipStream_t stream) {
    const float* x    = (const float*)d_in[0];
    const int*   ei   = (const int*)d_in[1];
    const float* W1   = (const float*)d_in[2];
    const float* b1   = (const float*)d_in[3];
    const float* W2   = (const float*)d_in[4];
    const float* b2   = (const float*)d_in[5];
    const float* Wout = (const float*)d_in[6];
    const float* bout = (const float*)d_in[7];
    float* out = (float*)d_out;

    const int* src = ei;            // edge_index[0]
    const int* dst = ei + N_EDGES;  // edge_index[1]

    // workspace (~110 MB)
    char* ws = (char*)d_ws;
    size_t o = 0;
    auto alloc = [&](size_t bytes) { size_t p = o; o = (o + bytes + 255) & ~(size_t)255; return p; };
    int*   cnt    = (int*)(ws + alloc((size_t)N_NODES * 4));
    float* dinv   = (float*)(ws + alloc((size_t)N_NODES * 4));
    int*   rowptr = (int*)(ws + alloc((size_t)(N_NODES + 1) * 4));
    int*   cursor = (int*)(ws + alloc((size_t)N_NODES * 4));
    int*   bsum   = (int*)(ws + alloc((size_t)NB_SCAN * 4));
    int*   boff   = (int*)(ws + alloc((size_t)NB_SCAN * 4));
    uint2* edata  = (uint2*)(ws + alloc((size_t)N_EDGES * 8));
    u16*   xb     = (u16*)(ws + alloc((size_t)N_NODES * F_IN * 2));
    u16*   aggxb  = (u16*)(ws + alloc((size_t)N_NODES * F_IN * 2));
    u16*   h1b    = (u16*)(ws + alloc((size_t)N_NODES * H_DIM * 2));
    u16*   agghb  = (u16*)(ws + alloc((size_t)N_NODES * H_DIM * 2));
    u16*   h2b    = (u16*)(ws + alloc((size_t)N_NODES * H_DIM * 2));
    u16*   W1b    = (u16*)(ws + alloc((size_t)H_DIM * F_IN * 2));
    u16*   W2b    = (u16*)(ws + alloc((size_t)H_DIM * H_DIM * 2));
    u16*   Woutb  = (u16*)(ws + alloc((size_t)C_OUT * H_DIM * 2));

    // CSR build (multi-block scan)
    hipMemsetAsync(cnt, 0, (size_t)N_NODES * 4, stream);
    count_k<<<(N_EDGES + 255) / 256, 256, 0, stream>>>(dst, cnt, N_EDGES);
    scan1_k<<<NB_SCAN, 256, 0, stream>>>(cnt, dinv, rowptr, bsum);
    scan2_k<<<1, 256, 0, stream>>>(bsum, boff, rowptr);
    scan3_k<<<NB_SCAN, 256, 0, stream>>>(rowptr, cursor, boff);
    bucket_k<<<(N_EDGES + 255) / 256, 256, 0, stream>>>(src, dst, dinv, cursor, edata, N_EDGES);

    // fp32 -> bf16 conversions
    cvt_all_k<<<(CVT_TOT + 255) / 256, 256, 0, stream>>>(
        (const float4*)x, (uint2*)xb, (const float4*)W1, (uint2*)W1b,
        (const float4*)W2, (uint2*)W2b, (const float4*)Wout, (uint2*)Woutb);

    // layer 1 (aggregate-first): aggx = A*xb ; h1 = relu(aggx@W1^T + b1)
    gather1_k<<<(N_NODES + 3) / 4, 256, 0, stream>>>((const u32*)xb, rowptr, edata, dinv, (u32*)aggxb);
    bgemm_k<F_IN, 4, true, false><<<dim3(768, 1), 256, 0, stream>>>(aggxb, W1b, b1, h1b, H_DIM - 1, H_DIM);

    // layer 2: aggh = A*h1 ; h2 = aggh@W2^T + b2
    gather2_k<<<(N_NODES + 3) / 4, 256, 0, stream>>>((const uint2*)h1b, rowptr, edata, dinv, (uint2*)agghb);
    bgemm_k<H_DIM, 2, false, false><<<dim3(768, 2), 256, 0, stream>>>(agghb, W2b, b2, h2b, H_DIM - 1, H_DIM);

    // head: out = h2@Wout^T + bout (fp32 out)
    bgemm_k<H_DIM, 1, false, true><<<dim3(512, 1), 256, 0, stream>>>(h2b, Woutb, bout, out, C_OUT - 1, C_OUT);
}

// Round 11
// 304.284 us; speedup vs baseline: 2.7802x; 1.0881x over previous
//
#include <hip/hip_runtime.h>

#define N_NODES 50000
#define N_EDGES 800000
#define F_IN    128
#define H_DIM   256
#define C_OUT   40
#define NB_SCAN ((N_NODES + 255) / 256)   // 196
#define MT_TOT  (N_NODES / 16)            // 3125 m-tiles
#define CNT_BLKS (N_EDGES / 256)          // 3125

typedef unsigned short u16;
typedef unsigned int   u32;
typedef short bf16x8 __attribute__((ext_vector_type(8)));
typedef float f32x4  __attribute__((ext_vector_type(4)));

__device__ inline float bfbits2f(u16 u) { return __uint_as_float(((u32)u) << 16); }
__device__ inline u16 f2bf(float f) {
    u32 u = __float_as_uint(f);
    u += 0x7fffu + ((u >> 16) & 1u);   // RNE
    return (u16)(u >> 16);
}
__device__ inline u32 pack2(float a, float b) {
    return (u32)f2bf(a) | ((u32)f2bf(b) << 16);
}

// ---- fused: in-degree count (blocks 0..3124) + fp32->bf16 cvt (rest) ----
#define CVT_X  (N_NODES * F_IN / 4)
#define CVT_W1 (H_DIM * F_IN / 4)
#define CVT_W2 (H_DIM * H_DIM / 4)
#define CVT_WO (C_OUT * H_DIM / 4)
#define CVT_TOT (CVT_X + CVT_W1 + CVT_W2 + CVT_WO)   // 1,627,136 = 6356*256
__global__ __launch_bounds__(256) void cc_k(const int* __restrict__ dst, int* __restrict__ cnt,
                                            const float4* __restrict__ x, uint2* __restrict__ xb,
                                            const float4* __restrict__ W1, uint2* __restrict__ W1b,
                                            const float4* __restrict__ W2, uint2* __restrict__ W2b,
                                            const float4* __restrict__ Wo, uint2* __restrict__ Wob) {
    if (blockIdx.x < CNT_BLKS) {
        int i = blockIdx.x * 256 + threadIdx.x;
        atomicAdd(&cnt[dst[i]], 1);
        return;
    }
    int i = (blockIdx.x - CNT_BLKS) * 256 + threadIdx.x;
    const float4* s; uint2* d; int j;
    if (i < CVT_X) { s = x; d = xb; j = i; }
    else if (i < CVT_X + CVT_W1) { s = W1; d = W1b; j = i - CVT_X; }
    else if (i < CVT_X + CVT_W1 + CVT_W2) { s = W2; d = W2b; j = i - CVT_X - CVT_W1; }
    else if (i < CVT_TOT) { s = Wo; d = Wob; j = i - CVT_X - CVT_W1 - CVT_W2; }
    else return;
    float4 v = s[j];
    uint2 o; o.x = pack2(v.x, v.y); o.y = pack2(v.z, v.w);
    d[j] = o;
}

// ---- scan phase 1 ----
__global__ __launch_bounds__(256) void scan1_k(const int* __restrict__ cnt,
                                               float* __restrict__ dinv,
                                               int* __restrict__ rowptr,
                                               int* __restrict__ bsum) {
    __shared__ int sh[256];
    const int t = threadIdx.x;
    const int i = blockIdx.x * 256 + t;
    int c = (i < N_NODES) ? cnt[i] : 0;
    if (i < N_NODES) dinv[i] = rsqrtf((float)c + 1.0f);
    sh[t] = c;
    __syncthreads();
    for (int off = 1; off < 256; off <<= 1) {
        int v = (t >= off) ? sh[t - off] : 0;
        __syncthreads();
        sh[t] += v;
        __syncthreads();
    }
    if (i < N_NODES) rowptr[i] = sh[t] - c;
    if (t == 255) bsum[blockIdx.x] = sh[255];
}

// ---- scan phase 2 ----
__global__ __launch_bounds__(256) void scan2_k(const int* __restrict__ bsum,
                                               int* __restrict__ boff,
                                               int* __restrict__ rowptr) {
    __shared__ int sh[256];
    const int t = threadIdx.x;
    int c = (t < NB_SCAN) ? bsum[t] : 0;
    sh[t] = c;
    __syncthreads();
    for (int off = 1; off < 256; off <<= 1) {
        int v = (t >= off) ? sh[t - off] : 0;
        __syncthreads();
        sh[t] += v;
        __syncthreads();
    }
    if (t < NB_SCAN) boff[t] = sh[t] - c;
    if (t == 0) rowptr[N_NODES] = N_EDGES;
}

// ---- scan phase 3 ----
__global__ __launch_bounds__(256) void scan3_k(int* __restrict__ rowptr,
                                               int* __restrict__ cursor,
                                               const int* __restrict__ boff) {
    const int i = blockIdx.x * 256 + threadIdx.x;
    if (i < N_NODES) {
        int r = rowptr[i] + boff[blockIdx.x];
        rowptr[i] = r;
        cursor[i] = r;
    }
}

// ---- bucket edges by dst; store {src, norm} packed per edge ----
__global__ __launch_bounds__(256) void bucket_k(const int* __restrict__ src, const int* __restrict__ dst,
                                                const float* __restrict__ dinv,
                                                int* __restrict__ cursor, uint2* __restrict__ edata, int E) {
    int i = blockIdx.x * 256 + threadIdx.x;
    if (i < E) {
        const int s = src[i], d = dst[i];
        int pos = atomicAdd(&cursor[d], 1);
        uint2 ed;
        ed.x = (u32)s;
        ed.y = __float_as_uint(dinv[s] * dinv[d]);
        edata[pos] = ed;
    }
}

// ---- gather width-128 bf16, one wave per node, unroll x8, scalar edata path ----
__global__ __launch_bounds__(256) void gather1_k(const u32* __restrict__ xb,
                                                 const int* __restrict__ rowptr,
                                                 const uint2* __restrict__ edata,
                                                 const float* __restrict__ dinv,
                                                 u32* __restrict__ aggx) {
    const int node = __builtin_amdgcn_readfirstlane(blockIdx.x * 4 + (threadIdx.x >> 6));
    const int lane = threadIdx.x & 63;
    if (node >= N_NODES) return;
    const int beg = __builtin_amdgcn_readfirstlane(rowptr[node]);
    const int end = __builtin_amdgcn_readfirstlane(rowptr[node + 1]);
    const float dd = dinv[node];
    const u32 vs = xb[(size_t)node * 64 + lane];
    float a0 = dd * dd * bfbits2f((u16)vs);
    float a1 = dd * dd * bfbits2f((u16)(vs >> 16));
    int e = beg;
    for (; e + 7 < end; e += 8) {
        uint2 ed[8];
#pragma unroll
        for (int j = 0; j < 8; j++) ed[j] = edata[e + j];
        u32 v[8];
#pragma unroll
        for (int j = 0; j < 8; j++) v[j] = xb[(size_t)ed[j].x * 64 + lane];
#pragma unroll
        for (int j = 0; j < 8; j++) {
            const float n = __uint_as_float(ed[j].y);
            a0 += n * bfbits2f((u16)v[j]);
            a1 += n * bfbits2f((u16)(v[j] >> 16));
        }
    }
    for (; e < end; e++) {
        const uint2 e0 = edata[e];
        const u32 v0 = xb[(size_t)e0.x * 64 + lane];
        const float n0 = __uint_as_float(e0.y);
        a0 += n0 * bfbits2f((u16)v0);
        a1 += n0 * bfbits2f((u16)(v0 >> 16));
    }
    aggx[(size_t)node * 64 + lane] = pack2(a0, a1);
}

// ---- gather width-256 bf16, one wave per node, uint2 loads, unroll x8, scalar edata ----
__global__ __launch_bounds__(256) void gather2_k(const uint2* __restrict__ hb,
                                                 const int* __restrict__ rowptr,
                                                 const uint2* __restrict__ edata,
                                                 const float* __restrict__ dinv,
                                                 uint2* __restrict__ agg) {
    const int node = __builtin_amdgcn_readfirstlane(blockIdx.x * 4 + (threadIdx.x >> 6));
    const int lane = threadIdx.x & 63;
    if (node >= N_NODES) return;
    const int beg = __builtin_amdgcn_readfirstlane(rowptr[node]);
    const int end = __builtin_amdgcn_readfirstlane(rowptr[node + 1]);
    const float dd = dinv[node];
    const uint2 vs = hb[(size_t)node * 64 + lane];
    const float ss = dd * dd;
    float a0 = ss * bfbits2f((u16)vs.x);
    float a1 = ss * bfbits2f((u16)(vs.x >> 16));
    float a2 = ss * bfbits2f((u16)vs.y);
    float a3 = ss * bfbits2f((u16)(vs.y >> 16));
    int e = beg;
    for (; e + 7 < end; e += 8) {
        uint2 ed[8];
#pragma unroll
        for (int j = 0; j < 8; j++) ed[j] = edata[e + j];
        uint2 v[8];
#pragma unroll
        for (int j = 0; j < 8; j++) v[j] = hb[(size_t)ed[j].x * 64 + lane];
#pragma unroll
        for (int j = 0; j < 8; j++) {
            const float n = __uint_as_float(ed[j].y);
            a0 += n * bfbits2f((u16)v[j].x); a1 += n * bfbits2f((u16)(v[j].x >> 16));
            a2 += n * bfbits2f((u16)v[j].y); a3 += n * bfbits2f((u16)(v[j].y >> 16));
        }
    }
    for (; e < end; e++) {
        const uint2 e0 = edata[e];
        const uint2 v0 = hb[(size_t)e0.x * 64 + lane];
        const float n0 = __uint_as_float(e0.y);
        a0 += n0 * bfbits2f((u16)v0.x); a1 += n0 * bfbits2f((u16)(v0.x >> 16));
        a2 += n0 * bfbits2f((u16)v0.y); a3 += n0 * bfbits2f((u16)(v0.y >> 16));
    }
    uint2 o; o.x = pack2(a0, a1); o.y = pack2(a2, a3);
    agg[(size_t)node * 64 + lane] = o;
}

// ---- B-stationary MFMA GEMM (layer 1, validated round 7) ----
template<int K, int NTW, bool RELU>
__global__ __launch_bounds__(256) void bgemm_k(const u16* __restrict__ X,
                                               const u16* __restrict__ W,
                                               const float* __restrict__ bias,
                                               u16* __restrict__ Y) {
    constexpr int KF = K / 32;
    const int wave = threadIdx.x >> 6;
    const int lane = threadIdx.x & 63;
    const int quad = lane >> 4;
    const int nn = lane & 15;
    const int ngbase = wave * (NTW * 16);

    bf16x8 Bf[NTW][KF];
    float bb[NTW];
#pragma unroll
    for (int j = 0; j < NTW; j++) {
        const int wr = ngbase + j * 16 + nn;
#pragma unroll
        for (int kf = 0; kf < KF; kf++)
            Bf[j][kf] = *(const bf16x8*)(W + (size_t)wr * K + kf * 32 + quad * 8);
        bb[j] = bias[wr];
    }

    int mt = blockIdx.x;
    if (mt >= MT_TOT) return;
    const int stride = gridDim.x;

    bf16x8 Acur[KF], Anext[KF];
    {
        const u16* ap = X + (size_t)(mt * 16 + nn) * K + quad * 8;
#pragma unroll
        for (int kf = 0; kf < KF; kf++) Acur[kf] = *(const bf16x8*)(ap + kf * 32);
    }

    while (true) {
        const int mtn = mt + stride;
        if (mtn < MT_TOT) {
            const u16* ap = X + (size_t)(mtn * 16 + nn) * K + quad * 8;
#pragma unroll
            for (int kf = 0; kf < KF; kf++) Anext[kf] = *(const bf16x8*)(ap + kf * 32);
        }

        f32x4 acc[NTW];
#pragma unroll
        for (int j = 0; j < NTW; j++) acc[j] = (f32x4){0.f, 0.f, 0.f, 0.f};
#pragma unroll
        for (int kf = 0; kf < KF; kf++)
#pragma unroll
            for (int j = 0; j < NTW; j++)
                acc[j] = __builtin_amdgcn_mfma_f32_16x16x32_bf16(Acur[kf], Bf[j][kf], acc[j], 0, 0, 0);

#pragma unroll
        for (int j = 0; j < NTW; j++) {
            const int col = ngbase + j * 16 + nn;
#pragma unroll
            for (int r = 0; r < 4; r++) {
                const int row = mt * 16 + quad * 4 + r;
                float v = acc[j][r] + bb[j];
                if (RELU) v = fmaxf(v, 0.f);
                Y[(size_t)row * H_DIM + col] = f2bf(v);
            }
        }

        if (mtn >= MT_TOT) break;
#pragma unroll
        for (int kf = 0; kf < KF; kf++) Acur[kf] = Anext[kf];
        mt = mtn;
    }
}

// ---- fused layer-2 GEMM + head: h2 tile stays in LDS, logits written directly ----
// per m-tile: 4 waves x NTW=4 cover 256 cols of h2 (single A pass);
// h2 -> LDS bf16 (C-layout write), barrier, A-layout b128 reads feed head MFMA.
__global__ __launch_bounds__(256) void l2f_k(const u16* __restrict__ X,     // agghb
                                             const u16* __restrict__ W2,
                                             const float* __restrict__ b2,
                                             const u16* __restrict__ Wo,
                                             const float* __restrict__ bo,
                                             float* __restrict__ out) {
    constexpr int KF = 8;   // K = 256
    __shared__ __align__(16) u16 hs[2][16][H_DIM + 8];   // +8 pad: <=2-way bank alias (free)
    const int wave = threadIdx.x >> 6;
    const int lane = threadIdx.x & 63;
    const int quad = lane >> 4;
    const int nn = lane & 15;
    const int ngbase = wave * 64;

    // W2 fragments (persistent, cols ngbase..ngbase+63)
    bf16x8 Bf[4][KF];
    float bb[4];
#pragma unroll
    for (int j = 0; j < 4; j++) {
        const int wr = ngbase + j * 16 + nn;
#pragma unroll
        for (int kf = 0; kf < KF; kf++)
            Bf[j][kf] = *(const bf16x8*)(W2 + (size_t)wr * H_DIM + kf * 32 + quad * 8);
        bb[j] = b2[wr];
    }
    // Wout fragments: wave w -> head n-tile w (waves 0..2 used; wave 3 clamped/dummy)
    bf16x8 Bh[KF];
    float bh;
    {
        int hr = wave * 16 + nn;
        if (hr > C_OUT - 1) hr = C_OUT - 1;
#pragma unroll
        for (int kf = 0; kf < KF; kf++)
            Bh[kf] = *(const bf16x8*)(Wo + (size_t)hr * H_DIM + kf * 32 + quad * 8);
        const int col = wave * 16 + nn;
        bh = (col < C_OUT) ? bo[col] : 0.f;
    }

    int mt = blockIdx.x;
    if (mt >= MT_TOT) return;
    const int stride = gridDim.x;
    int buf = 0;

    bf16x8 Acur[KF], Anext[KF];
    {
        const u16* ap = X + (size_t)(mt * 16 + nn) * H_DIM + quad * 8;
#pragma unroll
        for (int kf = 0; kf < KF; kf++) Acur[kf] = *(const bf16x8*)(ap + kf * 32);
    }

    while (true) {
        const int mtn = mt + stride;
        if (mtn < MT_TOT) {
            const u16* ap = X + (size_t)(mtn * 16 + nn) * H_DIM + quad * 8;
#pragma unroll
            for (int kf = 0; kf < KF; kf++) Anext[kf] = *(const bf16x8*)(ap + kf * 32);
        }

        f32x4 acc[4];
#pragma unroll
        for (int j = 0; j < 4; j++) acc[j] = (f32x4){0.f, 0.f, 0.f, 0.f};
#pragma unroll
        for (int kf = 0; kf < KF; kf++)
#pragma unroll
            for (int j = 0; j < 4; j++)
                acc[j] = __builtin_amdgcn_mfma_f32_16x16x32_bf16(Acur[kf], Bf[j][kf], acc[j], 0, 0, 0);

        // h2 tile -> LDS (bf16): C-layout row = quad*4+r, col = ngbase + j*16 + nn
#pragma unroll
        for (int j = 0; j < 4; j++)
#pragma unroll
            for (int r = 0; r < 4; r++)
                hs[buf][quad * 4 + r][ngbase + j * 16 + nn] = f2bf(acc[j][r] + bb[j]);
        __syncthreads();

        // head: A-frag A[m=nn][k=kf*32+quad*8+j] from LDS (16B contiguous -> ds_read_b128)
        f32x4 ah = (f32x4){0.f, 0.f, 0.f, 0.f};
#pragma unroll
        for (int kf = 0; kf < KF; kf++) {
            bf16x8 af = *(const bf16x8*)(&hs[buf][nn][kf * 32 + quad * 8]);
            ah = __builtin_amdgcn_mfma_f32_16x16x32_bf16(af, Bh[kf], ah, 0, 0, 0);
        }
        if (wave < 3) {
            const int col = wave * 16 + nn;
            if (col < C_OUT) {
#pragma unroll
                for (int r = 0; r < 4; r++) {
                    const int row = mt * 16 + quad * 4 + r;
                    out[(size_t)row * C_OUT + col] = ah[r] + bh;
                }
            }
        }

        if (mtn >= MT_TOT) break;
#pragma unroll
        for (int kf = 0; kf < KF; kf++) Acur[kf] = Anext[kf];
        mt = mtn;
        buf ^= 1;
    }
}

extern "C" void kernel_launch(void* const* d_in, const int* in_sizes, int n_in,
                              void* d_out, int out_size, void* d_ws, size_t ws_size,
                              hipStream_t stream) {
    const float* x    = (const float*)d_in[0];
    const int*   ei   = (const int*)d_in[1];
    const float* W1   = (const float*)d_in[2];
    const float* b1   = (const float*)d_in[3];
    const float* W2   = (const float*)d_in[4];
    const float* b2   = (const float*)d_in[5];
    const float* Wout = (const float*)d_in[6];
    const float* bout = (const float*)d_in[7];
    float* out = (float*)d_out;

    const int* src = ei;            // edge_index[0]
    const int* dst = ei + N_EDGES;  // edge_index[1]

    // workspace (~85 MB)
    char* ws = (char*)d_ws;
    size_t o = 0;
    auto alloc = [&](size_t bytes) { size_t p = o; o = (o + bytes + 255) & ~(size_t)255; return p; };
    int*   cnt    = (int*)(ws + alloc((size_t)N_NODES * 4));
    float* dinv   = (float*)(ws + alloc((size_t)N_NODES * 4));
    int*   rowptr = (int*)(ws + alloc((size_t)(N_NODES + 1) * 4));
    int*   cursor = (int*)(ws + alloc((size_t)N_NODES * 4));
    int*   bsum   = (int*)(ws + alloc((size_t)NB_SCAN * 4));
    int*   boff   = (int*)(ws + alloc((size_t)NB_SCAN * 4));
    uint2* edata  = (uint2*)(ws + alloc((size_t)N_EDGES * 8));
    u16*   xb     = (u16*)(ws + alloc((size_t)N_NODES * F_IN * 2));
    u16*   aggxb  = (u16*)(ws + alloc((size_t)N_NODES * F_IN * 2));
    u16*   h1b    = (u16*)(ws + alloc((size_t)N_NODES * H_DIM * 2));
    u16*   agghb  = (u16*)(ws + alloc((size_t)N_NODES * H_DIM * 2));
    u16*   W1b    = (u16*)(ws + alloc((size_t)H_DIM * F_IN * 2));
    u16*   W2b    = (u16*)(ws + alloc((size_t)H_DIM * H_DIM * 2));
    u16*   Woutb  = (u16*)(ws + alloc((size_t)C_OUT * H_DIM * 2));

    // CSR build + conversions (count and cvt fused: independent work)
    hipMemsetAsync(cnt, 0, (size_t)N_NODES * 4, stream);
    cc_k<<<CNT_BLKS + CVT_TOT / 256, 256, 0, stream>>>(
        dst, cnt,
        (const float4*)x, (uint2*)xb, (const float4*)W1, (uint2*)W1b,
        (const float4*)W2, (uint2*)W2b, (const float4*)Wout, (uint2*)Woutb);
    scan1_k<<<NB_SCAN, 256, 0, stream>>>(cnt, dinv, rowptr, bsum);
    scan2_k<<<1, 256, 0, stream>>>(bsum, boff, rowptr);
    scan3_k<<<NB_SCAN, 256, 0, stream>>>(rowptr, cursor, boff);
    bucket_k<<<(N_EDGES + 255) / 256, 256, 0, stream>>>(src, dst, dinv, cursor, edata, N_EDGES);

    // layer 1 (aggregate-first): aggx = A*xb ; h1 = relu(aggx@W1^T + b1)
    gather1_k<<<(N_NODES + 3) / 4, 256, 0, stream>>>((const u32*)xb, rowptr, edata, dinv, (u32*)aggxb);
    bgemm_k<F_IN, 4, true><<<768, 256, 0, stream>>>(aggxb, W1b, b1, h1b);

    // layer 2 + head fused: aggh = A*h1 ; out = (aggh@W2^T + b2)@Wout^T + bout
    gather2_k<<<(N_NODES + 3) / 4, 256, 0, stream>>>((const uint2*)h1b, rowptr, edata, dinv, (uint2*)agghb);
    l2f_k<<<768, 256, 0, stream>>>(agghb, W2b, b2, Woutb, bout, out);
}

// Round 12
// 252.643 us; speedup vs baseline: 3.3485x; 1.2044x over previous
//
#include <hip/hip_runtime.h>

#define N_NODES 50000
#define N_EDGES 800000
#define F_IN    128
#define H_DIM   256
#define C_OUT   40
#define NB_SCAN ((N_NODES + 255) / 256)   // 196
#define MT_TOT  (N_NODES / 16)            // 3125 m-tiles
#define CNT_BLKS (N_EDGES / 256)          // 3125
#define TPAD    64                        // t row padded to 64 bf16 (32 u32)

typedef unsigned short u16;
typedef unsigned int   u32;
typedef short bf16x8 __attribute__((ext_vector_type(8)));
typedef float f32x4  __attribute__((ext_vector_type(4)));

__device__ inline float bfbits2f(u16 u) { return __uint_as_float(((u32)u) << 16); }
__device__ inline u16 f2bf(float f) {
    u32 u = __float_as_uint(f);
    u += 0x7fffu + ((u >> 16) & 1u);   // RNE
    return (u16)(u >> 16);
}
__device__ inline u32 pack2(float a, float b) {
    return (u32)f2bf(a) | ((u32)f2bf(b) << 16);
}

// ---- fused: in-degree count | fp32->bf16 cvt (x, W1) | Wc = Wo*W2 precompute ----
#define CVT_X  (N_NODES * F_IN / 4)          // 1,600,000
#define CVT_W1 (H_DIM * F_IN / 4)            // 8192
#define CVT_TOT (CVT_X + CVT_W1)             // 1,608,192 = 6282*256
#define CC_CVT_BLKS (CVT_TOT / 256)          // 6282
__global__ __launch_bounds__(256) void cc_k(const int* __restrict__ dst, int* __restrict__ cnt,
                                            const float4* __restrict__ x, uint2* __restrict__ xb,
                                            const float4* __restrict__ W1, uint2* __restrict__ W1b,
                                            const float* __restrict__ W2, const float* __restrict__ Wo,
                                            const float* __restrict__ b2, const float* __restrict__ bo,
                                            u16* __restrict__ Wcb, float* __restrict__ bc) {
    if (blockIdx.x < CNT_BLKS) {
        int i = blockIdx.x * 256 + threadIdx.x;
        atomicAdd(&cnt[dst[i]], 1);
        return;
    }
    if (blockIdx.x < CNT_BLKS + CC_CVT_BLKS) {
        int i = (blockIdx.x - CNT_BLKS) * 256 + threadIdx.x;
        const float4* s; uint2* d; int j;
        if (i < CVT_X) { s = x; d = xb; j = i; }
        else { s = W1; d = W1b; j = i - CVT_X; }
        float4 v = s[j];
        uint2 o; o.x = pack2(v.x, v.y); o.y = pack2(v.z, v.w);
        d[j] = o;
        return;
    }
    // Wc block: c = blockIdx.x - CNT_BLKS - CC_CVT_BLKS in [0, 40)
    const int c = blockIdx.x - CNT_BLKS - CC_CVT_BLKS;
    const int t = threadIdx.x;                 // 'in' index 0..255
    float acc = 0.f;
    for (int o = 0; o < H_DIM; o += 8) {
        float w2v[8];
#pragma unroll
        for (int j = 0; j < 8; j++) w2v[j] = W2[(size_t)(o + j) * H_DIM + t];
#pragma unroll
        for (int j = 0; j < 8; j++) acc += Wo[(size_t)c * H_DIM + o + j] * w2v[j];
    }
    Wcb[(size_t)c * H_DIM + t] = f2bf(acc);
    // bc[c] = sum_k b2[k]*Wo[c,k] + bo[c]
    __shared__ float red[256];
    red[t] = b2[t] * Wo[(size_t)c * H_DIM + t];
    __syncthreads();
    for (int off = 128; off > 0; off >>= 1) {
        if (t < off) red[t] += red[t + off];
        __syncthreads();
    }
    if (t == 0) bc[c] = red[0] + bo[c];
}

// ---- scan phase 1 ----
__global__ __launch_bounds__(256) void scan1_k(const int* __restrict__ cnt,
                                               float* __restrict__ dinv,
                                               int* __restrict__ rowptr,
                                               int* __restrict__ bsum) {
    __shared__ int sh[256];
    const int t = threadIdx.x;
    const int i = blockIdx.x * 256 + t;
    int c = (i < N_NODES) ? cnt[i] : 0;
    if (i < N_NODES) dinv[i] = rsqrtf((float)c + 1.0f);
    sh[t] = c;
    __syncthreads();
    for (int off = 1; off < 256; off <<= 1) {
        int v = (t >= off) ? sh[t - off] : 0;
        __syncthreads();
        sh[t] += v;
        __syncthreads();
    }
    if (i < N_NODES) rowptr[i] = sh[t] - c;
    if (t == 255) bsum[blockIdx.x] = sh[255];
}

// ---- scan phase 2 ----
__global__ __launch_bounds__(256) void scan2_k(const int* __restrict__ bsum,
                                               int* __restrict__ boff,
                                               int* __restrict__ rowptr) {
    __shared__ int sh[256];
    const int t = threadIdx.x;
    int c = (t < NB_SCAN) ? bsum[t] : 0;
    sh[t] = c;
    __syncthreads();
    for (int off = 1; off < 256; off <<= 1) {
        int v = (t >= off) ? sh[t - off] : 0;
        __syncthreads();
        sh[t] += v;
        __syncthreads();
    }
    if (t < NB_SCAN) boff[t] = sh[t] - c;
    if (t == 0) rowptr[N_NODES] = N_EDGES;
}

// ---- scan phase 3 ----
__global__ __launch_bounds__(256) void scan3_k(int* __restrict__ rowptr,
                                               int* __restrict__ cursor,
                                               const int* __restrict__ boff) {
    const int i = blockIdx.x * 256 + threadIdx.x;
    if (i < N_NODES) {
        int r = rowptr[i] + boff[blockIdx.x];
        rowptr[i] = r;
        cursor[i] = r;
    }
}

// ---- bucket edges by dst; store {src, norm} packed per edge ----
__global__ __launch_bounds__(256) void bucket_k(const int* __restrict__ src, const int* __restrict__ dst,
                                                const float* __restrict__ dinv,
                                                int* __restrict__ cursor, uint2* __restrict__ edata, int E) {
    int i = blockIdx.x * 256 + threadIdx.x;
    if (i < E) {
        const int s = src[i], d = dst[i];
        int pos = atomicAdd(&cursor[d], 1);
        uint2 ed;
        ed.x = (u32)s;
        ed.y = __float_as_uint(dinv[s] * dinv[d]);
        edata[pos] = ed;
    }
}

// ---- gather width-128 bf16, one wave per node, unroll x8, scalar edata path ----
__global__ __launch_bounds__(256) void gather1_k(const u32* __restrict__ xb,
                                                 const int* __restrict__ rowptr,
                                                 const uint2* __restrict__ edata,
                                                 const float* __restrict__ dinv,
                                                 u32* __restrict__ aggx) {
    const int node = __builtin_amdgcn_readfirstlane(blockIdx.x * 4 + (threadIdx.x >> 6));
    const int lane = threadIdx.x & 63;
    if (node >= N_NODES) return;
    const int beg = __builtin_amdgcn_readfirstlane(rowptr[node]);
    const int end = __builtin_amdgcn_readfirstlane(rowptr[node + 1]);
    const float dd = dinv[node];
    const u32 vs = xb[(size_t)node * 64 + lane];
    float a0 = dd * dd * bfbits2f((u16)vs);
    float a1 = dd * dd * bfbits2f((u16)(vs >> 16));
    int e = beg;
    for (; e + 7 < end; e += 8) {
        uint2 ed[8];
#pragma unroll
        for (int j = 0; j < 8; j++) ed[j] = edata[e + j];
        u32 v[8];
#pragma unroll
        for (int j = 0; j < 8; j++) v[j] = xb[(size_t)ed[j].x * 64 + lane];
#pragma unroll
        for (int j = 0; j < 8; j++) {
            const float n = __uint_as_float(ed[j].y);
            a0 += n * bfbits2f((u16)v[j]);
            a1 += n * bfbits2f((u16)(v[j] >> 16));
        }
    }
    for (; e < end; e++) {
        const uint2 e0 = edata[e];
        const u32 v0 = xb[(size_t)e0.x * 64 + lane];
        const float n0 = __uint_as_float(e0.y);
        a0 += n0 * bfbits2f((u16)v0);
        a1 += n0 * bfbits2f((u16)(v0 >> 16));
    }
    aggx[(size_t)node * 64 + lane] = pack2(a0, a1);
}

// ---- fused layer-1 GEMM + t-GEMM: h1 tile lives only in LDS ----
// phase1: h1 = relu(aggx@W1^T + b1) per 16-row tile (4 waves x 4 n-tiles = 256 cols)
// phase2: t = h1_tile @ Wc^T (48 cols, waves 0..2), stored bf16 to tb [N][TPAD]
__global__ __launch_bounds__(256) void bgemm1f_k(const u16* __restrict__ X,      // aggxb [N][128]
                                                 const u16* __restrict__ W1b,
                                                 const float* __restrict__ b1,
                                                 const u16* __restrict__ Wcb,    // [40][256] bf16
                                                 u16* __restrict__ tb) {         // [N][TPAD]
    constexpr int KF1 = F_IN / 32;   // 4
    constexpr int KF2 = H_DIM / 32;  // 8
    __shared__ __align__(16) u16 hs[2][16][H_DIM + 8];
    const int wave = threadIdx.x >> 6;
    const int lane = threadIdx.x & 63;
    const int quad = lane >> 4;
    const int nn = lane & 15;
    const int ngbase = wave * 64;

    // W1 fragments (persistent)
    bf16x8 Bf[4][KF1];
    float bb[4];
#pragma unroll
    for (int j = 0; j < 4; j++) {
        const int wr = ngbase + j * 16 + nn;
#pragma unroll
        for (int kf = 0; kf < KF1; kf++)
            Bf[j][kf] = *(const bf16x8*)(W1b + (size_t)wr * F_IN + kf * 32 + quad * 8);
        bb[j] = b1[wr];
    }
    // Wc fragments: wave w covers t n-tile w (waves 0..2 real)
    bf16x8 Bh[KF2];
    {
        int hr = wave * 16 + nn;
        if (hr > C_OUT - 1) hr = C_OUT - 1;
#pragma unroll
        for (int kf = 0; kf < KF2; kf++)
            Bh[kf] = *(const bf16x8*)(Wcb + (size_t)hr * H_DIM + kf * 32 + quad * 8);
    }

    int mt = blockIdx.x;
    if (mt >= MT_TOT) return;
    const int stride = gridDim.x;
    int buf = 0;

    bf16x8 Acur[KF1], Anext[KF1];
    {
        const u16* ap = X + (size_t)(mt * 16 + nn) * F_IN + quad * 8;
#pragma unroll
        for (int kf = 0; kf < KF1; kf++) Acur[kf] = *(const bf16x8*)(ap + kf * 32);
    }

    while (true) {
        const int mtn = mt + stride;
        if (mtn < MT_TOT) {
            const u16* ap = X + (size_t)(mtn * 16 + nn) * F_IN + quad * 8;
#pragma unroll
            for (int kf = 0; kf < KF1; kf++) Anext[kf] = *(const bf16x8*)(ap + kf * 32);
        }

        f32x4 acc[4];
#pragma unroll
        for (int j = 0; j < 4; j++) acc[j] = (f32x4){0.f, 0.f, 0.f, 0.f};
#pragma unroll
        for (int kf = 0; kf < KF1; kf++)
#pragma unroll
            for (int j = 0; j < 4; j++)
                acc[j] = __builtin_amdgcn_mfma_f32_16x16x32_bf16(Acur[kf], Bf[j][kf], acc[j], 0, 0, 0);

        // h1 tile -> LDS (bf16, relu+bias): row = quad*4+r, col = ngbase + j*16 + nn
#pragma unroll
        for (int j = 0; j < 4; j++)
#pragma unroll
            for (int r = 0; r < 4; r++)
                hs[buf][quad * 4 + r][ngbase + j * 16 + nn] = f2bf(fmaxf(acc[j][r] + bb[j], 0.f));
        __syncthreads();

        // t = h1_tile @ Wc^T
        if (wave < 3) {
            f32x4 ah = (f32x4){0.f, 0.f, 0.f, 0.f};
#pragma unroll
            for (int kf = 0; kf < KF2; kf++) {
                bf16x8 af = *(const bf16x8*)(&hs[buf][nn][kf * 32 + quad * 8]);
                ah = __builtin_amdgcn_mfma_f32_16x16x32_bf16(af, Bh[kf], ah, 0, 0, 0);
            }
            const int col = wave * 16 + nn;   // 0..47
#pragma unroll
            for (int r = 0; r < 4; r++) {
                const int row = mt * 16 + quad * 4 + r;
                tb[(size_t)row * TPAD + col] = f2bf(ah[r]);
            }
        }

        if (mtn >= MT_TOT) break;
#pragma unroll
        for (int kf = 0; kf < KF1; kf++) Acur[kf] = Anext[kf];
        mt = mtn;
        buf ^= 1;
    }
}

// ---- final gather at width 40 (padded 64): out = A_hat * t + bc ----
__global__ __launch_bounds__(256) void gatherO_k(const u32* __restrict__ tb,     // [N][TPAD/2]
                                                 const int* __restrict__ rowptr,
                                                 const uint2* __restrict__ edata,
                                                 const float* __restrict__ dinv,
                                                 const float* __restrict__ bc,
                                                 float* __restrict__ out) {
    const int node = __builtin_amdgcn_readfirstlane(blockIdx.x * 4 + (threadIdx.x >> 6));
    const int lane = threadIdx.x & 63;
    if (node >= N_NODES) return;
    const int lc = lane & 31;                  // u32 col 0..31 (lanes 32-63 mirror)
    const int beg = __builtin_amdgcn_readfirstlane(rowptr[node]);
    const int end = __builtin_amdgcn_readfirstlane(rowptr[node + 1]);
    const float dd = dinv[node];
    const u32 vs = tb[(size_t)node * (TPAD / 2) + lc];
    float a0 = dd * dd * bfbits2f((u16)vs);
    float a1 = dd * dd * bfbits2f((u16)(vs >> 16));
    int e = beg;
    for (; e + 7 < end; e += 8) {
        uint2 ed[8];
#pragma unroll
        for (int j = 0; j < 8; j++) ed[j] = edata[e + j];
        u32 v[8];
#pragma unroll
        for (int j = 0; j < 8; j++) v[j] = tb[(size_t)ed[j].x * (TPAD / 2) + lc];
#pragma unroll
        for (int j = 0; j < 8; j++) {
            const float n = __uint_as_float(ed[j].y);
            a0 += n * bfbits2f((u16)v[j]);
            a1 += n * bfbits2f((u16)(v[j] >> 16));
        }
    }
    for (; e < end; e++) {
        const uint2 e0 = edata[e];
        const u32 v0 = tb[(size_t)e0.x * (TPAD / 2) + lc];
        const float n0 = __uint_as_float(e0.y);
        a0 += n0 * bfbits2f((u16)v0);
        a1 += n0 * bfbits2f((u16)(v0 >> 16));
    }
    if (lane < C_OUT / 2) {
        float2 o;
        o.x = a0 + bc[2 * lane];
        o.y = a1 + bc[2 * lane + 1];
        *(float2*)(out + (size_t)node * C_OUT + 2 * lane) = o;
    }
}

extern "C" void kernel_launch(void* const* d_in, const int* in_sizes, int n_in,
                              void* d_out, int out_size, void* d_ws, size_t ws_size,
                              hipStream_t stream) {
    const float* x    = (const float*)d_in[0];
    const int*   ei   = (const int*)d_in[1];
    const float* W1   = (const float*)d_in[2];
    const float* b1   = (const float*)d_in[3];
    const float* W2   = (const float*)d_in[4];
    const float* b2   = (const float*)d_in[5];
    const float* Wout = (const float*)d_in[6];
    const float* bout = (const float*)d_in[7];
    float* out = (float*)d_out;

    const int* src = ei;            // edge_index[0]
    const int* dst = ei + N_EDGES;  // edge_index[1]

    // workspace (~40 MB)
    char* ws = (char*)d_ws;
    size_t o = 0;
    auto alloc = [&](size_t bytes) { size_t p = o; o = (o + bytes + 255) & ~(size_t)255; return p; };
    int*   cnt    = (int*)(ws + alloc((size_t)N_NODES * 4));
    float* dinv   = (float*)(ws + alloc((size_t)N_NODES * 4));
    int*   rowptr = (int*)(ws + alloc((size_t)(N_NODES + 1) * 4));
    int*   cursor = (int*)(ws + alloc((size_t)N_NODES * 4));
    int*   bsum   = (int*)(ws + alloc((size_t)NB_SCAN * 4));
    int*   boff   = (int*)(ws + alloc((size_t)NB_SCAN * 4));
    uint2* edata  = (uint2*)(ws + alloc((size_t)N_EDGES * 8));          // 6.4 MB
    u16*   xb     = (u16*)(ws + alloc((size_t)N_NODES * F_IN * 2));     // 12.8 MB
    u16*   aggxb  = (u16*)(ws + alloc((size_t)N_NODES * F_IN * 2));     // 12.8 MB
    u16*   tb     = (u16*)(ws + alloc((size_t)N_NODES * TPAD * 2));     // 6.4 MB
    u16*   W1b    = (u16*)(ws + alloc((size_t)H_DIM * F_IN * 2));
    u16*   Wcb    = (u16*)(ws + alloc((size_t)C_OUT * H_DIM * 2));
    float* bc     = (float*)(ws + alloc((size_t)C_OUT * 4));

    // count + cvt(x, W1) + Wc precompute, all fused
    hipMemsetAsync(cnt, 0, (size_t)N_NODES * 4, stream);
    cc_k<<<CNT_BLKS + CC_CVT_BLKS + C_OUT, 256, 0, stream>>>(
        dst, cnt,
        (const float4*)x, (uint2*)xb, (const float4*)W1, (uint2*)W1b,
        W2, Wout, b2, bout, Wcb, bc);
    scan1_k<<<NB_SCAN, 256, 0, stream>>>(cnt, dinv, rowptr, bsum);
    scan2_k<<<1, 256, 0, stream>>>(bsum, boff, rowptr);
    scan3_k<<<NB_SCAN, 256, 0, stream>>>(rowptr, cursor, boff);
    bucket_k<<<(N_EDGES + 255) / 256, 256, 0, stream>>>(src, dst, dinv, cursor, edata, N_EDGES);

    // layer 1 aggregate-first: aggx = A_hat * xb
    gather1_k<<<(N_NODES + 3) / 4, 256, 0, stream>>>((const u32*)xb, rowptr, edata, dinv, (u32*)aggxb);
    // fused: h1 = relu(aggx@W1^T+b1) [LDS only] ; t = h1@Wc^T -> tb
    bgemm1f_k<<<768, 256, 0, stream>>>(aggxb, W1b, b1, Wcb, tb);
    // final: out = A_hat * t + bc
    gatherO_k<<<(N_NODES + 3) / 4, 256, 0, stream>>>((const u32*)tb, rowptr, edata, dinv, bc, out);
}

// Round 13
// 241.273 us; speedup vs baseline: 3.5063x; 1.0471x over previous
//
#include <hip/hip_runtime.h>

#define N_NODES 50000
#define N_EDGES 800000
#define F_IN    128
#define H_DIM   256
#define C_OUT   40
#define NB_SCAN ((N_NODES + 255) / 256)   // 196
#define MT_TOT  (N_NODES / 16)            // 3125 m-tiles
#define CNT_BLKS (N_EDGES / 256)          // 3125
#define TPAD    64                        // t row padded to 64 bf16 (32 u32)
#define NREP    8                         // atomic-counter replicas (one per XCD-ish)
#define N_PAD   50176                     // N_NODES rounded to 256

typedef unsigned short u16;
typedef unsigned int   u32;
typedef short bf16x8 __attribute__((ext_vector_type(8)));
typedef float f32x4  __attribute__((ext_vector_type(4)));

__device__ inline float bfbits2f(u16 u) { return __uint_as_float(((u32)u) << 16); }
__device__ inline u16 f2bf(float f) {
    u32 u = __float_as_uint(f);
    u += 0x7fffu + ((u >> 16) & 1u);   // RNE
    return (u16)(u >> 16);
}
__device__ inline u32 pack2(float a, float b) {
    return (u32)f2bf(a) | ((u32)f2bf(b) << 16);
}

// ---- fused: sharded in-degree count | fp32->bf16 cvt (x, W1) | Wc = Wo*W2 ----
#define CVT_X  (N_NODES * F_IN / 4)          // 1,600,000
#define CVT_W1 (H_DIM * F_IN / 4)            // 8192
#define CVT_TOT (CVT_X + CVT_W1)             // 1,608,192 = 6282*256
#define CC_CVT_BLKS (CVT_TOT / 256)          // 6282
__global__ __launch_bounds__(256) void cc_k(const int* __restrict__ dst, int* __restrict__ cnt,
                                            const float4* __restrict__ x, uint2* __restrict__ xb,
                                            const float4* __restrict__ W1, uint2* __restrict__ W1b,
                                            const float* __restrict__ W2, const float* __restrict__ Wo,
                                            const float* __restrict__ b2, const float* __restrict__ bo,
                                            u16* __restrict__ Wcb, float* __restrict__ bc) {
    if (blockIdx.x < CNT_BLKS) {
        int i = blockIdx.x * 256 + threadIdx.x;
        atomicAdd(&cnt[(blockIdx.x & (NREP - 1)) * N_PAD + dst[i]], 1);
        return;
    }
    if (blockIdx.x < CNT_BLKS + CC_CVT_BLKS) {
        int i = (blockIdx.x - CNT_BLKS) * 256 + threadIdx.x;
        const float4* s; uint2* d; int j;
        if (i < CVT_X) { s = x; d = xb; j = i; }
        else { s = W1; d = W1b; j = i - CVT_X; }
        float4 v = s[j];
        uint2 o; o.x = pack2(v.x, v.y); o.y = pack2(v.z, v.w);
        d[j] = o;
        return;
    }
    // Wc block: c in [0, 40)
    const int c = blockIdx.x - CNT_BLKS - CC_CVT_BLKS;
    const int t = threadIdx.x;                 // 'in' index 0..255
    float acc = 0.f;
    for (int o = 0; o < H_DIM; o += 8) {
        float w2v[8];
#pragma unroll
        for (int j = 0; j < 8; j++) w2v[j] = W2[(size_t)(o + j) * H_DIM + t];
#pragma unroll
        for (int j = 0; j < 8; j++) acc += Wo[(size_t)c * H_DIM + o + j] * w2v[j];
    }
    Wcb[(size_t)c * H_DIM + t] = f2bf(acc);
    __shared__ float red[256];
    red[t] = b2[t] * Wo[(size_t)c * H_DIM + t];
    __syncthreads();
    for (int off = 128; off > 0; off >>= 1) {
        if (t < off) red[t] += red[t + off];
        __syncthreads();
    }
    if (t == 0) bc[c] = red[0] + bo[c];
}

// ---- scan phase 1: sum replicas, dinv, block-local exclusive scan ----
__global__ __launch_bounds__(256) void scan1_k(const int* __restrict__ cnt,
                                               float* __restrict__ dinv,
                                               int* __restrict__ rowptr,
                                               int* __restrict__ bsum) {
    __shared__ int sh[256];
    const int t = threadIdx.x;
    const int i = blockIdx.x * 256 + t;
    int c = 0;
    if (i < N_NODES) {
#pragma unroll
        for (int r = 0; r < NREP; r++) c += cnt[r * N_PAD + i];
        dinv[i] = rsqrtf((float)c + 1.0f);
    }
    sh[t] = c;
    __syncthreads();
    for (int off = 1; off < 256; off <<= 1) {
        int v = (t >= off) ? sh[t - off] : 0;
        __syncthreads();
        sh[t] += v;
        __syncthreads();
    }
    if (i < N_NODES) rowptr[i] = sh[t] - c;
    if (t == 255) bsum[blockIdx.x] = sh[255];
}

// ---- scan phase 2 ----
__global__ __launch_bounds__(256) void scan2_k(const int* __restrict__ bsum,
                                               int* __restrict__ boff,
                                               int* __restrict__ rowptr) {
    __shared__ int sh[256];
    const int t = threadIdx.x;
    int c = (t < NB_SCAN) ? bsum[t] : 0;
    sh[t] = c;
    __syncthreads();
    for (int off = 1; off < 256; off <<= 1) {
        int v = (t >= off) ? sh[t - off] : 0;
        __syncthreads();
        sh[t] += v;
        __syncthreads();
    }
    if (t < NB_SCAN) boff[t] = sh[t] - c;
    if (t == 0) rowptr[N_NODES] = N_EDGES;
}

// ---- scan phase 3: finalize rowptr, lay out per-replica cursor bases ----
__global__ __launch_bounds__(256) void scan3_k(int* __restrict__ rowptr,
                                               int* __restrict__ cursor,
                                               const int* __restrict__ cnt,
                                               const int* __restrict__ boff) {
    const int i = blockIdx.x * 256 + threadIdx.x;
    if (i < N_NODES) {
        const int base = rowptr[i] + boff[blockIdx.x];
        rowptr[i] = base;
        int running = base;
#pragma unroll
        for (int r = 0; r < NREP; r++) {
            cursor[r * N_PAD + i] = running;
            running += cnt[r * N_PAD + i];
        }
    }
}

// ---- bucket edges by dst (sharded cursor); store {src, norm} per edge ----
__global__ __launch_bounds__(256) void bucket_k(const int* __restrict__ src, const int* __restrict__ dst,
                                                const float* __restrict__ dinv,
                                                int* __restrict__ cursor, uint2* __restrict__ edata, int E) {
    int i = blockIdx.x * 256 + threadIdx.x;
    if (i < E) {
        const int s = src[i], d = dst[i];
        int pos = atomicAdd(&cursor[(blockIdx.x & (NREP - 1)) * N_PAD + d], 1);
        uint2 ed;
        ed.x = (u32)s;
        ed.y = __float_as_uint(dinv[s] * dinv[d]);
        edata[pos] = ed;
    }
}

// ---- gather width-128 bf16, one wave per node, unroll x8, scalar edata path ----
__global__ __launch_bounds__(256) void gather1_k(const u32* __restrict__ xb,
                                                 const int* __restrict__ rowptr,
                                                 const uint2* __restrict__ edata,
                                                 const float* __restrict__ dinv,
                                                 u32* __restrict__ aggx) {
    const int node = __builtin_amdgcn_readfirstlane(blockIdx.x * 4 + (threadIdx.x >> 6));
    const int lane = threadIdx.x & 63;
    if (node >= N_NODES) return;
    const int beg = __builtin_amdgcn_readfirstlane(rowptr[node]);
    const int end = __builtin_amdgcn_readfirstlane(rowptr[node + 1]);
    const float dd = dinv[node];
    const u32 vs = xb[(size_t)node * 64 + lane];
    float a0 = dd * dd * bfbits2f((u16)vs);
    float a1 = dd * dd * bfbits2f((u16)(vs >> 16));
    int e = beg;
    for (; e + 7 < end; e += 8) {
        uint2 ed[8];
#pragma unroll
        for (int j = 0; j < 8; j++) ed[j] = edata[e + j];
        u32 v[8];
#pragma unroll
        for (int j = 0; j < 8; j++) v[j] = xb[(size_t)ed[j].x * 64 + lane];
#pragma unroll
        for (int j = 0; j < 8; j++) {
            const float n = __uint_as_float(ed[j].y);
            a0 += n * bfbits2f((u16)v[j]);
            a1 += n * bfbits2f((u16)(v[j] >> 16));
        }
    }
    for (; e < end; e++) {
        const uint2 e0 = edata[e];
        const u32 v0 = xb[(size_t)e0.x * 64 + lane];
        const float n0 = __uint_as_float(e0.y);
        a0 += n0 * bfbits2f((u16)v0);
        a1 += n0 * bfbits2f((u16)(v0 >> 16));
    }
    aggx[(size_t)node * 64 + lane] = pack2(a0, a1);
}

// ---- fused layer-1 GEMM + t-GEMM (validated round 12) ----
__global__ __launch_bounds__(256) void bgemm1f_k(const u16* __restrict__ X,      // aggxb [N][128]
                                                 const u16* __restrict__ W1b,
                                                 const float* __restrict__ b1,
                                                 const u16* __restrict__ Wcb,    // [40][256] bf16
                                                 u16* __restrict__ tb) {         // [N][TPAD]
    constexpr int KF1 = F_IN / 32;   // 4
    constexpr int KF2 = H_DIM / 32;  // 8
    __shared__ __align__(16) u16 hs[2][16][H_DIM + 8];
    const int wave = threadIdx.x >> 6;
    const int lane = threadIdx.x & 63;
    const int quad = lane >> 4;
    const int nn = lane & 15;
    const int ngbase = wave * 64;

    bf16x8 Bf[4][KF1];
    float bb[4];
#pragma unroll
    for (int j = 0; j < 4; j++) {
        const int wr = ngbase + j * 16 + nn;
#pragma unroll
        for (int kf = 0; kf < KF1; kf++)
            Bf[j][kf] = *(const bf16x8*)(W1b + (size_t)wr * F_IN + kf * 32 + quad * 8);
        bb[j] = b1[wr];
    }
    bf16x8 Bh[KF2];
    {
        int hr = wave * 16 + nn;
        if (hr > C_OUT - 1) hr = C_OUT - 1;
#pragma unroll
        for (int kf = 0; kf < KF2; kf++)
            Bh[kf] = *(const bf16x8*)(Wcb + (size_t)hr * H_DIM + kf * 32 + quad * 8);
    }

    int mt = blockIdx.x;
    if (mt >= MT_TOT) return;
    const int stride = gridDim.x;
    int buf = 0;

    bf16x8 Acur[KF1], Anext[KF1];
    {
        const u16* ap = X + (size_t)(mt * 16 + nn) * F_IN + quad * 8;
#pragma unroll
        for (int kf = 0; kf < KF1; kf++) Acur[kf] = *(const bf16x8*)(ap + kf * 32);
    }

    while (true) {
        const int mtn = mt + stride;
        if (mtn < MT_TOT) {
            const u16* ap = X + (size_t)(mtn * 16 + nn) * F_IN + quad * 8;
#pragma unroll
            for (int kf = 0; kf < KF1; kf++) Anext[kf] = *(const bf16x8*)(ap + kf * 32);
        }

        f32x4 acc[4];
#pragma unroll
        for (int j = 0; j < 4; j++) acc[j] = (f32x4){0.f, 0.f, 0.f, 0.f};
#pragma unroll
        for (int kf = 0; kf < KF1; kf++)
#pragma unroll
            for (int j = 0; j < 4; j++)
                acc[j] = __builtin_amdgcn_mfma_f32_16x16x32_bf16(Acur[kf], Bf[j][kf], acc[j], 0, 0, 0);

#pragma unroll
        for (int j = 0; j < 4; j++)
#pragma unroll
            for (int r = 0; r < 4; r++)
                hs[buf][quad * 4 + r][ngbase + j * 16 + nn] = f2bf(fmaxf(acc[j][r] + bb[j], 0.f));
        __syncthreads();

        if (wave < 3) {
            f32x4 ah = (f32x4){0.f, 0.f, 0.f, 0.f};
#pragma unroll
            for (int kf = 0; kf < KF2; kf++) {
                bf16x8 af = *(const bf16x8*)(&hs[buf][nn][kf * 32 + quad * 8]);
                ah = __builtin_amdgcn_mfma_f32_16x16x32_bf16(af, Bh[kf], ah, 0, 0, 0);
            }
            const int col = wave * 16 + nn;   // 0..47
#pragma unroll
            for (int r = 0; r < 4; r++) {
                const int row = mt * 16 + quad * 4 + r;
                tb[(size_t)row * TPAD + col] = f2bf(ah[r]);
            }
        }

        if (mtn >= MT_TOT) break;
#pragma unroll
        for (int kf = 0; kf < KF1; kf++) Acur[kf] = Anext[kf];
        mt = mtn;
        buf ^= 1;
    }
}

// ---- final gather at width 40 (padded 64): out = A_hat * t + bc ----
__global__ __launch_bounds__(256) void gatherO_k(const u32* __restrict__ tb,     // [N][TPAD/2]
                                                 const int* __restrict__ rowptr,
                                                 const uint2* __restrict__ edata,
                                                 const float* __restrict__ dinv,
                                                 const float* __restrict__ bc,
                                                 float* __restrict__ out) {
    const int node = __builtin_amdgcn_readfirstlane(blockIdx.x * 4 + (threadIdx.x >> 6));
    const int lane = threadIdx.x & 63;
    if (node >= N_NODES) return;
    const int lc = lane & 31;
    const int beg = __builtin_amdgcn_readfirstlane(rowptr[node]);
    const int end = __builtin_amdgcn_readfirstlane(rowptr[node + 1]);
    const float dd = dinv[node];
    const u32 vs = tb[(size_t)node * (TPAD / 2) + lc];
    float a0 = dd * dd * bfbits2f((u16)vs);
    float a1 = dd * dd * bfbits2f((u16)(vs >> 16));
    int e = beg;
    for (; e + 7 < end; e += 8) {
        uint2 ed[8];
#pragma unroll
        for (int j = 0; j < 8; j++) ed[j] = edata[e + j];
        u32 v[8];
#pragma unroll
        for (int j = 0; j < 8; j++) v[j] = tb[(size_t)ed[j].x * (TPAD / 2) + lc];
#pragma unroll
        for (int j = 0; j < 8; j++) {
            const float n = __uint_as_float(ed[j].y);
            a0 += n * bfbits2f((u16)v[j]);
            a1 += n * bfbits2f((u16)(v[j] >> 16));
        }
    }
    for (; e < end; e++) {
        const uint2 e0 = edata[e];
        const u32 v0 = tb[(size_t)e0.x * (TPAD / 2) + lc];
        const float n0 = __uint_as_float(e0.y);
        a0 += n0 * bfbits2f((u16)v0);
        a1 += n0 * bfbits2f((u16)(v0 >> 16));
    }
    if (lane < C_OUT / 2) {
        float2 o;
        o.x = a0 + bc[2 * lane];
        o.y = a1 + bc[2 * lane + 1];
        *(float2*)(out + (size_t)node * C_OUT + 2 * lane) = o;
    }
}

extern "C" void kernel_launch(void* const* d_in, const int* in_sizes, int n_in,
                              void* d_out, int out_size, void* d_ws, size_t ws_size,
                              hipStream_t stream) {
    const float* x    = (const float*)d_in[0];
    const int*   ei   = (const int*)d_in[1];
    const float* W1   = (const float*)d_in[2];
    const float* b1   = (const float*)d_in[3];
    const float* W2   = (const float*)d_in[4];
    const float* b2   = (const float*)d_in[5];
    const float* Wout = (const float*)d_in[6];
    const float* bout = (const float*)d_in[7];
    float* out = (float*)d_out;

    const int* src = ei;            // edge_index[0]
    const int* dst = ei + N_EDGES;  // edge_index[1]

    // workspace (~45 MB)
    char* ws = (char*)d_ws;
    size_t o = 0;
    auto alloc = [&](size_t bytes) { size_t p = o; o = (o + bytes + 255) & ~(size_t)255; return p; };
    int*   cnt    = (int*)(ws + alloc((size_t)NREP * N_PAD * 4));       // 1.6 MB (sharded)
    int*   cursor = (int*)(ws + alloc((size_t)NREP * N_PAD * 4));       // 1.6 MB (sharded)
    float* dinv   = (float*)(ws + alloc((size_t)N_NODES * 4));
    int*   rowptr = (int*)(ws + alloc((size_t)(N_NODES + 1) * 4));
    int*   bsum   = (int*)(ws + alloc((size_t)NB_SCAN * 4));
    int*   boff   = (int*)(ws + alloc((size_t)NB_SCAN * 4));
    uint2* edata  = (uint2*)(ws + alloc((size_t)N_EDGES * 8));          // 6.4 MB
    u16*   xb     = (u16*)(ws + alloc((size_t)N_NODES * F_IN * 2));     // 12.8 MB
    u16*   aggxb  = (u16*)(ws + alloc((size_t)N_NODES * F_IN * 2));     // 12.8 MB
    u16*   tb     = (u16*)(ws + alloc((size_t)N_NODES * TPAD * 2));     // 6.4 MB
    u16*   W1b    = (u16*)(ws + alloc((size_t)H_DIM * F_IN * 2));
    u16*   Wcb    = (u16*)(ws + alloc((size_t)C_OUT * H_DIM * 2));
    float* bc     = (float*)(ws + alloc((size_t)C_OUT * 4));

    // sharded count + cvt(x, W1) + Wc precompute, fused
    hipMemsetAsync(cnt, 0, (size_t)NREP * N_PAD * 4, stream);
    cc_k<<<CNT_BLKS + CC_CVT_BLKS + C_OUT, 256, 0, stream>>>(
        dst, cnt,
        (const float4*)x, (uint2*)xb, (const float4*)W1, (uint2*)W1b,
        W2, Wout, b2, bout, Wcb, bc);
    scan1_k<<<NB_SCAN, 256, 0, stream>>>(cnt, dinv, rowptr, bsum);
    scan2_k<<<1, 256, 0, stream>>>(bsum, boff, rowptr);
    scan3_k<<<NB_SCAN, 256, 0, stream>>>(rowptr, cursor, cnt, boff);
    bucket_k<<<(N_EDGES + 255) / 256, 256, 0, stream>>>(src, dst, dinv, cursor, edata, N_EDGES);

    // layer 1 aggregate-first: aggx = A_hat * xb
    gather1_k<<<(N_NODES + 3) / 4, 256, 0, stream>>>((const u32*)xb, rowptr, edata, dinv, (u32*)aggxb);
    // fused: h1 = relu(aggx@W1^T+b1) [LDS only] ; t = h1@Wc^T -> tb
    bgemm1f_k<<<768, 256, 0, stream>>>(aggxb, W1b, b1, Wcb, tb);
    // final: out = A_hat * t + bc
    gatherO_k<<<(N_NODES + 3) / 4, 256, 0, stream>>>((const u32*)tb, rowptr, edata, dinv, bc, out);
}

// Round 14
// 206.111 us; speedup vs baseline: 4.1044x; 1.1706x over previous
//
#include <hip/hip_runtime.h>

#define N_NODES 50000
#define N_EDGES 800000
#define F_IN    128
#define H_DIM   256
#define C_OUT   40
#define MT_TOT  (N_NODES / 16)            // 3125 m-tiles
#define TPAD    64                        // t row padded to 64 bf16 (32 u32)
#define NBIN1   196                       // coarse bins: dst>>8 (50000/256)
#define NCHB    200                       // p1/p2 edge-chunk blocks
#define CHSZ    (N_EDGES / NCHB)          // 4000 edges per block

typedef unsigned short u16;
typedef unsigned int   u32;
typedef short bf16x8 __attribute__((ext_vector_type(8)));
typedef float f32x4  __attribute__((ext_vector_type(4)));

__device__ inline float bfbits2f(u16 u) { return __uint_as_float(((u32)u) << 16); }
__device__ inline u16 f2bf(float f) {
    u32 u = __float_as_uint(f);
    u += 0x7fffu + ((u >> 16) & 1u);   // RNE
    return (u16)(u >> 16);
}
__device__ inline u32 pack2(float a, float b) {
    return (u32)f2bf(a) | ((u32)f2bf(b) << 16);
}

// ---- cvt (x, W1) + Wc = Wo*W2 + bc (no atomics) ----
#define CVT_X  (N_NODES * F_IN / 4)          // 1,600,000
#define CVT_W1 (H_DIM * F_IN / 4)            // 8192
#define CVT_TOT (CVT_X + CVT_W1)             // 1,608,192 = 6282*256
#define CC_CVT_BLKS (CVT_TOT / 256)          // 6282
__global__ __launch_bounds__(256) void cvtwc_k(const float4* __restrict__ x, uint2* __restrict__ xb,
                                               const float4* __restrict__ W1, uint2* __restrict__ W1b,
                                               const float* __restrict__ W2, const float* __restrict__ Wo,
                                               const float* __restrict__ b2, const float* __restrict__ bo,
                                               u16* __restrict__ Wcb, float* __restrict__ bc) {
    if (blockIdx.x < CC_CVT_BLKS) {
        int i = blockIdx.x * 256 + threadIdx.x;
        const float4* s; uint2* d; int j;
        if (i < CVT_X) { s = x; d = xb; j = i; }
        else { s = W1; d = W1b; j = i - CVT_X; }
        float4 v = s[j];
        uint2 o; o.x = pack2(v.x, v.y); o.y = pack2(v.z, v.w);
        d[j] = o;
        return;
    }
    const int c = blockIdx.x - CC_CVT_BLKS;    // 0..39
    const int t = threadIdx.x;
    float acc = 0.f;
    for (int o = 0; o < H_DIM; o += 8) {
        float w2v[8];
#pragma unroll
        for (int j = 0; j < 8; j++) w2v[j] = W2[(size_t)(o + j) * H_DIM + t];
#pragma unroll
        for (int j = 0; j < 8; j++) acc += Wo[(size_t)c * H_DIM + o + j] * w2v[j];
    }
    Wcb[(size_t)c * H_DIM + t] = f2bf(acc);
    __shared__ float red[256];
    red[t] = b2[t] * Wo[(size_t)c * H_DIM + t];
    __syncthreads();
    for (int off = 128; off > 0; off >>= 1) {
        if (t < off) red[t] += red[t + off];
        __syncthreads();
    }
    if (t == 0) bc[c] = red[0] + bo[c];
}

// ---- pass 1: per-chunk coarse histogram (LDS atomics only) ----
__global__ __launch_bounds__(256) void p1hist_k(const int* __restrict__ dst, int* __restrict__ Ht) {
    __shared__ int hist[NBIN1];
    const int t = threadIdx.x;
    const int b = blockIdx.x;
    if (t < NBIN1) hist[t] = 0;
    __syncthreads();
    for (int i = b * CHSZ + t; i < (b + 1) * CHSZ; i += 256)
        atomicAdd(&hist[dst[i] >> 8], 1);
    __syncthreads();
    if (t < NBIN1) Ht[t * NCHB + b] = hist[t];
}

// ---- pass 1 scan: per-bin exclusive scan over chunks (in place) + totals ----
__global__ __launch_bounds__(256) void p1scan_k(int* __restrict__ Ht, int* __restrict__ totals) {
    __shared__ int sc[256];
    const int t = threadIdx.x;
    const int g = blockIdx.x;
    int v = (t < NCHB) ? Ht[g * NCHB + t] : 0;
    sc[t] = v;
    __syncthreads();
    for (int off = 1; off < 256; off <<= 1) {
        int u = (t >= off) ? sc[t - off] : 0;
        __syncthreads();
        sc[t] += u;
        __syncthreads();
    }
    if (t < NCHB) Ht[g * NCHB + t] = sc[t] - v;        // exclusive
    if (t == NCHB - 1) totals[g] = sc[t];
}

// ---- pass 1 base: scan bin totals -> base[g], set rowptr[N]=E ----
__global__ __launch_bounds__(256) void p1base_k(const int* __restrict__ totals,
                                                int* __restrict__ base, int* __restrict__ rowptr) {
    __shared__ int sc[256];
    const int t = threadIdx.x;
    int v = (t < NBIN1) ? totals[t] : 0;
    sc[t] = v;
    __syncthreads();
    for (int off = 1; off < 256; off <<= 1) {
        int u = (t >= off) ? sc[t - off] : 0;
        __syncthreads();
        sc[t] += u;
        __syncthreads();
    }
    if (t < NBIN1) base[t] = sc[t] - v;
    if (t == NBIN1 - 1) base[NBIN1] = sc[t];           // == N_EDGES
    if (t == 0) rowptr[N_NODES] = N_EDGES;
}

// ---- pass 2: scatter {src,dst} into coarse bins (LDS cursors, no global atomics) ----
__global__ __launch_bounds__(256) void p2scatter_k(const int* __restrict__ src, const int* __restrict__ dst,
                                                   const int* __restrict__ Ht, const int* __restrict__ base,
                                                   uint2* __restrict__ T) {
    __shared__ int cur[NBIN1];
    const int t = threadIdx.x;
    const int b = blockIdx.x;
    if (t < NBIN1) cur[t] = base[t] + Ht[t * NCHB + b];
    __syncthreads();
    for (int i = b * CHSZ + t; i < (b + 1) * CHSZ; i += 256) {
        const int s = src[i], d = dst[i];
        const int pos = atomicAdd(&cur[d >> 8], 1);    // LDS atomic
        uint2 ed; ed.x = (u32)s; ed.y = (u32)d;
        T[pos] = ed;
    }
}

// ---- pass 3a: per-bin fine histogram -> rowptr + dinv ----
__global__ __launch_bounds__(256) void p3a_k(const uint2* __restrict__ T, const int* __restrict__ base,
                                             int* __restrict__ rowptr, float* __restrict__ dinv) {
    __shared__ int hcnt[256];
    __shared__ int sc[256];
    const int t = threadIdx.x;
    const int g = blockIdx.x;
    const int nbeg = base[g], nend = base[g + 1];
    hcnt[t] = 0;
    __syncthreads();
    for (int i = nbeg + t; i < nend; i += 256)
        atomicAdd(&hcnt[T[i].y & 255], 1);
    __syncthreads();
    const int my = hcnt[t];
    sc[t] = my;
    __syncthreads();
    for (int off = 1; off < 256; off <<= 1) {
        int u = (t >= off) ? sc[t - off] : 0;
        __syncthreads();
        sc[t] += u;
        __syncthreads();
    }
    const int node = g * 256 + t;
    if (node < N_NODES) {
        rowptr[node] = nbeg + sc[t] - my;
        dinv[node] = rsqrtf((float)my + 1.0f);
    }
}

// ---- pass 3b: within-bin scatter -> final edata {src, dinv[src]} ----
__global__ __launch_bounds__(256) void p3b_k(const uint2* __restrict__ T, const int* __restrict__ base,
                                             const float* __restrict__ dinv, uint2* __restrict__ edata) {
    __shared__ int hcnt[256];
    __shared__ int sc[256];
    __shared__ int cur[256];
    const int t = threadIdx.x;
    const int g = blockIdx.x;
    const int nbeg = base[g], nend = base[g + 1];
    hcnt[t] = 0;
    __syncthreads();
    for (int i = nbeg + t; i < nend; i += 256)
        atomicAdd(&hcnt[T[i].y & 255], 1);
    __syncthreads();
    const int my = hcnt[t];
    sc[t] = my;
    __syncthreads();
    for (int off = 1; off < 256; off <<= 1) {
        int u = (t >= off) ? sc[t - off] : 0;
        __syncthreads();
        sc[t] += u;
        __syncthreads();
    }
    cur[t] = nbeg + sc[t] - my;
    __syncthreads();
    for (int i = nbeg + t; i < nend; i += 256) {
        const uint2 e = T[i];
        const int pos = atomicAdd(&cur[e.y & 255], 1); // LDS atomic
        const float w = dinv[e.x];
        uint2 ed; ed.x = e.x; ed.y = __float_as_uint(w);
        edata[pos] = ed;
    }
}

// ---- gather width-128 bf16, one wave per node, unroll x8 ----
// edge weight w = dinv[src]; result = dd*(sum w*x_s + dd*x_self)
__global__ __launch_bounds__(256) void gather1_k(const u32* __restrict__ xb,
                                                 const int* __restrict__ rowptr,
                                                 const uint2* __restrict__ edata,
                                                 const float* __restrict__ dinv,
                                                 u32* __restrict__ aggx) {
    const int node = __builtin_amdgcn_readfirstlane(blockIdx.x * 4 + (threadIdx.x >> 6));
    const int lane = threadIdx.x & 63;
    if (node >= N_NODES) return;
    const int beg = __builtin_amdgcn_readfirstlane(rowptr[node]);
    const int end = __builtin_amdgcn_readfirstlane(rowptr[node + 1]);
    const float dd = dinv[node];
    const u32 vs = xb[(size_t)node * 64 + lane];
    float a0 = dd * bfbits2f((u16)vs);
    float a1 = dd * bfbits2f((u16)(vs >> 16));
    int e = beg;
    for (; e + 7 < end; e += 8) {
        uint2 ed[8];
#pragma unroll
        for (int j = 0; j < 8; j++) ed[j] = edata[e + j];
        u32 v[8];
#pragma unroll
        for (int j = 0; j < 8; j++) v[j] = xb[(size_t)ed[j].x * 64 + lane];
#pragma unroll
        for (int j = 0; j < 8; j++) {
            const float n = __uint_as_float(ed[j].y);
            a0 += n * bfbits2f((u16)v[j]);
            a1 += n * bfbits2f((u16)(v[j] >> 16));
        }
    }
    for (; e < end; e++) {
        const uint2 e0 = edata[e];
        const u32 v0 = xb[(size_t)e0.x * 64 + lane];
        const float n0 = __uint_as_float(e0.y);
        a0 += n0 * bfbits2f((u16)v0);
        a1 += n0 * bfbits2f((u16)(v0 >> 16));
    }
    aggx[(size_t)node * 64 + lane] = pack2(dd * a0, dd * a1);
}

// ---- fused layer-1 GEMM + t-GEMM (validated round 12) ----
__global__ __launch_bounds__(256) void bgemm1f_k(const u16* __restrict__ X,      // aggxb [N][128]
                                                 const u16* __restrict__ W1b,
                                                 const float* __restrict__ b1,
                                                 const u16* __restrict__ Wcb,    // [40][256] bf16
                                                 u16* __restrict__ tb) {         // [N][TPAD]
    constexpr int KF1 = F_IN / 32;   // 4
    constexpr int KF2 = H_DIM / 32;  // 8
    __shared__ __align__(16) u16 hs[2][16][H_DIM + 8];
    const int wave = threadIdx.x >> 6;
    const int lane = threadIdx.x & 63;
    const int quad = lane >> 4;
    const int nn = lane & 15;
    const int ngbase = wave * 64;

    bf16x8 Bf[4][KF1];
    float bb[4];
#pragma unroll
    for (int j = 0; j < 4; j++) {
        const int wr = ngbase + j * 16 + nn;
#pragma unroll
        for (int kf = 0; kf < KF1; kf++)
            Bf[j][kf] = *(const bf16x8*)(W1b + (size_t)wr * F_IN + kf * 32 + quad * 8);
        bb[j] = b1[wr];
    }
    bf16x8 Bh[KF2];
    {
        int hr = wave * 16 + nn;
        if (hr > C_OUT - 1) hr = C_OUT - 1;
#pragma unroll
        for (int kf = 0; kf < KF2; kf++)
            Bh[kf] = *(const bf16x8*)(Wcb + (size_t)hr * H_DIM + kf * 32 + quad * 8);
    }

    int mt = blockIdx.x;
    if (mt >= MT_TOT) return;
    const int stride = gridDim.x;
    int buf = 0;

    bf16x8 Acur[KF1], Anext[KF1];
    {
        const u16* ap = X + (size_t)(mt * 16 + nn) * F_IN + quad * 8;
#pragma unroll
        for (int kf = 0; kf < KF1; kf++) Acur[kf] = *(const bf16x8*)(ap + kf * 32);
    }

    while (true) {
        const int mtn = mt + stride;
        if (mtn < MT_TOT) {
            const u16* ap = X + (size_t)(mtn * 16 + nn) * F_IN + quad * 8;
#pragma unroll
            for (int kf = 0; kf < KF1; kf++) Anext[kf] = *(const bf16x8*)(ap + kf * 32);
        }

        f32x4 acc[4];
#pragma unroll
        for (int j = 0; j < 4; j++) acc[j] = (f32x4){0.f, 0.f, 0.f, 0.f};
#pragma unroll
        for (int kf = 0; kf < KF1; kf++)
#pragma unroll
            for (int j = 0; j < 4; j++)
                acc[j] = __builtin_amdgcn_mfma_f32_16x16x32_bf16(Acur[kf], Bf[j][kf], acc[j], 0, 0, 0);

#pragma unroll
        for (int j = 0; j < 4; j++)
#pragma unroll
            for (int r = 0; r < 4; r++)
                hs[buf][quad * 4 + r][ngbase + j * 16 + nn] = f2bf(fmaxf(acc[j][r] + bb[j], 0.f));
        __syncthreads();

        if (wave < 3) {
            f32x4 ah = (f32x4){0.f, 0.f, 0.f, 0.f};
#pragma unroll
            for (int kf = 0; kf < KF2; kf++) {
                bf16x8 af = *(const bf16x8*)(&hs[buf][nn][kf * 32 + quad * 8]);
                ah = __builtin_amdgcn_mfma_f32_16x16x32_bf16(af, Bh[kf], ah, 0, 0, 0);
            }
            const int col = wave * 16 + nn;   // 0..47
#pragma unroll
            for (int r = 0; r < 4; r++) {
                const int row = mt * 16 + quad * 4 + r;
                tb[(size_t)row * TPAD + col] = f2bf(ah[r]);
            }
        }

        if (mtn >= MT_TOT) break;
#pragma unroll
        for (int kf = 0; kf < KF1; kf++) Acur[kf] = Anext[kf];
        mt = mtn;
        buf ^= 1;
    }
}

// ---- final gather at width 40 (padded 64): out = dd*(sum w*t_s + dd*t_self) + bc ----
__global__ __launch_bounds__(256) void gatherO_k(const u32* __restrict__ tb,     // [N][TPAD/2]
                                                 const int* __restrict__ rowptr,
                                                 const uint2* __restrict__ edata,
                                                 const float* __restrict__ dinv,
                                                 const float* __restrict__ bc,
                                                 float* __restrict__ out) {
    const int node = __builtin_amdgcn_readfirstlane(blockIdx.x * 4 + (threadIdx.x >> 6));
    const int lane = threadIdx.x & 63;
    if (node >= N_NODES) return;
    const int lc = lane & 31;
    const int beg = __builtin_amdgcn_readfirstlane(rowptr[node]);
    const int end = __builtin_amdgcn_readfirstlane(rowptr[node + 1]);
    const float dd = dinv[node];
    const u32 vs = tb[(size_t)node * (TPAD / 2) + lc];
    float a0 = dd * bfbits2f((u16)vs);
    float a1 = dd * bfbits2f((u16)(vs >> 16));
    int e = beg;
    for (; e + 7 < end; e += 8) {
        uint2 ed[8];
#pragma unroll
        for (int j = 0; j < 8; j++) ed[j] = edata[e + j];
        u32 v[8];
#pragma unroll
        for (int j = 0; j < 8; j++) v[j] = tb[(size_t)ed[j].x * (TPAD / 2) + lc];
#pragma unroll
        for (int j = 0; j < 8; j++) {
            const float n = __uint_as_float(ed[j].y);
            a0 += n * bfbits2f((u16)v[j]);
            a1 += n * bfbits2f((u16)(v[j] >> 16));
        }
    }
    for (; e < end; e++) {
        const uint2 e0 = edata[e];
        const u32 v0 = tb[(size_t)e0.x * (TPAD / 2) + lc];
        const float n0 = __uint_as_float(e0.y);
        a0 += n0 * bfbits2f((u16)v0);
        a1 += n0 * bfbits2f((u16)(v0 >> 16));
    }
    if (lane < C_OUT / 2) {
        float2 o;
        o.x = dd * a0 + bc[2 * lane];
        o.y = dd * a1 + bc[2 * lane + 1];
        *(float2*)(out + (size_t)node * C_OUT + 2 * lane) = o;
    }
}

extern "C" void kernel_launch(void* const* d_in, const int* in_sizes, int n_in,
                              void* d_out, int out_size, void* d_ws, size_t ws_size,
                              hipStream_t stream) {
    const float* x    = (const float*)d_in[0];
    const int*   ei   = (const int*)d_in[1];
    const float* W1   = (const float*)d_in[2];
    const float* b1   = (const float*)d_in[3];
    const float* W2   = (const float*)d_in[4];
    const float* b2   = (const float*)d_in[5];
    const float* Wout = (const float*)d_in[6];
    const float* bout = (const float*)d_in[7];
    float* out = (float*)d_out;

    const int* src = ei;            // edge_index[0]
    const int* dst = ei + N_EDGES;  // edge_index[1]

    // workspace (~52 MB)
    char* ws = (char*)d_ws;
    size_t o = 0;
    auto alloc = [&](size_t bytes) { size_t p = o; o = (o + bytes + 255) & ~(size_t)255; return p; };
    int*   Ht     = (int*)(ws + alloc((size_t)NBIN1 * NCHB * 4));       // 157 KB
    int*   totals = (int*)(ws + alloc((size_t)NBIN1 * 4));
    int*   base   = (int*)(ws + alloc((size_t)(NBIN1 + 1) * 4));
    float* dinv   = (float*)(ws + alloc((size_t)N_NODES * 4));
    int*   rowptr = (int*)(ws + alloc((size_t)(N_NODES + 1) * 4));
    uint2* T      = (uint2*)(ws + alloc((size_t)N_EDGES * 8));          // 6.4 MB
    uint2* edata  = (uint2*)(ws + alloc((size_t)N_EDGES * 8));          // 6.4 MB
    u16*   xb     = (u16*)(ws + alloc((size_t)N_NODES * F_IN * 2));     // 12.8 MB
    u16*   aggxb  = (u16*)(ws + alloc((size_t)N_NODES * F_IN * 2));     // 12.8 MB
    u16*   tb     = (u16*)(ws + alloc((size_t)N_NODES * TPAD * 2));     // 6.4 MB
    u16*   W1b    = (u16*)(ws + alloc((size_t)H_DIM * F_IN * 2));
    u16*   Wcb    = (u16*)(ws + alloc((size_t)C_OUT * H_DIM * 2));
    float* bc     = (float*)(ws + alloc((size_t)C_OUT * 4));

    // cvt + Wc (first: also absorbs any poison-writeback drag for attribution)
    cvtwc_k<<<CC_CVT_BLKS + C_OUT, 256, 0, stream>>>(
        (const float4*)x, (uint2*)xb, (const float4*)W1, (uint2*)W1b,
        W2, Wout, b2, bout, Wcb, bc);

    // atomic-free CSR build (counting sort, LDS atomics only)
    p1hist_k<<<NCHB, 256, 0, stream>>>(dst, Ht);
    p1scan_k<<<NBIN1, 256, 0, stream>>>(Ht, totals);
    p1base_k<<<1, 256, 0, stream>>>(totals, base, rowptr);
    p2scatter_k<<<NCHB, 256, 0, stream>>>(src, dst, Ht, base, T);
    p3a_k<<<NBIN1, 256, 0, stream>>>(T, base, rowptr, dinv);
    p3b_k<<<NBIN1, 256, 0, stream>>>(T, base, dinv, edata);

    // layer 1 aggregate-first: aggx = A_hat * xb
    gather1_k<<<(N_NODES + 3) / 4, 256, 0, stream>>>((const u32*)xb, rowptr, edata, dinv, (u32*)aggxb);
    // fused: h1 = relu(aggx@W1^T+b1) [LDS only] ; t = h1@Wc^T -> tb
    bgemm1f_k<<<768, 256, 0, stream>>>(aggxb, W1b, b1, Wcb, tb);
    // final: out = A_hat * t + bc
    gatherO_k<<<(N_NODES + 3) / 4, 256, 0, stream>>>((const u32*)tb, rowptr, edata, dinv, bc, out);
}

// Round 15
// 199.706 us; speedup vs baseline: 4.2361x; 1.0321x over previous
//
#include <hip/hip_runtime.h>

#define N_NODES 50000
#define N_EDGES 800000
#define F_IN    128
#define H_DIM   256
#define C_OUT   40
#define MT_TOT  (N_NODES / 16)            // 3125 m-tiles
#define TPAD    64                        // t row padded to 64 bf16 (32 u32)
#define NBIN1   196                       // coarse bins: dst>>8
#define NCHB    200                       // p1/p2 edge-chunk blocks
#define CHSZ    (N_EDGES / NCHB)          // 4000 edges per block
#define CVT_X   (N_NODES * F_IN / 4)      // 1,600,000 float4 groups
#define CVT_W1B (H_DIM * F_IN / 4 / 256)  // 32 blocks for W1 cvt

typedef unsigned short u16;
typedef unsigned int   u32;
typedef short bf16x8 __attribute__((ext_vector_type(8)));
typedef float f32x4  __attribute__((ext_vector_type(4)));

__device__ inline float bfbits2f(u16 u) { return __uint_as_float(((u32)u) << 16); }
__device__ inline u16 f2bf(float f) {
    u32 u = __float_as_uint(f);
    u += 0x7fffu + ((u >> 16) & 1u);   // RNE
    return (u16)(u >> 16);
}
__device__ inline u32 pack2(float a, float b) {
    return (u32)f2bf(a) | ((u32)f2bf(b) << 16);
}

// ---- pre: p1 coarse histogram | W1 cvt | Wc = Wo*W2 + bc ----
__global__ __launch_bounds__(256) void pre_k(const int* __restrict__ dst, int* __restrict__ Ht,
                                             const float4* __restrict__ W1, uint2* __restrict__ W1b,
                                             const float* __restrict__ W2, const float* __restrict__ Wo,
                                             const float* __restrict__ b2, const float* __restrict__ bo,
                                             u16* __restrict__ Wcb, float* __restrict__ bc) {
    __shared__ int hist[NBIN1];
    __shared__ float red[256];
    const int t = threadIdx.x;
    if (blockIdx.x < NCHB) {               // coarse histogram chunk
        const int b = blockIdx.x;
        if (t < NBIN1) hist[t] = 0;
        __syncthreads();
        for (int i = b * CHSZ + t; i < (b + 1) * CHSZ; i += 256)
            atomicAdd(&hist[dst[i] >> 8], 1);
        __syncthreads();
        if (t < NBIN1) Ht[t * NCHB + b] = hist[t];
        return;
    }
    if (blockIdx.x < NCHB + CVT_W1B) {     // W1 fp32 -> bf16
        int i = (blockIdx.x - NCHB) * 256 + t;
        float4 v = W1[i];
        uint2 o; o.x = pack2(v.x, v.y); o.y = pack2(v.z, v.w);
        W1b[i] = o;
        return;
    }
    const int c = blockIdx.x - NCHB - CVT_W1B;   // 0..39: Wc row
    float acc = 0.f;
    for (int o = 0; o < H_DIM; o += 8) {
        float w2v[8];
#pragma unroll
        for (int j = 0; j < 8; j++) w2v[j] = W2[(size_t)(o + j) * H_DIM + t];
#pragma unroll
        for (int j = 0; j < 8; j++) acc += Wo[(size_t)c * H_DIM + o + j] * w2v[j];
    }
    Wcb[(size_t)c * H_DIM + t] = f2bf(acc);
    red[t] = b2[t] * Wo[(size_t)c * H_DIM + t];
    __syncthreads();
    for (int off = 128; off > 0; off >>= 1) {
        if (t < off) red[t] += red[t + off];
        __syncthreads();
    }
    if (t == 0) bc[c] = red[0] + bo[c];
}

// ---- pass 1 scan: per-bin exclusive scan over chunks + totals ----
__global__ __launch_bounds__(256) void p1scan_k(int* __restrict__ Ht, int* __restrict__ totals) {
    __shared__ int sc[256];
    const int t = threadIdx.x;
    const int g = blockIdx.x;
    int v = (t < NCHB) ? Ht[g * NCHB + t] : 0;
    sc[t] = v;
    __syncthreads();
    for (int off = 1; off < 256; off <<= 1) {
        int u = (t >= off) ? sc[t - off] : 0;
        __syncthreads();
        sc[t] += u;
        __syncthreads();
    }
    if (t < NCHB) Ht[g * NCHB + t] = sc[t] - v;
    if (t == NCHB - 1) totals[g] = sc[t];
}

// ---- pass 1 base: scan bin totals -> base[], rowptr[N]=E ----
__global__ __launch_bounds__(256) void p1base_k(const int* __restrict__ totals,
                                                int* __restrict__ base, int* __restrict__ rowptr) {
    __shared__ int sc[256];
    const int t = threadIdx.x;
    int v = (t < NBIN1) ? totals[t] : 0;
    sc[t] = v;
    __syncthreads();
    for (int off = 1; off < 256; off <<= 1) {
        int u = (t >= off) ? sc[t - off] : 0;
        __syncthreads();
        sc[t] += u;
        __syncthreads();
    }
    if (t < NBIN1) base[t] = sc[t] - v;
    if (t == NBIN1 - 1) base[NBIN1] = sc[t];
    if (t == 0) rowptr[N_NODES] = N_EDGES;
}

// ---- pass 2: scatter {src,dst} into coarse bins (LDS cursors) ----
__global__ __launch_bounds__(256) void p2scatter_k(const int* __restrict__ src, const int* __restrict__ dst,
                                                   const int* __restrict__ Ht, const int* __restrict__ base,
                                                   uint2* __restrict__ T) {
    __shared__ int cur[NBIN1];
    const int t = threadIdx.x;
    const int b = blockIdx.x;
    if (t < NBIN1) cur[t] = base[t] + Ht[t * NCHB + b];
    __syncthreads();
    for (int i = b * CHSZ + t; i < (b + 1) * CHSZ; i += 256) {
        const int s = src[i], d = dst[i];
        const int pos = atomicAdd(&cur[d >> 8], 1);
        uint2 ed; ed.x = (u32)s; ed.y = (u32)d;
        T[pos] = ed;
    }
}

// ---- pass 3 (merged): fine histogram -> rowptr + dinv + scatter src-only edata ----
__global__ __launch_bounds__(256) void p3_k(const uint2* __restrict__ T, const int* __restrict__ base,
                                            int* __restrict__ rowptr, float* __restrict__ dinv,
                                            u32* __restrict__ edata) {
    __shared__ int hcnt[256];
    __shared__ int sc[256];
    __shared__ int cur[256];
    const int t = threadIdx.x;
    const int g = blockIdx.x;
    const int nbeg = base[g], nend = base[g + 1];
    hcnt[t] = 0;
    __syncthreads();
    for (int i = nbeg + t; i < nend; i += 256)
        atomicAdd(&hcnt[T[i].y & 255], 1);
    __syncthreads();
    const int my = hcnt[t];
    sc[t] = my;
    __syncthreads();
    for (int off = 1; off < 256; off <<= 1) {
        int u = (t >= off) ? sc[t - off] : 0;
        __syncthreads();
        sc[t] += u;
        __syncthreads();
    }
    const int rbeg = nbeg + sc[t] - my;
    const int node = g * 256 + t;
    if (node < N_NODES) {
        rowptr[node] = rbeg;
        dinv[node] = rsqrtf((float)my + 1.0f);
    }
    cur[t] = rbeg;
    __syncthreads();
    for (int i = nbeg + t; i < nend; i += 256) {    // T re-read: L2-resident (32 KB/bin)
        const uint2 e = T[i];
        const int pos = atomicAdd(&cur[e.y & 255], 1);
        edata[pos] = e.x;
    }
}

// ---- x cvt with row pre-scale: xb[s] = bf16(dinv[s] * x[s]) ----
__global__ __launch_bounds__(256) void xcvt_k(const float4* __restrict__ x,
                                              const float* __restrict__ dinv,
                                              uint2* __restrict__ xb) {
    int i = blockIdx.x * 256 + threadIdx.x;
    if (i >= CVT_X) return;
    const int row = i >> 5;                 // 32 float4 groups per 128-wide row
    const float s = dinv[row];
    float4 v = x[i];
    uint2 o; o.x = pack2(s * v.x, s * v.y); o.y = pack2(s * v.z, s * v.w);
    xb[i] = o;
}

// ---- gather width-128: aggx[d] = dd * (sum_{s in N(d)} xs[s] + xs[d]) — weight-free ----
__global__ __launch_bounds__(256) void gather1_k(const u32* __restrict__ xb,
                                                 const int* __restrict__ rowptr,
                                                 const u32* __restrict__ edata,
                                                 const float* __restrict__ dinv,
                                                 u32* __restrict__ aggx) {
    const int node = __builtin_amdgcn_readfirstlane(blockIdx.x * 4 + (threadIdx.x >> 6));
    const int lane = threadIdx.x & 63;
    if (node >= N_NODES) return;
    const int beg = __builtin_amdgcn_readfirstlane(rowptr[node]);
    const int end = __builtin_amdgcn_readfirstlane(rowptr[node + 1]);
    const float dd = dinv[node];
    const u32 vs = xb[(size_t)node * 64 + lane];
    float a0 = bfbits2f((u16)vs);
    float a1 = bfbits2f((u16)(vs >> 16));
    int e = beg;
    for (; e + 7 < end; e += 8) {
        u32 s8[8];
#pragma unroll
        for (int j = 0; j < 8; j++) s8[j] = edata[e + j];
        u32 v[8];
#pragma unroll
        for (int j = 0; j < 8; j++) v[j] = xb[(size_t)s8[j] * 64 + lane];
#pragma unroll
        for (int j = 0; j < 8; j++) {
            a0 += bfbits2f((u16)v[j]);
            a1 += bfbits2f((u16)(v[j] >> 16));
        }
    }
    for (; e < end; e++) {
        const u32 v0 = xb[(size_t)edata[e] * 64 + lane];
        a0 += bfbits2f((u16)v0);
        a1 += bfbits2f((u16)(v0 >> 16));
    }
    aggx[(size_t)node * 64 + lane] = pack2(dd * a0, dd * a1);
}

// ---- fused layer-1 GEMM + t-GEMM; epilogue pre-scales t by dinv[row] ----
__global__ __launch_bounds__(256) void bgemm1f_k(const u16* __restrict__ X,      // aggxb [N][128]
                                                 const u16* __restrict__ W1b,
                                                 const float* __restrict__ b1,
                                                 const u16* __restrict__ Wcb,    // [40][256] bf16
                                                 const float* __restrict__ dinv,
                                                 u16* __restrict__ tb) {         // [N][TPAD] = dinv*t
    constexpr int KF1 = F_IN / 32;   // 4
    constexpr int KF2 = H_DIM / 32;  // 8
    __shared__ __align__(16) u16 hs[2][16][H_DIM + 8];
    const int wave = threadIdx.x >> 6;
    const int lane = threadIdx.x & 63;
    const int quad = lane >> 4;
    const int nn = lane & 15;
    const int ngbase = wave * 64;

    bf16x8 Bf[4][KF1];
    float bb[4];
#pragma unroll
    for (int j = 0; j < 4; j++) {
        const int wr = ngbase + j * 16 + nn;
#pragma unroll
        for (int kf = 0; kf < KF1; kf++)
            Bf[j][kf] = *(const bf16x8*)(W1b + (size_t)wr * F_IN + kf * 32 + quad * 8);
        bb[j] = b1[wr];
    }
    bf16x8 Bh[KF2];
    {
        int hr = wave * 16 + nn;
        if (hr > C_OUT - 1) hr = C_OUT - 1;
#pragma unroll
        for (int kf = 0; kf < KF2; kf++)
            Bh[kf] = *(const bf16x8*)(Wcb + (size_t)hr * H_DIM + kf * 32 + quad * 8);
    }

    int mt = blockIdx.x;
    if (mt >= MT_TOT) return;
    const int stride = gridDim.x;
    int buf = 0;

    bf16x8 Acur[KF1], Anext[KF1];
    {
        const u16* ap = X + (size_t)(mt * 16 + nn) * F_IN + quad * 8;
#pragma unroll
        for (int kf = 0; kf < KF1; kf++) Acur[kf] = *(const bf16x8*)(ap + kf * 32);
    }

    while (true) {
        const int mtn = mt + stride;
        if (mtn < MT_TOT) {
            const u16* ap = X + (size_t)(mtn * 16 + nn) * F_IN + quad * 8;
#pragma unroll
            for (int kf = 0; kf < KF1; kf++) Anext[kf] = *(const bf16x8*)(ap + kf * 32);
        }

        f32x4 acc[4];
#pragma unroll
        for (int j = 0; j < 4; j++) acc[j] = (f32x4){0.f, 0.f, 0.f, 0.f};
#pragma unroll
        for (int kf = 0; kf < KF1; kf++)
#pragma unroll
            for (int j = 0; j < 4; j++)
                acc[j] = __builtin_amdgcn_mfma_f32_16x16x32_bf16(Acur[kf], Bf[j][kf], acc[j], 0, 0, 0);

#pragma unroll
        for (int j = 0; j < 4; j++)
#pragma unroll
            for (int r = 0; r < 4; r++)
                hs[buf][quad * 4 + r][ngbase + j * 16 + nn] = f2bf(fmaxf(acc[j][r] + bb[j], 0.f));
        __syncthreads();

        if (wave < 3) {
            f32x4 ah = (f32x4){0.f, 0.f, 0.f, 0.f};
#pragma unroll
            for (int kf = 0; kf < KF2; kf++) {
                bf16x8 af = *(const bf16x8*)(&hs[buf][nn][kf * 32 + quad * 8]);
                ah = __builtin_amdgcn_mfma_f32_16x16x32_bf16(af, Bh[kf], ah, 0, 0, 0);
            }
            const int col = wave * 16 + nn;   // 0..47
#pragma unroll
            for (int r = 0; r < 4; r++) {
                const int row = mt * 16 + quad * 4 + r;
                tb[(size_t)row * TPAD + col] = f2bf(dinv[row] * ah[r]);
            }
        }

        if (mtn >= MT_TOT) break;
#pragma unroll
        for (int kf = 0; kf < KF1; kf++) Acur[kf] = Anext[kf];
        mt = mtn;
        buf ^= 1;
    }
}

// ---- final gather width 40: out[d] = dd * (sum ts[s] + ts[d]) + bc — weight-free ----
__global__ __launch_bounds__(256) void gatherO_k(const u32* __restrict__ tb,     // [N][TPAD/2]
                                                 const int* __restrict__ rowptr,
                                                 const u32* __restrict__ edata,
                                                 const float* __restrict__ dinv,
                                                 const float* __restrict__ bc,
                                                 float* __restrict__ out) {
    const int node = __builtin_amdgcn_readfirstlane(blockIdx.x * 4 + (threadIdx.x >> 6));
    const int lane = threadIdx.x & 63;
    if (node >= N_NODES) return;
    const int lc = lane & 31;
    const int beg = __builtin_amdgcn_readfirstlane(rowptr[node]);
    const int end = __builtin_amdgcn_readfirstlane(rowptr[node + 1]);
    const float dd = dinv[node];
    const u32 vs = tb[(size_t)node * (TPAD / 2) + lc];
    float a0 = bfbits2f((u16)vs);
    float a1 = bfbits2f((u16)(vs >> 16));
    int e = beg;
    for (; e + 7 < end; e += 8) {
        u32 s8[8];
#pragma unroll
        for (int j = 0; j < 8; j++) s8[j] = edata[e + j];
        u32 v[8];
#pragma unroll
        for (int j = 0; j < 8; j++) v[j] = tb[(size_t)s8[j] * (TPAD / 2) + lc];
#pragma unroll
        for (int j = 0; j < 8; j++) {
            a0 += bfbits2f((u16)v[j]);
            a1 += bfbits2f((u16)(v[j] >> 16));
        }
    }
    for (; e < end; e++) {
        const u32 v0 = tb[(size_t)edata[e] * (TPAD / 2) + lc];
        a0 += bfbits2f((u16)v0);
        a1 += bfbits2f((u16)(v0 >> 16));
    }
    if (lane < C_OUT / 2) {
        float2 o;
        o.x = dd * a0 + bc[2 * lane];
        o.y = dd * a1 + bc[2 * lane + 1];
        *(float2*)(out + (size_t)node * C_OUT + 2 * lane) = o;
    }
}

extern "C" void kernel_launch(void* const* d_in, const int* in_sizes, int n_in,
                              void* d_out, int out_size, void* d_ws, size_t ws_size,
                              hipStream_t stream) {
    const float* x    = (const float*)d_in[0];
    const int*   ei   = (const int*)d_in[1];
    const float* W1   = (const float*)d_in[2];
    const float* b1   = (const float*)d_in[3];
    const float* W2   = (const float*)d_in[4];
    const float* b2   = (const float*)d_in[5];
    const float* Wout = (const float*)d_in[6];
    const float* bout = (const float*)d_in[7];
    float* out = (float*)d_out;

    const int* src = ei;            // edge_index[0]
    const int* dst = ei + N_EDGES;  // edge_index[1]

    // workspace (~42 MB)
    char* ws = (char*)d_ws;
    size_t o = 0;
    auto alloc = [&](size_t bytes) { size_t p = o; o = (o + bytes + 255) & ~(size_t)255; return p; };
    int*   Ht     = (int*)(ws + alloc((size_t)NBIN1 * NCHB * 4));
    int*   totals = (int*)(ws + alloc((size_t)NBIN1 * 4));
    int*   base   = (int*)(ws + alloc((size_t)(NBIN1 + 1) * 4));
    float* dinv   = (float*)(ws + alloc((size_t)N_NODES * 4));
    int*   rowptr = (int*)(ws + alloc((size_t)(N_NODES + 1) * 4));
    uint2* T      = (uint2*)(ws + alloc((size_t)N_EDGES * 8));          // 6.4 MB
    u32*   edata  = (u32*)(ws + alloc((size_t)N_EDGES * 4));            // 3.2 MB
    u16*   xb     = (u16*)(ws + alloc((size_t)N_NODES * F_IN * 2));     // 12.8 MB
    u16*   aggxb  = (u16*)(ws + alloc((size_t)N_NODES * F_IN * 2));     // 12.8 MB
    u16*   tb     = (u16*)(ws + alloc((size_t)N_NODES * TPAD * 2));     // 6.4 MB
    u16*   W1b    = (u16*)(ws + alloc((size_t)H_DIM * F_IN * 2));
    u16*   Wcb    = (u16*)(ws + alloc((size_t)C_OUT * H_DIM * 2));
    float* bc     = (float*)(ws + alloc((size_t)C_OUT * 4));

    // pre: coarse histogram + W1 cvt + Wc/bc
    pre_k<<<NCHB + CVT_W1B + C_OUT, 256, 0, stream>>>(
        dst, Ht, (const float4*)W1, (uint2*)W1b, W2, Wout, b2, bout, Wcb, bc);
    // CSR build (no global atomics)
    p1scan_k<<<NBIN1, 256, 0, stream>>>(Ht, totals);
    p1base_k<<<1, 256, 0, stream>>>(totals, base, rowptr);
    p2scatter_k<<<NCHB, 256, 0, stream>>>(src, dst, Ht, base, T);
    p3_k<<<NBIN1, 256, 0, stream>>>(T, base, rowptr, dinv, edata);
    // x cvt with dinv pre-scale
    xcvt_k<<<(CVT_X + 255) / 256, 256, 0, stream>>>((const float4*)x, dinv, (uint2*)xb);

    // layer 1 aggregate-first: aggx = dd*(sum xs + xs_self)
    gather1_k<<<(N_NODES + 3) / 4, 256, 0, stream>>>((const u32*)xb, rowptr, edata, dinv, (u32*)aggxb);
    // fused: h1 = relu(aggx@W1^T+b1) [LDS only] ; tb = dinv*(h1@Wc^T)
    bgemm1f_k<<<768, 256, 0, stream>>>(aggxb, W1b, b1, Wcb, dinv, tb);
    // final: out = dd*(sum ts + ts_self) + bc
    gatherO_k<<<(N_NODES + 3) / 4, 256, 0, stream>>>((const u32*)tb, rowptr, edata, dinv, bc, out);
}